// Round 2
// baseline (5484.266 us; speedup 1.0000x reference)
//
#include <hip/hip_runtime.h>
#include <math.h>

#define HIDDEN 128
#define NEG_SLOPE 0.2f

__device__ __forceinline__ unsigned enc_f(float f) {
    unsigned u = __float_as_uint(f);
    return (u & 0x80000000u) ? ~u : (u | 0x80000000u);
}
__device__ __forceinline__ float dec_f(unsigned u) {
    return (u & 0x80000000u) ? __uint_as_float(u ^ 0x80000000u) : __uint_as_float(~u);
}

// ---------------- encoder: per-node 2-layer MLP (type-selected weights) -----
__global__ void encode_kernel(const float* __restrict__ x, const int* __restrict__ types,
                              const float* __restrict__ ew1, const float* __restrict__ eb1,
                              const float* __restrict__ ew2, const float* __restrict__ eb2,
                              const float* __restrict__ cw1, const float* __restrict__ cb1,
                              const float* __restrict__ cw2, const float* __restrict__ cb2,
                              float* __restrict__ h, int N) {
    int n = blockIdx.x;
    int t = threadIdx.x;
    if (n >= N) return;
    int ty = types[n];                      // block-uniform (one node per block)
    float x0 = x[2 * n], x1 = x[2 * n + 1];
    __shared__ float h1[HIDDEN];
    float v;
    if (ty == 0) v = ew1[2 * t] * x0 + ew1[2 * t + 1] * x1 + eb1[t];
    else         v = cw1[t] * x0 + cb1[t];
    h1[t] = fmaxf(v, 0.f);
    __syncthreads();
    const float* W2 = (ty == 0) ? ew2 : cw2;
    const float* B2 = (ty == 0) ? eb2 : cb2;
    float acc = B2[t];
    const float* wr = W2 + t * HIDDEN;
#pragma unroll 8
    for (int j = 0; j < HIDDEN; j++) acc += wr[j] * h1[j];
    h[(size_t)n * HIDDEN + t] = fmaxf(acc, 0.f);
}

// ---------------- hl = X @ W^T  + per-head attention dots -------------------
template <int H>
__global__ void lin_attn_kernel(const float* __restrict__ X, const float* __restrict__ W,
                                const float* __restrict__ att_s, const float* __restrict__ att_d,
                                float* __restrict__ hl, float* __restrict__ a_s,
                                float* __restrict__ a_d, int N) {
    constexpr int C = HIDDEN / H;
    int n = blockIdx.x;
    int t = threadIdx.x;
    if (n >= N) return;
    __shared__ float xs[HIDDEN];
    __shared__ float ss[HIDDEN];
    __shared__ float sd[HIDDEN];
    xs[t] = X[(size_t)n * HIDDEN + t];
    __syncthreads();
    float acc = 0.f;
    const float* wr = W + t * HIDDEN;
#pragma unroll 8
    for (int j = 0; j < HIDDEN; j++) acc += wr[j] * xs[j];
    hl[(size_t)n * HIDDEN + t] = acc;
    ss[t] = acc * att_s[t];
    sd[t] = acc * att_d[t];
    __syncthreads();
    if (t < H) {
        float a = 0.f, b = 0.f;
        for (int c = 0; c < C; c++) { a += ss[t * C + c]; b += sd[t * C + c]; }
        a_s[n * H + t] = a;
        a_d[n * H + t] = b;
    }
}

// ---------------- per-layer scratch init ------------------------------------
__global__ void init_kernel(float* __restrict__ agg, float* __restrict__ denom,
                            unsigned* __restrict__ amax, int N, int H) {
    int i = blockIdx.x * blockDim.x + threadIdx.x;
    if (i < N * HIDDEN) agg[i] = 0.f;
    if (i < N * H) { denom[i] = 0.f; amax[i] = 0x00800000u; /* enc(-FLT_MAX) */ }
}

// ---------------- edge pass 1: segment max of leaky_relu(alpha) -------------
template <int H>
__global__ void edge_max_kernel(const int* __restrict__ ei, int E, int E2,
                                const float* __restrict__ a_s, const float* __restrict__ a_d,
                                unsigned* __restrict__ amax) {
    int i = blockIdx.x * blockDim.x + threadIdx.x;
    if (i >= E2 * H) return;
    int e = i / H, hh = i % H;
    int s, d;
    if (e < E) { s = ei[e]; d = ei[E + e]; }
    else       { s = d = e - E; }
    float al = a_s[s * H + hh] + a_d[d * H + hh];
    al = (al > 0.f) ? al : NEG_SLOPE * al;
    atomicMax(&amax[d * H + hh], enc_f(al));
}

__global__ void dec_amax_kernel(unsigned* __restrict__ amax, int count) {
    int i = blockIdx.x * blockDim.x + threadIdx.x;
    if (i < count) {
        float v = dec_f(amax[i]);
        ((float*)amax)[i] = v;
    }
}

// ---------------- edge pass 2: ex = exp(alpha - amax), denom += ex ----------
template <int H>
__global__ void edge_exp_kernel(const int* __restrict__ ei, int E, int E2,
                                const float* __restrict__ a_s, const float* __restrict__ a_d,
                                const float* __restrict__ amax, float* __restrict__ ex,
                                float* __restrict__ denom) {
    int i = blockIdx.x * blockDim.x + threadIdx.x;
    if (i >= E2 * H) return;
    int e = i / H, hh = i % H;
    int s, d;
    if (e < E) { s = ei[e]; d = ei[E + e]; }
    else       { s = d = e - E; }
    float al = a_s[s * H + hh] + a_d[d * H + hh];
    al = (al > 0.f) ? al : NEG_SLOPE * al;
    float v = expf(al - amax[d * H + hh]);
    ex[i] = v;
    atomicAdd(&denom[d * H + hh], v);
}

// ---------------- edge pass 3: agg[dst] += hl[src] * att --------------------
template <int H>
__global__ void edge_agg_kernel(const int* __restrict__ ei, int E, int total,
                                const float* __restrict__ hl, const float* __restrict__ ex,
                                const float* __restrict__ denom, float* __restrict__ agg) {
    constexpr int C = HIDDEN / H;
    int i = blockIdx.x * blockDim.x + threadIdx.x;
    if (i >= total) return;
    int f = i & (HIDDEN - 1);
    int e = i >> 7;
    int hh = f / C;
    int s, d;
    if (e < E) { s = ei[e]; d = ei[E + e]; }
    else       { s = d = e - E; }
    float att = ex[e * H + hh] / denom[d * H + hh];
    atomicAdd(&agg[(size_t)d * HIDDEN + f], hl[(size_t)s * HIDDEN + f] * att);
}

// ---------------- finalize: out = [res +] relu(agg + bias) ------------------
__global__ void finalize_kernel(const float* __restrict__ agg, const float* __restrict__ bias,
                                const float* __restrict__ res, float* __restrict__ out, int N) {
    int i = blockIdx.x * blockDim.x + threadIdx.x;
    if (i >= N * HIDDEN) return;
    int f = i & (HIDDEN - 1);
    float v = fmaxf(agg[i] + bias[f], 0.f);
    if (res) v += res[i];
    out[i] = v;
}

// ---------------- decoder ---------------------------------------------------
__global__ void decoder_kernel(const float* __restrict__ H2, const int* __restrict__ types,
                               const float* __restrict__ dw1, const float* __restrict__ db1,
                               const float* __restrict__ dw2, const float* __restrict__ db2,
                               const float* __restrict__ dw3, const float* __restrict__ db3,
                               float* __restrict__ out, int N) {
    int n = blockIdx.x;
    int t = threadIdx.x;
    if (n >= N) return;
    __shared__ float h2s[HIDDEN];
    __shared__ float d1[HIDDEN];
    __shared__ float d2[64];
    h2s[t] = H2[(size_t)n * HIDDEN + t];
    __syncthreads();
    float acc = db1[t];
    const float* wr = dw1 + t * HIDDEN;
#pragma unroll 8
    for (int j = 0; j < HIDDEN; j++) acc += wr[j] * h2s[j];
    d1[t] = fmaxf(acc, 0.f);
    __syncthreads();
    if (t < 64) {
        float a2 = db2[t];
        const float* w2 = dw2 + t * HIDDEN;
#pragma unroll 8
        for (int j = 0; j < HIDDEN; j++) a2 += w2[j] * d1[j];
        d2[t] = fmaxf(a2, 0.f);
    }
    __syncthreads();
    if (t < 64) {
        float p = dw3[t] * d2[t];
#pragma unroll
        for (int off = 32; off; off >>= 1) p += __shfl_down(p, off, 64);
        if (t == 0) {
            float logit = p + db3[0];
            float prob = 1.f / (1.f + expf(-logit));
            out[n] = (types[n] == 0) ? prob : 0.f;
        }
    }
}

// ---------------- host-side layer driver ------------------------------------
template <int H>
static void gat_layer(const float* X, const float* lin, const float* as_, const float* ad_,
                      const float* bias, const float* res, float* hl, float* agg, float* outb,
                      float* a_s, float* a_d, float* amax, float* denom, float* ex,
                      const int* ei, int N, int E, int E2, hipStream_t stream) {
    lin_attn_kernel<H><<<N, 128, 0, stream>>>(X, lin, as_, ad_, hl, a_s, a_d, N);
    int initN = N * HIDDEN;
    init_kernel<<<(initN + 255) / 256, 256, 0, stream>>>(agg, denom, (unsigned*)amax, N, H);
    int eh = E2 * H;
    edge_max_kernel<H><<<(eh + 255) / 256, 256, 0, stream>>>(ei, E, E2, a_s, a_d, (unsigned*)amax);
    dec_amax_kernel<<<(N * H + 255) / 256, 256, 0, stream>>>((unsigned*)amax, N * H);
    edge_exp_kernel<H><<<(eh + 255) / 256, 256, 0, stream>>>(ei, E, E2, a_s, a_d, amax, ex, denom);
    int tot = E2 * HIDDEN;
    edge_agg_kernel<H><<<(tot + 255) / 256, 256, 0, stream>>>(ei, E, tot, hl, ex, denom, agg);
    finalize_kernel<<<(initN + 255) / 256, 256, 0, stream>>>(agg, bias, res, outb, N);
}

extern "C" void kernel_launch(void* const* d_in, const int* in_sizes, int n_in,
                              void* d_out, int out_size, void* d_ws, size_t ws_size,
                              hipStream_t stream) {
    const float* x     = (const float*)d_in[0];
    const int*   types = (const int*)d_in[1];
    const int*   ei    = (const int*)d_in[2];   // int64 in reference, int32 on device
    const float* ew1 = (const float*)d_in[3];
    const float* eb1 = (const float*)d_in[4];
    const float* ew2 = (const float*)d_in[5];
    const float* eb2 = (const float*)d_in[6];
    const float* cw1 = (const float*)d_in[7];
    const float* cb1 = (const float*)d_in[8];
    const float* cw2 = (const float*)d_in[9];
    const float* cb2 = (const float*)d_in[10];
    const float* lin0 = (const float*)d_in[11];
    const float* as0  = (const float*)d_in[12];
    const float* ad0  = (const float*)d_in[13];
    const float* b0   = (const float*)d_in[14];
    const float* lin1 = (const float*)d_in[15];
    const float* as1  = (const float*)d_in[16];
    const float* ad1  = (const float*)d_in[17];
    const float* b1   = (const float*)d_in[18];
    const float* lin2 = (const float*)d_in[19];
    const float* as2  = (const float*)d_in[20];
    const float* ad2  = (const float*)d_in[21];
    const float* b2   = (const float*)d_in[22];
    const float* dw1 = (const float*)d_in[23];
    const float* db1 = (const float*)d_in[24];
    const float* dw2 = (const float*)d_in[25];
    const float* db2 = (const float*)d_in[26];
    const float* dw3 = (const float*)d_in[27];
    const float* db3 = (const float*)d_in[28];

    int N  = in_sizes[1];
    int E  = in_sizes[2] / 2;
    int E2 = E + N;

    float* ws = (float*)d_ws;
    size_t NF = (size_t)N * HIDDEN;
    float* bufA = ws;
    float* bufB = ws + NF;
    float* bufC = ws + 2 * NF;
    float* a_s   = ws + 3 * NF;
    float* a_d   = a_s + (size_t)N * 4;
    float* amax  = a_d + (size_t)N * 4;
    float* denom = amax + (size_t)N * 4;
    float* ex    = denom + (size_t)N * 4;   // E2*4 floats

    // encoder -> bufA
    encode_kernel<<<N, 128, 0, stream>>>(x, types, ew1, eb1, ew2, eb2, cw1, cb1, cw2, cb2,
                                         bufA, N);
    // layer 0: h0 = relu(gat(h)) -> bufA (hl=bufB, agg=bufC)
    gat_layer<4>(bufA, lin0, as0, ad0, b0, nullptr, bufB, bufC, bufA,
                 a_s, a_d, amax, denom, ex, ei, N, E, E2, stream);
    // layer 1: h1 = h0 + relu(gat(h0)) -> bufB
    gat_layer<4>(bufA, lin1, as1, ad1, b1, bufA, bufB, bufC, bufB,
                 a_s, a_d, amax, denom, ex, ei, N, E, E2, stream);
    // layer 2 (1 head, no concat): h2 = h1 + relu(gat(h1)) -> bufA
    gat_layer<1>(bufB, lin2, as2, ad2, b2, bufB, bufA, bufC, bufA,
                 a_s, a_d, amax, denom, ex, ei, N, E, E2, stream);
    // decoder
    decoder_kernel<<<N, 128, 0, stream>>>(bufA, types, dw1, db1, dw2, db2, dw3, db3,
                                          (float*)d_out, N);
}

// Round 3
// 2476.149 us; speedup vs baseline: 2.2148x; 2.2148x over previous
//
#include <hip/hip_runtime.h>
#include <math.h>

#define HIDDEN 128
#define NEG_SLOPE 0.2f
#define LP 132   // LDS row pitch (floats): 128 + 4 pad, keeps float4 alignment

__device__ __forceinline__ unsigned enc_f(float f) {
    unsigned u = __float_as_uint(f);
    return (u & 0x80000000u) ? ~u : (u | 0x80000000u);
}
__device__ __forceinline__ float dec_f(unsigned u) {
    return (u & 0x80000000u) ? __uint_as_float(u ^ 0x80000000u) : __uint_as_float(~u);
}

// ============ generic tiled GEMM: out[N,OUT] = op(X[N,128] @ W[OUT,128]^T) =====
// mode 0: raw     mode 1: relu(acc + bias)
// mode 2: relu(acc + bias) then select: type==0 -> keep prev(out), type==1 -> v, else 0
__global__ __launch_bounds__(128) void gemm_kernel(
        const float* __restrict__ X, const float* __restrict__ W,
        const float* __restrict__ bias, const int* __restrict__ types,
        float* __restrict__ out, int N, int OUT, int mode) {
    __shared__ float Xs[64 * LP];
    __shared__ float Ws[32 * LP];
    const int n0 = blockIdx.x * 64;
    const int oo = blockIdx.y * 32;
    const int tid = threadIdx.x;

    // stage X tile (64 x 128), zero-fill rows past N
#pragma unroll
    for (int r = 0; r < 16; r++) {
        int j = tid + 128 * r;
        int m = j >> 5, k4 = (j & 31) << 2;
        int n = n0 + m;
        float4 v = make_float4(0.f, 0.f, 0.f, 0.f);
        if (n < N) v = *(const float4*)&X[(size_t)n * 128 + k4];
        *(float4*)&Xs[m * LP + k4] = v;
    }
    // stage W tile (32 x 128)
#pragma unroll
    for (int r = 0; r < 8; r++) {
        int j = tid + 128 * r;
        int o = j >> 5, k4 = (j & 31) << 2;
        *(float4*)&Ws[o * LP + k4] = *(const float4*)&W[(size_t)(oo + o) * 128 + k4];
    }
    __syncthreads();

    const int tm = tid & 15;   // node group: nodes 4*tm..4*tm+3
    const int to = tid >> 4;   // out group : outs 4*to..4*to+3 (0..7)
    float acc[4][4] = {{0.f}};
#pragma unroll 4
    for (int kk = 0; kk < 128; kk += 4) {
        float4 xv[4], wv[4];
#pragma unroll
        for (int i = 0; i < 4; i++) xv[i] = *(float4*)&Xs[(4 * tm + i) * LP + kk];
#pragma unroll
        for (int j = 0; j < 4; j++) wv[j] = *(float4*)&Ws[(4 * to + j) * LP + kk];
#pragma unroll
        for (int i = 0; i < 4; i++)
#pragma unroll
            for (int j = 0; j < 4; j++)
                acc[i][j] += xv[i].x * wv[j].x + xv[i].y * wv[j].y +
                             xv[i].z * wv[j].z + xv[i].w * wv[j].w;
    }

    float4 bv = make_float4(0.f, 0.f, 0.f, 0.f);
    if (mode >= 1) bv = *(const float4*)&bias[oo + 4 * to];
#pragma unroll
    for (int i = 0; i < 4; i++) {
        int n = n0 + 4 * tm + i;
        if (n >= N) continue;
        size_t base = (size_t)n * OUT + oo + 4 * to;
        float v0 = acc[i][0], v1 = acc[i][1], v2 = acc[i][2], v3 = acc[i][3];
        if (mode >= 1) {
            v0 = fmaxf(v0 + bv.x, 0.f); v1 = fmaxf(v1 + bv.y, 0.f);
            v2 = fmaxf(v2 + bv.z, 0.f); v3 = fmaxf(v3 + bv.w, 0.f);
        }
        if (mode == 2) {
            int ty = types[n];
            if (ty == 0) {
                float4 pv = *(const float4*)&out[base];
                v0 = pv.x; v1 = pv.y; v2 = pv.z; v3 = pv.w;
            } else if (ty != 1) { v0 = v1 = v2 = v3 = 0.f; }
        }
        float4 o4 = make_float4(v0, v1, v2, v3);
        *(float4*)&out[base] = o4;
    }
}

// ============ encoder layer-1 (elementwise, both types) ========================
__global__ void enc_h1_kernel(const float* __restrict__ x,
                              const float* __restrict__ ew1, const float* __restrict__ eb1,
                              const float* __restrict__ cw1, const float* __restrict__ cb1,
                              float* __restrict__ h1_item, float* __restrict__ h1_con, int N) {
    int i = blockIdx.x * blockDim.x + threadIdx.x;
    if (i >= N * HIDDEN) return;
    int n = i >> 7, t = i & 127;
    float x0 = x[2 * n], x1 = x[2 * n + 1];
    h1_item[i] = fmaxf(ew1[2 * t] * x0 + ew1[2 * t + 1] * x1 + eb1[t], 0.f);
    h1_con[i]  = fmaxf(cw1[t] * x0 + cb1[t], 0.f);
}

// ============ attention dots: a_s/a_d[n,h] = sum_c hl[n,h,c]*att[h,c] ==========
template <int H>
__global__ void attn_dots_kernel(const float* __restrict__ hl,
                                 const float* __restrict__ att_s, const float* __restrict__ att_d,
                                 float* __restrict__ a_s, float* __restrict__ a_d, int N) {
    int n = blockIdx.x * 4 + (threadIdx.x >> 6);
    int l = threadIdx.x & 63;
    if (n >= N) return;
    float v1 = hl[(size_t)n * 128 + l];
    float v2 = hl[(size_t)n * 128 + 64 + l];
    float s1 = v1 * att_s[l], s2 = v2 * att_s[64 + l];
    float d1 = v1 * att_d[l], d2 = v2 * att_d[64 + l];
    if (H == 1) {
        float s = s1 + s2, d = d1 + d2;
#pragma unroll
        for (int off = 32; off; off >>= 1) {
            s += __shfl_down(s, off, 64);
            d += __shfl_down(d, off, 64);
        }
        if (l == 0) { a_s[n] = s; a_d[n] = d; }
    } else {  // H == 4, heads are 32-channel segments
#pragma unroll
        for (int off = 16; off; off >>= 1) {
            s1 += __shfl_down(s1, off, 32); s2 += __shfl_down(s2, off, 32);
            d1 += __shfl_down(d1, off, 32); d2 += __shfl_down(d2, off, 32);
        }
        if ((l & 31) == 0) {
            int g = l >> 5;  // 0 or 1
            a_s[n * 4 + g]     = s1;  a_s[n * 4 + 2 + g] = s2;
            a_d[n * 4 + g]     = d1;  a_d[n * 4 + 2 + g] = d2;
        }
    }
}

// ============ per-layer scratch init ==========================================
__global__ void init_kernel(float* __restrict__ agg, float* __restrict__ denom,
                            unsigned* __restrict__ amax, int N, int H) {
    int i = blockIdx.x * blockDim.x + threadIdx.x;
    if (i < N * HIDDEN) agg[i] = 0.f;
    if (i < N * H) { denom[i] = 0.f; amax[i] = 0x00800000u; /* enc(-FLT_MAX) */ }
}

// ============ edge pass 1: segment max ========================================
template <int H>
__global__ void edge_max_kernel(const int* __restrict__ ei, int E, int E2,
                                const float* __restrict__ a_s, const float* __restrict__ a_d,
                                unsigned* __restrict__ amax) {
    int i = blockIdx.x * blockDim.x + threadIdx.x;
    if (i >= E2 * H) return;
    int e = i / H, hh = i % H;
    int s, d;
    if (e < E) { s = ei[e]; d = ei[E + e]; }
    else       { s = d = e - E; }
    float al = a_s[s * H + hh] + a_d[d * H + hh];
    al = (al > 0.f) ? al : NEG_SLOPE * al;
    atomicMax(&amax[d * H + hh], enc_f(al));
}

__global__ void dec_amax_kernel(unsigned* __restrict__ amax, int count) {
    int i = blockIdx.x * blockDim.x + threadIdx.x;
    if (i < count) {
        float v = dec_f(amax[i]);
        ((float*)amax)[i] = v;
    }
}

// ============ edge pass 2: ex + denom =========================================
template <int H>
__global__ void edge_exp_kernel(const int* __restrict__ ei, int E, int E2,
                                const float* __restrict__ a_s, const float* __restrict__ a_d,
                                const float* __restrict__ amax, float* __restrict__ ex,
                                float* __restrict__ denom) {
    int i = blockIdx.x * blockDim.x + threadIdx.x;
    if (i >= E2 * H) return;
    int e = i / H, hh = i % H;
    int s, d;
    if (e < E) { s = ei[e]; d = ei[E + e]; }
    else       { s = d = e - E; }
    float al = a_s[s * H + hh] + a_d[d * H + hh];
    al = (al > 0.f) ? al : NEG_SLOPE * al;
    float v = expf(al - amax[d * H + hh]);
    ex[i] = v;
    atomicAdd(&denom[d * H + hh], v);
}

// ============ edge pass 3: aggregate ==========================================
template <int H>
__global__ void edge_agg_kernel(const int* __restrict__ ei, int E, int total,
                                const float* __restrict__ hl, const float* __restrict__ ex,
                                const float* __restrict__ denom, float* __restrict__ agg) {
    constexpr int C = HIDDEN / H;
    int i = blockIdx.x * blockDim.x + threadIdx.x;
    if (i >= total) return;
    int f = i & (HIDDEN - 1);
    int e = i >> 7;
    int hh = f / C;
    int s, d;
    if (e < E) { s = ei[e]; d = ei[E + e]; }
    else       { s = d = e - E; }
    float att = ex[e * H + hh] / denom[d * H + hh];
    atomicAdd(&agg[(size_t)d * HIDDEN + f], hl[(size_t)s * HIDDEN + f] * att);
}

// ============ finalize: out = [res +] relu(agg + bias) ========================
__global__ void finalize_kernel(const float* __restrict__ agg, const float* __restrict__ bias,
                                const float* __restrict__ res, float* __restrict__ out, int N) {
    int i = blockIdx.x * blockDim.x + threadIdx.x;
    if (i >= N * HIDDEN) return;
    int f = i & (HIDDEN - 1);
    float v = fmaxf(agg[i] + bias[f], 0.f);
    if (res) v += res[i];
    out[i] = v;
}

// ============ decoder final dot + sigmoid + mask ==============================
__global__ void dec_final_kernel(const float* __restrict__ d2, const int* __restrict__ types,
                                 const float* __restrict__ dw3, const float* __restrict__ db3,
                                 float* __restrict__ out, int N) {
    int n = blockIdx.x * 4 + (threadIdx.x >> 6);
    int l = threadIdx.x & 63;
    if (n >= N) return;
    float p = d2[(size_t)n * 64 + l] * dw3[l];
#pragma unroll
    for (int off = 32; off; off >>= 1) p += __shfl_down(p, off, 64);
    if (l == 0) {
        float prob = 1.f / (1.f + expf(-(p + db3[0])));
        out[n] = (types[n] == 0) ? prob : 0.f;
    }
}

// ============ host-side layer driver ==========================================
template <int H>
static void gat_layer(const float* X, const float* lin, const float* as_, const float* ad_,
                      const float* bias, const float* res, float* hl, float* agg, float* outb,
                      float* a_s, float* a_d, float* amax, float* denom, float* ex,
                      const int* ei, int N, int E, int E2, hipStream_t stream) {
    dim3 ggrid((N + 63) / 64, 4);
    gemm_kernel<<<ggrid, 128, 0, stream>>>(X, lin, nullptr, nullptr, hl, N, 128, 0);
    attn_dots_kernel<H><<<(N + 3) / 4, 256, 0, stream>>>(hl, as_, ad_, a_s, a_d, N);
    int initN = N * HIDDEN;
    init_kernel<<<(initN + 255) / 256, 256, 0, stream>>>(agg, denom, (unsigned*)amax, N, H);
    int eh = E2 * H;
    edge_max_kernel<H><<<(eh + 255) / 256, 256, 0, stream>>>(ei, E, E2, a_s, a_d, (unsigned*)amax);
    dec_amax_kernel<<<(N * H + 255) / 256, 256, 0, stream>>>((unsigned*)amax, N * H);
    edge_exp_kernel<H><<<(eh + 255) / 256, 256, 0, stream>>>(ei, E, E2, a_s, a_d, amax, ex, denom);
    int tot = E2 * HIDDEN;
    edge_agg_kernel<H><<<(tot + 255) / 256, 256, 0, stream>>>(ei, E, tot, hl, ex, denom, agg);
    finalize_kernel<<<(initN + 255) / 256, 256, 0, stream>>>(agg, bias, res, outb, N);
}

extern "C" void kernel_launch(void* const* d_in, const int* in_sizes, int n_in,
                              void* d_out, int out_size, void* d_ws, size_t ws_size,
                              hipStream_t stream) {
    const float* x     = (const float*)d_in[0];
    const int*   types = (const int*)d_in[1];
    const int*   ei    = (const int*)d_in[2];   // int64 in reference -> int32 on device
    const float* ew1 = (const float*)d_in[3];
    const float* eb1 = (const float*)d_in[4];
    const float* ew2 = (const float*)d_in[5];
    const float* eb2 = (const float*)d_in[6];
    const float* cw1 = (const float*)d_in[7];
    const float* cb1 = (const float*)d_in[8];
    const float* cw2 = (const float*)d_in[9];
    const float* cb2 = (const float*)d_in[10];
    const float* lin0 = (const float*)d_in[11];
    const float* as0  = (const float*)d_in[12];
    const float* ad0  = (const float*)d_in[13];
    const float* b0   = (const float*)d_in[14];
    const float* lin1 = (const float*)d_in[15];
    const float* as1  = (const float*)d_in[16];
    const float* ad1  = (const float*)d_in[17];
    const float* b1   = (const float*)d_in[18];
    const float* lin2 = (const float*)d_in[19];
    const float* as2  = (const float*)d_in[20];
    const float* ad2  = (const float*)d_in[21];
    const float* b2   = (const float*)d_in[22];
    const float* dw1 = (const float*)d_in[23];
    const float* db1 = (const float*)d_in[24];
    const float* dw2 = (const float*)d_in[25];
    const float* db2 = (const float*)d_in[26];
    const float* dw3 = (const float*)d_in[27];
    const float* db3 = (const float*)d_in[28];

    int N  = in_sizes[1];
    int E  = in_sizes[2] / 2;
    int E2 = E + N;

    float* ws = (float*)d_ws;
    size_t NF = (size_t)N * HIDDEN;
    float* bufA = ws;
    float* bufB = ws + NF;
    float* bufC = ws + 2 * NF;
    float* a_s   = ws + 3 * NF;
    float* a_d   = a_s + (size_t)N * 4;
    float* amax  = a_d + (size_t)N * 4;
    float* denom = amax + (size_t)N * 4;
    float* ex    = denom + (size_t)N * 4;   // E2*4 floats

    dim3 g128((N + 63) / 64, 4);
    dim3 g64((N + 63) / 64, 2);

    // ---- encoder: h1 for both types -> two GEMMs -> type select into bufA
    enc_h1_kernel<<<(N * HIDDEN + 255) / 256, 256, 0, stream>>>(x, ew1, eb1, cw1, cb1,
                                                               bufB, bufC, N);
    gemm_kernel<<<g128, 128, 0, stream>>>(bufB, ew2, eb2, nullptr, bufA, N, 128, 1);
    gemm_kernel<<<g128, 128, 0, stream>>>(bufC, cw2, cb2, types, bufA, N, 128, 2);

    // ---- layer 0: h0 = relu(gat(h)) -> bufA (hl=bufB, agg=bufC)
    gat_layer<4>(bufA, lin0, as0, ad0, b0, nullptr, bufB, bufC, bufA,
                 a_s, a_d, amax, denom, ex, ei, N, E, E2, stream);
    // ---- layer 1: h1 = h0 + relu(gat(h0)) -> bufB
    gat_layer<4>(bufA, lin1, as1, ad1, b1, bufA, bufB, bufC, bufB,
                 a_s, a_d, amax, denom, ex, ei, N, E, E2, stream);
    // ---- layer 2 (1 head, no concat): h2 = h1 + relu(gat(h1)) -> bufA
    gat_layer<1>(bufB, lin2, as2, ad2, b2, bufB, bufA, bufC, bufA,
                 a_s, a_d, amax, denom, ex, ei, N, E, E2, stream);

    // ---- decoder: d1 = relu(h2@dw1^T+db1) -> bufC ; d2 -> bufB ; final dot
    gemm_kernel<<<g128, 128, 0, stream>>>(bufA, dw1, db1, nullptr, bufC, N, 128, 1);
    gemm_kernel<<<g64, 128, 0, stream>>>(bufC, dw2, db2, nullptr, bufB, N, 64, 1);
    dec_final_kernel<<<(N + 3) / 4, 256, 0, stream>>>(bufB, types, dw3, db3,
                                                      (float*)d_out, N);
}

// Round 5
// 1686.369 us; speedup vs baseline: 3.2521x; 1.4683x over previous
//
#include <hip/hip_runtime.h>
#include <math.h>

#define HIDDEN 128
#define NEG_SLOPE 0.2f
#define LP 132   // LDS row pitch (floats): 128 + 4 pad

// ============ generic tiled GEMM: out[N,OUT] = op(X[N,128] @ W[OUT,128]^T) =====
// mode 0: raw     mode 1: relu(acc + bias)
// mode 2: relu(acc + bias) then select: type==0 -> keep prev(out), type==1 -> v, else 0
__global__ __launch_bounds__(128) void gemm_kernel(
        const float* __restrict__ X, const float* __restrict__ W,
        const float* __restrict__ bias, const int* __restrict__ types,
        float* __restrict__ out, int N, int OUT, int mode) {
    __shared__ float Xs[64 * LP];
    __shared__ float Ws[32 * LP];
    const int n0 = blockIdx.x * 64;
    const int oo = blockIdx.y * 32;
    const int tid = threadIdx.x;

#pragma unroll
    for (int r = 0; r < 16; r++) {
        int j = tid + 128 * r;
        int m = j >> 5, k4 = (j & 31) << 2;
        int n = n0 + m;
        float4 v = make_float4(0.f, 0.f, 0.f, 0.f);
        if (n < N) v = *(const float4*)&X[(size_t)n * 128 + k4];
        *(float4*)&Xs[m * LP + k4] = v;
    }
#pragma unroll
    for (int r = 0; r < 8; r++) {
        int j = tid + 128 * r;
        int o = j >> 5, k4 = (j & 31) << 2;
        *(float4*)&Ws[o * LP + k4] = *(const float4*)&W[(size_t)(oo + o) * 128 + k4];
    }
    __syncthreads();

    const int tm = tid & 15;
    const int to = tid >> 4;
    float acc[4][4] = {{0.f}};
#pragma unroll 4
    for (int kk = 0; kk < 128; kk += 4) {
        float4 xv[4], wv[4];
#pragma unroll
        for (int i = 0; i < 4; i++) xv[i] = *(float4*)&Xs[(4 * tm + i) * LP + kk];
#pragma unroll
        for (int j = 0; j < 4; j++) wv[j] = *(float4*)&Ws[(4 * to + j) * LP + kk];
#pragma unroll
        for (int i = 0; i < 4; i++)
#pragma unroll
            for (int j = 0; j < 4; j++)
                acc[i][j] += xv[i].x * wv[j].x + xv[i].y * wv[j].y +
                             xv[i].z * wv[j].z + xv[i].w * wv[j].w;
    }

    float4 bv = make_float4(0.f, 0.f, 0.f, 0.f);
    if (mode >= 1) bv = *(const float4*)&bias[oo + 4 * to];
#pragma unroll
    for (int i = 0; i < 4; i++) {
        int n = n0 + 4 * tm + i;
        if (n >= N) continue;
        size_t base = (size_t)n * OUT + oo + 4 * to;
        float v0 = acc[i][0], v1 = acc[i][1], v2 = acc[i][2], v3 = acc[i][3];
        if (mode >= 1) {
            v0 = fmaxf(v0 + bv.x, 0.f); v1 = fmaxf(v1 + bv.y, 0.f);
            v2 = fmaxf(v2 + bv.z, 0.f); v3 = fmaxf(v3 + bv.w, 0.f);
        }
        if (mode == 2) {
            int ty = types[n];
            if (ty == 0) {
                float4 pv = *(const float4*)&out[base];
                v0 = pv.x; v1 = pv.y; v2 = pv.z; v3 = pv.w;
            } else if (ty != 1) { v0 = v1 = v2 = v3 = 0.f; }
        }
        *(float4*)&out[base] = make_float4(v0, v1, v2, v3);
    }
}

// ============ encoder layer-1 (elementwise, both types) ========================
__global__ void enc_h1_kernel(const float* __restrict__ x,
                              const float* __restrict__ ew1, const float* __restrict__ eb1,
                              const float* __restrict__ cw1, const float* __restrict__ cb1,
                              float* __restrict__ h1_item, float* __restrict__ h1_con, int N) {
    int i = blockIdx.x * blockDim.x + threadIdx.x;
    if (i >= N * HIDDEN) return;
    int n = i >> 7, t = i & 127;
    float x0 = x[2 * n], x1 = x[2 * n + 1];
    h1_item[i] = fmaxf(ew1[2 * t] * x0 + ew1[2 * t + 1] * x1 + eb1[t], 0.f);
    h1_con[i]  = fmaxf(cw1[t] * x0 + cb1[t], 0.f);
}

// ============ attention dots ===================================================
template <int H>
__global__ void attn_dots_kernel(const float* __restrict__ hl,
                                 const float* __restrict__ att_s, const float* __restrict__ att_d,
                                 float* __restrict__ a_s, float* __restrict__ a_d, int N) {
    int n = blockIdx.x * 4 + (threadIdx.x >> 6);
    int l = threadIdx.x & 63;
    if (n >= N) return;
    float v1 = hl[(size_t)n * 128 + l];
    float v2 = hl[(size_t)n * 128 + 64 + l];
    float s1 = v1 * att_s[l], s2 = v2 * att_s[64 + l];
    float d1 = v1 * att_d[l], d2 = v2 * att_d[64 + l];
    if (H == 1) {
        float s = s1 + s2, d = d1 + d2;
#pragma unroll
        for (int off = 32; off; off >>= 1) {
            s += __shfl_down(s, off, 64);
            d += __shfl_down(d, off, 64);
        }
        if (l == 0) { a_s[n] = s; a_d[n] = d; }
    } else {
#pragma unroll
        for (int off = 16; off; off >>= 1) {
            s1 += __shfl_down(s1, off, 32); s2 += __shfl_down(s2, off, 32);
            d1 += __shfl_down(d1, off, 32); d2 += __shfl_down(d2, off, 32);
        }
        if ((l & 31) == 0) {
            int g = l >> 5;
            a_s[n * 4 + g]     = s1;  a_s[n * 4 + 2 + g] = s2;
            a_d[n * 4 + g]     = d1;  a_d[n * 4 + 2 + g] = d2;
        }
    }
}

// ============ CSR build ========================================================
__global__ void zero2_kernel(int* __restrict__ a, int* __restrict__ b, int N) {
    int i = blockIdx.x * blockDim.x + threadIdx.x;
    if (i < N) { a[i] = 0; b[i] = 0; }
}

__global__ void hist_kernel(const int* __restrict__ ei, int E, int E2, int* __restrict__ cnt) {
    int e = blockIdx.x * blockDim.x + threadIdx.x;
    if (e >= E2) return;
    int d = (e < E) ? ei[E + e] : e - E;
    atomicAdd(&cnt[d], 1);
}

__global__ void scan1_kernel(const int* __restrict__ cnt, int* __restrict__ rs,
                             int* __restrict__ bsum, int N) {
    __shared__ int s[256];
    int i = blockIdx.x * 256 + threadIdx.x;
    int v = (i < N) ? cnt[i] : 0;
    s[threadIdx.x] = v;
    __syncthreads();
    for (int off = 1; off < 256; off <<= 1) {
        int t = (threadIdx.x >= off) ? s[threadIdx.x - off] : 0;
        __syncthreads();
        s[threadIdx.x] += t;
        __syncthreads();
    }
    if (i < N) rs[i] = s[threadIdx.x];
    if (threadIdx.x == 255) bsum[blockIdx.x] = s[255];
}

__global__ void scan2_kernel(int* __restrict__ bsum, int nb) {
    __shared__ int s[1024];
    int i = threadIdx.x;
    int v = (i < nb) ? bsum[i] : 0;
    s[i] = v;
    __syncthreads();
    for (int off = 1; off < 1024; off <<= 1) {
        int t = (i >= off) ? s[i - off] : 0;
        __syncthreads();
        s[i] += t;
        __syncthreads();
    }
    if (i < nb) bsum[i] = s[i] - v;
}

__global__ void scan3_kernel(int* __restrict__ rs, const int* __restrict__ cnt,
                             const int* __restrict__ bsum, int N) {
    int i = blockIdx.x * 256 + threadIdx.x;
    if (i < N) rs[i] = rs[i] - cnt[i] + bsum[blockIdx.x];
}

__global__ void scatter_kernel(const int* __restrict__ ei, int E, int E2,
                               const int* __restrict__ rs, int* __restrict__ cursor,
                               int* __restrict__ srclist) {
    int e = blockIdx.x * blockDim.x + threadIdx.x;
    if (e >= E2) return;
    int s, d;
    if (e < E) { s = ei[e]; d = ei[E + e]; }
    else       { s = d = e - E; }
    int pos = atomicAdd(&cursor[d], 1);
    srclist[rs[d] + pos] = s;
}

// ============ fused GAT aggregation: online softmax + gather + epilogue ========
// NOTE: `out` must NEVER alias `hl` (cross-block reads of hl rows). out may
// alias X/res (each row touched only by its own node's thread group).
template <int H>
__global__ __launch_bounds__(256) void gat_agg_kernel(
        const int* __restrict__ rs, const int* __restrict__ cnt,
        const int* __restrict__ srclist, const float* __restrict__ hl,
        const float* __restrict__ a_s, const float* __restrict__ a_d,
        const float* __restrict__ bias, const float* __restrict__ res,
        float* __restrict__ out, int N) {
    int n = blockIdx.x * 2 + (threadIdx.x >> 7);
    int f = threadIdx.x & 127;
    if (n >= N) return;
    const int hh = (H == 1) ? 0 : (f >> 5);    // C = 128/H = 32 for H=4
    const float ad = a_d[n * H + hh];
    const int beg = rs[n];
    const int deg = cnt[n];
    float m = -INFINITY, l = 0.f, acc = 0.f;
    for (int i = 0; i < deg; i++) {
        int s = srclist[beg + i];
        float al = a_s[s * H + hh] + ad;
        al = (al > 0.f) ? al : NEG_SLOPE * al;
        float hv = hl[(size_t)s * 128 + f];
        float nm = fmaxf(m, al);
        float sc = expf(m - nm);    // 0 when m == -inf
        float p  = expf(al - nm);
        acc = acc * sc + p * hv;
        l   = l * sc + p;
        m   = nm;
    }
    float v = fmaxf(acc / l + bias[f], 0.f);   // deg >= 1 (self-loop)
    if (res) v += res[(size_t)n * 128 + f];
    out[(size_t)n * 128 + f] = v;
}

// ============ decoder final dot + sigmoid + mask ==============================
__global__ void dec_final_kernel(const float* __restrict__ d2, const int* __restrict__ types,
                                 const float* __restrict__ dw3, const float* __restrict__ db3,
                                 float* __restrict__ out, int N) {
    int n = blockIdx.x * 4 + (threadIdx.x >> 6);
    int l = threadIdx.x & 63;
    if (n >= N) return;
    float p = d2[(size_t)n * 64 + l] * dw3[l];
#pragma unroll
    for (int off = 32; off; off >>= 1) p += __shfl_down(p, off, 64);
    if (l == 0) {
        float prob = 1.f / (1.f + expf(-(p + db3[0])));
        out[n] = (types[n] == 0) ? prob : 0.f;
    }
}

// ============ host-side layer driver ==========================================
template <int H>
static void gat_layer(const float* X, const float* lin, const float* as_, const float* ad_,
                      const float* bias, const float* res, float* hl, float* outb,
                      float* a_s, float* a_d, const int* rs, const int* cnt,
                      const int* srclist, int N, hipStream_t stream) {
    dim3 ggrid((N + 63) / 64, 4);
    gemm_kernel<<<ggrid, 128, 0, stream>>>(X, lin, nullptr, nullptr, hl, N, 128, 0);
    attn_dots_kernel<H><<<(N + 3) / 4, 256, 0, stream>>>(hl, as_, ad_, a_s, a_d, N);
    gat_agg_kernel<H><<<(N + 1) / 2, 256, 0, stream>>>(rs, cnt, srclist, hl, a_s, a_d,
                                                       bias, res, outb, N);
}

extern "C" void kernel_launch(void* const* d_in, const int* in_sizes, int n_in,
                              void* d_out, int out_size, void* d_ws, size_t ws_size,
                              hipStream_t stream) {
    const float* x     = (const float*)d_in[0];
    const int*   types = (const int*)d_in[1];
    const int*   ei    = (const int*)d_in[2];   // int64 in reference -> int32 on device
    const float* ew1 = (const float*)d_in[3];
    const float* eb1 = (const float*)d_in[4];
    const float* ew2 = (const float*)d_in[5];
    const float* eb2 = (const float*)d_in[6];
    const float* cw1 = (const float*)d_in[7];
    const float* cb1 = (const float*)d_in[8];
    const float* cw2 = (const float*)d_in[9];
    const float* cb2 = (const float*)d_in[10];
    const float* lin0 = (const float*)d_in[11];
    const float* as0  = (const float*)d_in[12];
    const float* ad0  = (const float*)d_in[13];
    const float* b0   = (const float*)d_in[14];
    const float* lin1 = (const float*)d_in[15];
    const float* as1  = (const float*)d_in[16];
    const float* ad1  = (const float*)d_in[17];
    const float* b1   = (const float*)d_in[18];
    const float* lin2 = (const float*)d_in[19];
    const float* as2  = (const float*)d_in[20];
    const float* ad2  = (const float*)d_in[21];
    const float* b2   = (const float*)d_in[22];
    const float* dw1 = (const float*)d_in[23];
    const float* db1 = (const float*)d_in[24];
    const float* dw2 = (const float*)d_in[25];
    const float* db2 = (const float*)d_in[26];
    const float* dw3 = (const float*)d_in[27];
    const float* db3 = (const float*)d_in[28];

    int N  = in_sizes[1];
    int E  = in_sizes[2] / 2;
    int E2 = E + N;

    float* ws = (float*)d_ws;
    size_t NF = (size_t)N * HIDDEN;
    float* bufA = ws;
    float* bufB = ws + NF;
    float* bufC = ws + 2 * NF;
    float* a_s  = ws + 3 * NF;
    float* a_d  = a_s + (size_t)N * 4;
    int* rs      = (int*)(a_d + (size_t)N * 4);
    int* cnt     = rs + N;
    int* cursor  = cnt + N;
    int* bsum    = cursor + N;          // up to 1024 entries
    int* srclist = bsum + 1024;         // E2 entries

    int nb = (N + 255) / 256;

    // ---- CSR build (edge structure shared by all 3 layers)
    zero2_kernel<<<nb, 256, 0, stream>>>(cnt, cursor, N);
    hist_kernel<<<(E2 + 255) / 256, 256, 0, stream>>>(ei, E, E2, cnt);
    scan1_kernel<<<nb, 256, 0, stream>>>(cnt, rs, bsum, N);
    scan2_kernel<<<1, 1024, 0, stream>>>(bsum, nb);
    scan3_kernel<<<nb, 256, 0, stream>>>(rs, cnt, bsum, N);
    scatter_kernel<<<(E2 + 255) / 256, 256, 0, stream>>>(ei, E, E2, rs, cursor, srclist);

    dim3 g128((N + 63) / 64, 4);
    dim3 g64((N + 63) / 64, 2);

    // ---- encoder -> bufA
    enc_h1_kernel<<<(N * HIDDEN + 255) / 256, 256, 0, stream>>>(x, ew1, eb1, cw1, cb1,
                                                               bufB, bufC, N);
    gemm_kernel<<<g128, 128, 0, stream>>>(bufB, ew2, eb2, nullptr, bufA, N, 128, 1);
    gemm_kernel<<<g128, 128, 0, stream>>>(bufC, cw2, cb2, types, bufA, N, 128, 2);

    // ---- GAT layers (out never aliases hl=bufB)
    // layer 0: h0 = relu(gat(h))            bufA -> bufA
    gat_layer<4>(bufA, lin0, as0, ad0, b0, nullptr, bufB, bufA,
                 a_s, a_d, rs, cnt, srclist, N, stream);
    // layer 1: h1 = h0 + relu(gat(h0))      bufA -> bufC
    gat_layer<4>(bufA, lin1, as1, ad1, b1, bufA, bufB, bufC,
                 a_s, a_d, rs, cnt, srclist, N, stream);
    // layer 2: h2 = h1 + relu(gat(h1))      bufC -> bufA  (1 head, mean=identity)
    gat_layer<1>(bufC, lin2, as2, ad2, b2, bufC, bufB, bufA,
                 a_s, a_d, rs, cnt, srclist, N, stream);

    // ---- decoder
    gemm_kernel<<<g128, 128, 0, stream>>>(bufA, dw1, db1, nullptr, bufC, N, 128, 1);
    gemm_kernel<<<g64, 128, 0, stream>>>(bufC, dw2, db2, nullptr, bufB, N, 64, 1);
    dec_final_kernel<<<(N + 3) / 4, 256, 0, stream>>>(bufB, types, dw3, db3,
                                                      (float*)d_out, N);
}

// Round 6
// 1495.882 us; speedup vs baseline: 3.6662x; 1.1273x over previous
//
#include <hip/hip_runtime.h>
#include <math.h>

#define HIDDEN 128
#define NEG_SLOPE 0.2f
#define LP 132   // LDS row pitch (floats): 128 + 4 pad

// ============ generic tiled GEMM: out[N,OUT] = op(X[N,128] @ W[OUT,128]^T) =====
// mode 0: raw     mode 1: relu(acc + bias)
// mode 2: relu(acc + bias) then select: type==0 -> keep prev(out), type==1 -> v, else 0
__global__ __launch_bounds__(128) void gemm_kernel(
        const float* __restrict__ X, const float* __restrict__ W,
        const float* __restrict__ bias, const int* __restrict__ types,
        float* __restrict__ out, int N, int OUT, int mode) {
    __shared__ float Xs[64 * LP];
    __shared__ float Ws[32 * LP];
    const int n0 = blockIdx.x * 64;
    const int oo = blockIdx.y * 32;
    const int tid = threadIdx.x;

#pragma unroll
    for (int r = 0; r < 16; r++) {
        int j = tid + 128 * r;
        int m = j >> 5, k4 = (j & 31) << 2;
        int n = n0 + m;
        float4 v = make_float4(0.f, 0.f, 0.f, 0.f);
        if (n < N) v = *(const float4*)&X[(size_t)n * 128 + k4];
        *(float4*)&Xs[m * LP + k4] = v;
    }
#pragma unroll
    for (int r = 0; r < 8; r++) {
        int j = tid + 128 * r;
        int o = j >> 5, k4 = (j & 31) << 2;
        *(float4*)&Ws[o * LP + k4] = *(const float4*)&W[(size_t)(oo + o) * 128 + k4];
    }
    __syncthreads();

    const int tm = tid & 15;
    const int to = tid >> 4;
    float acc[4][4] = {{0.f}};
#pragma unroll 4
    for (int kk = 0; kk < 128; kk += 4) {
        float4 xv[4], wv[4];
#pragma unroll
        for (int i = 0; i < 4; i++) xv[i] = *(float4*)&Xs[(4 * tm + i) * LP + kk];
#pragma unroll
        for (int j = 0; j < 4; j++) wv[j] = *(float4*)&Ws[(4 * to + j) * LP + kk];
#pragma unroll
        for (int i = 0; i < 4; i++)
#pragma unroll
            for (int j = 0; j < 4; j++)
                acc[i][j] += xv[i].x * wv[j].x + xv[i].y * wv[j].y +
                             xv[i].z * wv[j].z + xv[i].w * wv[j].w;
    }

    float4 bv = make_float4(0.f, 0.f, 0.f, 0.f);
    if (mode >= 1) bv = *(const float4*)&bias[oo + 4 * to];
#pragma unroll
    for (int i = 0; i < 4; i++) {
        int n = n0 + 4 * tm + i;
        if (n >= N) continue;
        size_t base = (size_t)n * OUT + oo + 4 * to;
        float v0 = acc[i][0], v1 = acc[i][1], v2 = acc[i][2], v3 = acc[i][3];
        if (mode >= 1) {
            v0 = fmaxf(v0 + bv.x, 0.f); v1 = fmaxf(v1 + bv.y, 0.f);
            v2 = fmaxf(v2 + bv.z, 0.f); v3 = fmaxf(v3 + bv.w, 0.f);
        }
        if (mode == 2) {
            int ty = types[n];
            if (ty == 0) {
                float4 pv = *(const float4*)&out[base];
                v0 = pv.x; v1 = pv.y; v2 = pv.z; v3 = pv.w;
            } else if (ty != 1) { v0 = v1 = v2 = v3 = 0.f; }
        }
        *(float4*)&out[base] = make_float4(v0, v1, v2, v3);
    }
}

// ============ encoder layer-1 (elementwise, both types) ========================
__global__ void enc_h1_kernel(const float* __restrict__ x,
                              const float* __restrict__ ew1, const float* __restrict__ eb1,
                              const float* __restrict__ cw1, const float* __restrict__ cb1,
                              float* __restrict__ h1_item, float* __restrict__ h1_con, int N) {
    int i = blockIdx.x * blockDim.x + threadIdx.x;
    if (i >= N * HIDDEN) return;
    int n = i >> 7, t = i & 127;
    float x0 = x[2 * n], x1 = x[2 * n + 1];
    h1_item[i] = fmaxf(ew1[2 * t] * x0 + ew1[2 * t + 1] * x1 + eb1[t], 0.f);
    h1_con[i]  = fmaxf(cw1[t] * x0 + cb1[t], 0.f);
}

// ============ attention dots ===================================================
template <int H>
__global__ void attn_dots_kernel(const float* __restrict__ hl,
                                 const float* __restrict__ att_s, const float* __restrict__ att_d,
                                 float* __restrict__ a_s, float* __restrict__ a_d, int N) {
    int n = blockIdx.x * 4 + (threadIdx.x >> 6);
    int l = threadIdx.x & 63;
    if (n >= N) return;
    float v1 = hl[(size_t)n * 128 + l];
    float v2 = hl[(size_t)n * 128 + 64 + l];
    float s1 = v1 * att_s[l], s2 = v2 * att_s[64 + l];
    float d1 = v1 * att_d[l], d2 = v2 * att_d[64 + l];
    if (H == 1) {
        float s = s1 + s2, d = d1 + d2;
#pragma unroll
        for (int off = 32; off; off >>= 1) {
            s += __shfl_down(s, off, 64);
            d += __shfl_down(d, off, 64);
        }
        if (l == 0) { a_s[n] = s; a_d[n] = d; }
    } else {
#pragma unroll
        for (int off = 16; off; off >>= 1) {
            s1 += __shfl_down(s1, off, 32); s2 += __shfl_down(s2, off, 32);
            d1 += __shfl_down(d1, off, 32); d2 += __shfl_down(d2, off, 32);
        }
        if ((l & 31) == 0) {
            int g = l >> 5;
            a_s[n * 4 + g]     = s1;  a_s[n * 4 + 2 + g] = s2;
            a_d[n * 4 + g]     = d1;  a_d[n * 4 + 2 + g] = d2;
        }
    }
}

// ============ CSR build ========================================================
__global__ void zero2_kernel(int* __restrict__ a, int* __restrict__ b, int N) {
    int i = blockIdx.x * blockDim.x + threadIdx.x;
    if (i < N) { a[i] = 0; b[i] = 0; }
}

__global__ void hist_kernel(const int* __restrict__ ei, int E, int E2, int* __restrict__ cnt) {
    int e = blockIdx.x * blockDim.x + threadIdx.x;
    if (e >= E2) return;
    int d = (e < E) ? ei[E + e] : e - E;
    atomicAdd(&cnt[d], 1);
}

__global__ void scan1_kernel(const int* __restrict__ cnt, int* __restrict__ rs,
                             int* __restrict__ bsum, int N) {
    __shared__ int s[256];
    int i = blockIdx.x * 256 + threadIdx.x;
    int v = (i < N) ? cnt[i] : 0;
    s[threadIdx.x] = v;
    __syncthreads();
    for (int off = 1; off < 256; off <<= 1) {
        int t = (threadIdx.x >= off) ? s[threadIdx.x - off] : 0;
        __syncthreads();
        s[threadIdx.x] += t;
        __syncthreads();
    }
    if (i < N) rs[i] = s[threadIdx.x];
    if (threadIdx.x == 255) bsum[blockIdx.x] = s[255];
}

__global__ void scan2_kernel(int* __restrict__ bsum, int nb) {
    __shared__ int s[1024];
    int i = threadIdx.x;
    int v = (i < nb) ? bsum[i] : 0;
    s[i] = v;
    __syncthreads();
    for (int off = 1; off < 1024; off <<= 1) {
        int t = (i >= off) ? s[i - off] : 0;
        __syncthreads();
        s[i] += t;
        __syncthreads();
    }
    if (i < nb) bsum[i] = s[i] - v;
}

__global__ void scan3_kernel(int* __restrict__ rs, const int* __restrict__ cnt,
                             const int* __restrict__ bsum, int N) {
    int i = blockIdx.x * 256 + threadIdx.x;
    if (i < N) rs[i] = rs[i] - cnt[i] + bsum[blockIdx.x];
}

__global__ void scatter_kernel(const int* __restrict__ ei, int E, int E2,
                               const int* __restrict__ rs, int* __restrict__ cursor,
                               int* __restrict__ srclist) {
    int e = blockIdx.x * blockDim.x + threadIdx.x;
    if (e >= E2) return;
    int s, d;
    if (e < E) { s = ei[e]; d = ei[E + e]; }
    else       { s = d = e - E; }
    int pos = atomicAdd(&cursor[d], 1);
    srclist[rs[d] + pos] = s;
}

// ============ attention coefficients: two-pass softmax per (node, head) ========
// writes unnormalized ex[edge*H+h] and dinv[n*H+h] = 1/denom
template <int H>
__global__ void att_kernel(const int* __restrict__ rs, const int* __restrict__ cnt,
                           const int* __restrict__ srclist,
                           const float* __restrict__ a_s, const float* __restrict__ a_d,
                           float* __restrict__ ex, float* __restrict__ dinv, int N) {
    int i = blockIdx.x * blockDim.x + threadIdx.x;
    if (i >= N * H) return;
    int n = (H == 1) ? i : (i >> 2);
    int h = (H == 1) ? 0 : (i & 3);
    int beg = rs[n], deg = cnt[n];
    float ad = a_d[i];
    float m = -INFINITY;
    for (int k = 0; k < deg; k++) {
        float al = a_s[srclist[beg + k] * H + h] + ad;
        al = (al > 0.f) ? al : NEG_SLOPE * al;
        m = fmaxf(m, al);
    }
    float l = 0.f;
    for (int k = 0; k < deg; k++) {
        float al = a_s[srclist[beg + k] * H + h] + ad;
        al = (al > 0.f) ? al : NEG_SLOPE * al;
        float p = expf(al - m);
        ex[(beg + k) * H + h] = p;
        l += p;
    }
    dinv[i] = 1.f / l;   // deg >= 1 (self-loop)
}

// ============ GAT aggregation: pure gather + fma ==============================
// NOTE: `out` must NEVER alias `hl` (cross-block reads of hl rows). out may
// alias X/res (each row touched only by its own node's thread group).
template <int H>
__global__ __launch_bounds__(256) void gat_agg_kernel(
        const int* __restrict__ rs, const int* __restrict__ cnt,
        const int* __restrict__ srclist, const float* __restrict__ hl,
        const float* __restrict__ ex, const float* __restrict__ dinv,
        const float* __restrict__ bias, const float* __restrict__ res,
        float* __restrict__ out, int N) {
    int n = blockIdx.x * 2 + (threadIdx.x >> 7);
    int f = threadIdx.x & 127;
    if (n >= N) return;
    const int hh = (H == 1) ? 0 : (f >> 5);    // C = 128/H = 32 for H=4
    const int beg = rs[n];
    const int deg = cnt[n];
    float acc0 = 0.f, acc1 = 0.f;
    int k = 0;
    for (; k + 1 < deg; k += 2) {
        int s0 = srclist[beg + k];
        int s1 = srclist[beg + k + 1];
        float p0 = ex[(beg + k) * H + hh];
        float p1 = ex[(beg + k + 1) * H + hh];
        acc0 += p0 * hl[(size_t)s0 * 128 + f];
        acc1 += p1 * hl[(size_t)s1 * 128 + f];
    }
    if (k < deg) {
        int s0 = srclist[beg + k];
        acc0 += ex[(beg + k) * H + hh] * hl[(size_t)s0 * 128 + f];
    }
    float v = fmaxf((acc0 + acc1) * dinv[n * H + hh] + bias[f], 0.f);
    if (res) v += res[(size_t)n * 128 + f];
    out[(size_t)n * 128 + f] = v;
}

// ============ decoder final dot + sigmoid + mask ==============================
__global__ void dec_final_kernel(const float* __restrict__ d2, const int* __restrict__ types,
                                 const float* __restrict__ dw3, const float* __restrict__ db3,
                                 float* __restrict__ out, int N) {
    int n = blockIdx.x * 4 + (threadIdx.x >> 6);
    int l = threadIdx.x & 63;
    if (n >= N) return;
    float p = d2[(size_t)n * 64 + l] * dw3[l];
#pragma unroll
    for (int off = 32; off; off >>= 1) p += __shfl_down(p, off, 64);
    if (l == 0) {
        float prob = 1.f / (1.f + expf(-(p + db3[0])));
        out[n] = (types[n] == 0) ? prob : 0.f;
    }
}

// ============ host-side layer driver ==========================================
template <int H>
static void gat_layer(const float* X, const float* lin, const float* as_, const float* ad_,
                      const float* bias, const float* res, float* hl, float* outb,
                      float* a_s, float* a_d, float* ex, float* dinv,
                      const int* rs, const int* cnt, const int* srclist,
                      int N, hipStream_t stream) {
    dim3 ggrid((N + 63) / 64, 4);
    gemm_kernel<<<ggrid, 128, 0, stream>>>(X, lin, nullptr, nullptr, hl, N, 128, 0);
    attn_dots_kernel<H><<<(N + 3) / 4, 256, 0, stream>>>(hl, as_, ad_, a_s, a_d, N);
    att_kernel<H><<<(N * H + 255) / 256, 256, 0, stream>>>(rs, cnt, srclist, a_s, a_d,
                                                           ex, dinv, N);
    gat_agg_kernel<H><<<(N + 1) / 2, 256, 0, stream>>>(rs, cnt, srclist, hl, ex, dinv,
                                                       bias, res, outb, N);
}

extern "C" void kernel_launch(void* const* d_in, const int* in_sizes, int n_in,
                              void* d_out, int out_size, void* d_ws, size_t ws_size,
                              hipStream_t stream) {
    const float* x     = (const float*)d_in[0];
    const int*   types = (const int*)d_in[1];
    const int*   ei    = (const int*)d_in[2];   // int64 in reference -> int32 on device
    const float* ew1 = (const float*)d_in[3];
    const float* eb1 = (const float*)d_in[4];
    const float* ew2 = (const float*)d_in[5];
    const float* eb2 = (const float*)d_in[6];
    const float* cw1 = (const float*)d_in[7];
    const float* cb1 = (const float*)d_in[8];
    const float* cw2 = (const float*)d_in[9];
    const float* cb2 = (const float*)d_in[10];
    const float* lin0 = (const float*)d_in[11];
    const float* as0  = (const float*)d_in[12];
    const float* ad0  = (const float*)d_in[13];
    const float* b0   = (const float*)d_in[14];
    const float* lin1 = (const float*)d_in[15];
    const float* as1  = (const float*)d_in[16];
    const float* ad1  = (const float*)d_in[17];
    const float* b1   = (const float*)d_in[18];
    const float* lin2 = (const float*)d_in[19];
    const float* as2  = (const float*)d_in[20];
    const float* ad2  = (const float*)d_in[21];
    const float* b2   = (const float*)d_in[22];
    const float* dw1 = (const float*)d_in[23];
    const float* db1 = (const float*)d_in[24];
    const float* dw2 = (const float*)d_in[25];
    const float* db2 = (const float*)d_in[26];
    const float* dw3 = (const float*)d_in[27];
    const float* db3 = (const float*)d_in[28];

    int N  = in_sizes[1];
    int E  = in_sizes[2] / 2;
    int E2 = E + N;

    float* ws = (float*)d_ws;
    size_t NF = (size_t)N * HIDDEN;
    float* bufA = ws;
    float* bufB = ws + NF;
    float* bufC = ws + 2 * NF;
    float* a_s  = ws + 3 * NF;
    float* a_d  = a_s + (size_t)N * 4;
    float* dinv = a_d + (size_t)N * 4;
    float* ex   = dinv + (size_t)N * 4;             // E2*4 floats
    int* rs      = (int*)(ex + (size_t)E2 * 4);
    int* cnt     = rs + N;
    int* cursor  = cnt + N;
    int* bsum    = cursor + N;          // up to 1024 entries
    int* srclist = bsum + 1024;         // E2 entries

    int nb = (N + 255) / 256;

    // ---- CSR build (edge structure shared by all 3 layers)
    zero2_kernel<<<nb, 256, 0, stream>>>(cnt, cursor, N);
    hist_kernel<<<(E2 + 255) / 256, 256, 0, stream>>>(ei, E, E2, cnt);
    scan1_kernel<<<nb, 256, 0, stream>>>(cnt, rs, bsum, N);
    scan2_kernel<<<1, 1024, 0, stream>>>(bsum, nb);
    scan3_kernel<<<nb, 256, 0, stream>>>(rs, cnt, bsum, N);
    scatter_kernel<<<(E2 + 255) / 256, 256, 0, stream>>>(ei, E, E2, rs, cursor, srclist);

    dim3 g128((N + 63) / 64, 4);
    dim3 g64((N + 63) / 64, 2);

    // ---- encoder -> bufA
    enc_h1_kernel<<<(N * HIDDEN + 255) / 256, 256, 0, stream>>>(x, ew1, eb1, cw1, cb1,
                                                               bufB, bufC, N);
    gemm_kernel<<<g128, 128, 0, stream>>>(bufB, ew2, eb2, nullptr, bufA, N, 128, 1);
    gemm_kernel<<<g128, 128, 0, stream>>>(bufC, cw2, cb2, types, bufA, N, 128, 2);

    // ---- GAT layers (out never aliases hl=bufB)
    // layer 0: h0 = relu(gat(h))            bufA -> bufA
    gat_layer<4>(bufA, lin0, as0, ad0, b0, nullptr, bufB, bufA,
                 a_s, a_d, ex, dinv, rs, cnt, srclist, N, stream);
    // layer 1: h1 = h0 + relu(gat(h0))      bufA -> bufC
    gat_layer<4>(bufA, lin1, as1, ad1, b1, bufA, bufB, bufC,
                 a_s, a_d, ex, dinv, rs, cnt, srclist, N, stream);
    // layer 2: h2 = h1 + relu(gat(h1))      bufC -> bufA  (1 head, mean=identity)
    gat_layer<1>(bufC, lin2, as2, ad2, b2, bufC, bufB, bufA,
                 a_s, a_d, ex, dinv, rs, cnt, srclist, N, stream);

    // ---- decoder
    gemm_kernel<<<g128, 128, 0, stream>>>(bufA, dw1, db1, nullptr, bufC, N, 128, 1);
    gemm_kernel<<<g64, 128, 0, stream>>>(bufC, dw2, db2, nullptr, bufB, N, 64, 1);
    dec_final_kernel<<<(N + 3) / 4, 256, 0, stream>>>(bufB, types, dw3, db3,
                                                      (float*)d_out, N);
}

// Round 7
// 987.953 us; speedup vs baseline: 5.5511x; 1.5141x over previous
//
#include <hip/hip_runtime.h>
#include <math.h>

#define HIDDEN 128
#define NEG_SLOPE 0.2f

typedef __attribute__((ext_vector_type(8))) short bf16x8;
typedef __attribute__((ext_vector_type(4))) float f32x4;

__device__ __forceinline__ unsigned short f2bf(float f) {
    unsigned u = __float_as_uint(f);
    unsigned r = (u + 0x7FFFu + ((u >> 16) & 1u)) >> 16;   // round-nearest-even
    return (unsigned short)r;
}

// ============ MFMA bf16 GEMM: out[N,OUT] = op(X[N,128] @ W[OUT,128]^T) ========
// mode 0: raw   mode 1: relu(acc+bias)
// mode 2: relu(acc+bias) then: type==0 -> keep prev(out), type==1 -> v, else 0
// LDS rows padded to 136 bf16 (272 B): frag reads 2-way bank aliased = free.
template <int OUT>
__global__ __launch_bounds__(256) void gemm_mfma_kernel(
        const float* __restrict__ X, const float* __restrict__ W,
        const float* __restrict__ bias, const int* __restrict__ types,
        float* __restrict__ out, int N, int mode) {
    constexpr int NT = OUT / 16;          // 16-col tiles
    __shared__ unsigned short Xs[64 * 136];
    __shared__ unsigned short Ws[OUT * 136];
    const int tid = threadIdx.x;
    const int n0 = blockIdx.x * 64;

    // stage X tile (64 rows x 128), fp32 -> bf16
#pragma unroll
    for (int r = 0; r < 8; r++) {
        int j = r * 256 + tid;
        int row = j >> 5, c4 = (j & 31) << 2;
        int n = n0 + row;
        float4 v = make_float4(0.f, 0.f, 0.f, 0.f);
        if (n < N) v = *(const float4*)&X[(size_t)n * 128 + c4];
        unsigned lo = f2bf(v.x) | ((unsigned)f2bf(v.y) << 16);
        unsigned hi = f2bf(v.z) | ((unsigned)f2bf(v.w) << 16);
        *(uint2*)&Xs[row * 136 + c4] = make_uint2(lo, hi);
    }
    // stage W (OUT rows x 128), fp32 -> bf16
#pragma unroll
    for (int r = 0; r < NT * 2; r++) {
        int j = r * 256 + tid;
        int row = j >> 5, c4 = (j & 31) << 2;
        float4 v = *(const float4*)&W[(size_t)row * 128 + c4];
        unsigned lo = f2bf(v.x) | ((unsigned)f2bf(v.y) << 16);
        unsigned hi = f2bf(v.z) | ((unsigned)f2bf(v.w) << 16);
        *(uint2*)&Ws[row * 136 + c4] = make_uint2(lo, hi);
    }
    __syncthreads();

    const int w = tid >> 6, lane = tid & 63;
    const int qd = lane >> 4, lr = lane & 15;

    f32x4 acc[NT];
#pragma unroll
    for (int j = 0; j < NT; j++) acc[j] = (f32x4){0.f, 0.f, 0.f, 0.f};

#pragma unroll
    for (int k = 0; k < 4; k++) {
        bf16x8 a = *(const bf16x8*)&Xs[(w * 16 + lr) * 136 + k * 32 + qd * 8];
#pragma unroll
        for (int j = 0; j < NT; j++) {
            bf16x8 b = *(const bf16x8*)&Ws[(j * 16 + lr) * 136 + k * 32 + qd * 8];
            acc[j] = __builtin_amdgcn_mfma_f32_16x16x32_bf16(a, b, acc[j], 0, 0, 0);
        }
    }

    // epilogue: D mapping col=lane&15, row=(lane>>4)*4+reg
#pragma unroll
    for (int r = 0; r < 4; r++) {
        int row = n0 + w * 16 + qd * 4 + r;
        if (row >= N) continue;
        int ty = (mode == 2) ? types[row] : 0;
#pragma unroll
        for (int j = 0; j < NT; j++) {
            int col = j * 16 + lr;
            float v = acc[j][r];
            if (mode >= 1) v = fmaxf(v + bias[col], 0.f);
            size_t base = (size_t)row * OUT + col;
            if (mode == 2) {
                if (ty == 0) v = out[base];
                else if (ty != 1) v = 0.f;
            }
            out[base] = v;
        }
    }
}

// ============ encoder layer-1 (elementwise, both types) ========================
__global__ void enc_h1_kernel(const float* __restrict__ x,
                              const float* __restrict__ ew1, const float* __restrict__ eb1,
                              const float* __restrict__ cw1, const float* __restrict__ cb1,
                              float* __restrict__ h1_item, float* __restrict__ h1_con, int N) {
    int i = blockIdx.x * blockDim.x + threadIdx.x;
    if (i >= N * HIDDEN) return;
    int n = i >> 7, t = i & 127;
    float x0 = x[2 * n], x1 = x[2 * n + 1];
    h1_item[i] = fmaxf(ew1[2 * t] * x0 + ew1[2 * t + 1] * x1 + eb1[t], 0.f);
    h1_con[i]  = fmaxf(cw1[t] * x0 + cb1[t], 0.f);
}

// ============ attention dots ===================================================
template <int H>
__global__ void attn_dots_kernel(const float* __restrict__ hl,
                                 const float* __restrict__ att_s, const float* __restrict__ att_d,
                                 float* __restrict__ a_s, float* __restrict__ a_d, int N) {
    int n = blockIdx.x * 4 + (threadIdx.x >> 6);
    int l = threadIdx.x & 63;
    if (n >= N) return;
    float v1 = hl[(size_t)n * 128 + l];
    float v2 = hl[(size_t)n * 128 + 64 + l];
    float s1 = v1 * att_s[l], s2 = v2 * att_s[64 + l];
    float d1 = v1 * att_d[l], d2 = v2 * att_d[64 + l];
    if (H == 1) {
        float s = s1 + s2, d = d1 + d2;
#pragma unroll
        for (int off = 32; off; off >>= 1) {
            s += __shfl_down(s, off, 64);
            d += __shfl_down(d, off, 64);
        }
        if (l == 0) { a_s[n] = s; a_d[n] = d; }
    } else {
#pragma unroll
        for (int off = 16; off; off >>= 1) {
            s1 += __shfl_down(s1, off, 32); s2 += __shfl_down(s2, off, 32);
            d1 += __shfl_down(d1, off, 32); d2 += __shfl_down(d2, off, 32);
        }
        if ((l & 31) == 0) {
            int g = l >> 5;
            a_s[n * 4 + g]     = s1;  a_s[n * 4 + 2 + g] = s2;
            a_d[n * 4 + g]     = d1;  a_d[n * 4 + 2 + g] = d2;
        }
    }
}

// ============ CSR build ========================================================
__global__ void zero2_kernel(int* __restrict__ a, int* __restrict__ b, int N) {
    int i = blockIdx.x * blockDim.x + threadIdx.x;
    if (i < N) { a[i] = 0; b[i] = 0; }
}

__global__ void hist_kernel(const int* __restrict__ ei, int E, int E2, int* __restrict__ cnt) {
    int e = blockIdx.x * blockDim.x + threadIdx.x;
    if (e >= E2) return;
    int d = (e < E) ? ei[E + e] : e - E;
    atomicAdd(&cnt[d], 1);
}

__global__ void scan1_kernel(const int* __restrict__ cnt, int* __restrict__ rs,
                             int* __restrict__ bsum, int N) {
    __shared__ int s[256];
    int i = blockIdx.x * 256 + threadIdx.x;
    int v = (i < N) ? cnt[i] : 0;
    s[threadIdx.x] = v;
    __syncthreads();
    for (int off = 1; off < 256; off <<= 1) {
        int t = (threadIdx.x >= off) ? s[threadIdx.x - off] : 0;
        __syncthreads();
        s[threadIdx.x] += t;
        __syncthreads();
    }
    if (i < N) rs[i] = s[threadIdx.x];
    if (threadIdx.x == 255) bsum[blockIdx.x] = s[255];
}

__global__ void scan2_kernel(int* __restrict__ bsum, int nb) {
    __shared__ int s[1024];
    int i = threadIdx.x;
    int v = (i < nb) ? bsum[i] : 0;
    s[i] = v;
    __syncthreads();
    for (int off = 1; off < 1024; off <<= 1) {
        int t = (i >= off) ? s[i - off] : 0;
        __syncthreads();
        s[i] += t;
        __syncthreads();
    }
    if (i < nb) bsum[i] = s[i] - v;
}

__global__ void scan3_kernel(int* __restrict__ rs, const int* __restrict__ cnt,
                             const int* __restrict__ bsum, int N) {
    int i = blockIdx.x * 256 + threadIdx.x;
    if (i < N) rs[i] = rs[i] - cnt[i] + bsum[blockIdx.x];
}

__global__ void scatter_kernel(const int* __restrict__ ei, int E, int E2,
                               const int* __restrict__ rs, int* __restrict__ cursor,
                               int* __restrict__ srclist) {
    int e = blockIdx.x * blockDim.x + threadIdx.x;
    if (e >= E2) return;
    int s, d;
    if (e < E) { s = ei[e]; d = ei[E + e]; }
    else       { s = d = e - E; }
    int pos = atomicAdd(&cursor[d], 1);
    srclist[rs[d] + pos] = s;
}

// ============ attention coefficients: two-pass softmax per (node, head) ========
template <int H>
__global__ void att_kernel(const int* __restrict__ rs, const int* __restrict__ cnt,
                           const int* __restrict__ srclist,
                           const float* __restrict__ a_s, const float* __restrict__ a_d,
                           float* __restrict__ ex, float* __restrict__ dinv, int N) {
    int i = blockIdx.x * blockDim.x + threadIdx.x;
    if (i >= N * H) return;
    int n = (H == 1) ? i : (i >> 2);
    int h = (H == 1) ? 0 : (i & 3);
    int beg = rs[n], deg = cnt[n];
    float ad = a_d[i];
    float m = -INFINITY;
    for (int k = 0; k < deg; k++) {
        float al = a_s[srclist[beg + k] * H + h] + ad;
        al = (al > 0.f) ? al : NEG_SLOPE * al;
        m = fmaxf(m, al);
    }
    float l = 0.f;
    for (int k = 0; k < deg; k++) {
        float al = a_s[srclist[beg + k] * H + h] + ad;
        al = (al > 0.f) ? al : NEG_SLOPE * al;
        float p = expf(al - m);
        ex[(beg + k) * H + h] = p;
        l += p;
    }
    dinv[i] = 1.f / l;   // deg >= 1 (self-loop)
}

// ============ GAT aggregation: pure gather + fma ==============================
// NOTE: `out` must NEVER alias `hl` (cross-block reads of hl rows).
template <int H>
__global__ __launch_bounds__(256) void gat_agg_kernel(
        const int* __restrict__ rs, const int* __restrict__ cnt,
        const int* __restrict__ srclist, const float* __restrict__ hl,
        const float* __restrict__ ex, const float* __restrict__ dinv,
        const float* __restrict__ bias, const float* __restrict__ res,
        float* __restrict__ out, int N) {
    int n = blockIdx.x * 2 + (threadIdx.x >> 7);
    int f = threadIdx.x & 127;
    if (n >= N) return;
    const int hh = (H == 1) ? 0 : (f >> 5);
    const int beg = rs[n];
    const int deg = cnt[n];
    float acc0 = 0.f, acc1 = 0.f;
    int k = 0;
    for (; k + 1 < deg; k += 2) {
        int s0 = srclist[beg + k];
        int s1 = srclist[beg + k + 1];
        float p0 = ex[(beg + k) * H + hh];
        float p1 = ex[(beg + k + 1) * H + hh];
        acc0 += p0 * hl[(size_t)s0 * 128 + f];
        acc1 += p1 * hl[(size_t)s1 * 128 + f];
    }
    if (k < deg) {
        int s0 = srclist[beg + k];
        acc0 += ex[(beg + k) * H + hh] * hl[(size_t)s0 * 128 + f];
    }
    float v = fmaxf((acc0 + acc1) * dinv[n * H + hh] + bias[f], 0.f);
    if (res) v += res[(size_t)n * 128 + f];
    out[(size_t)n * 128 + f] = v;
}

// ============ decoder final dot + sigmoid + mask ==============================
__global__ void dec_final_kernel(const float* __restrict__ d2, const int* __restrict__ types,
                                 const float* __restrict__ dw3, const float* __restrict__ db3,
                                 float* __restrict__ out, int N) {
    int n = blockIdx.x * 4 + (threadIdx.x >> 6);
    int l = threadIdx.x & 63;
    if (n >= N) return;
    float p = d2[(size_t)n * 64 + l] * dw3[l];
#pragma unroll
    for (int off = 32; off; off >>= 1) p += __shfl_down(p, off, 64);
    if (l == 0) {
        float prob = 1.f / (1.f + expf(-(p + db3[0])));
        out[n] = (types[n] == 0) ? prob : 0.f;
    }
}

// ============ host-side layer driver ==========================================
template <int H>
static void gat_layer(const float* X, const float* lin, const float* as_, const float* ad_,
                      const float* bias, const float* res, float* hl, float* outb,
                      float* a_s, float* a_d, float* ex, float* dinv,
                      const int* rs, const int* cnt, const int* srclist,
                      int N, hipStream_t stream) {
    int gx = (N + 63) / 64;
    gemm_mfma_kernel<128><<<gx, 256, 0, stream>>>(X, lin, nullptr, nullptr, hl, N, 0);
    attn_dots_kernel<H><<<(N + 3) / 4, 256, 0, stream>>>(hl, as_, ad_, a_s, a_d, N);
    att_kernel<H><<<(N * H + 255) / 256, 256, 0, stream>>>(rs, cnt, srclist, a_s, a_d,
                                                           ex, dinv, N);
    gat_agg_kernel<H><<<(N + 1) / 2, 256, 0, stream>>>(rs, cnt, srclist, hl, ex, dinv,
                                                       bias, res, outb, N);
}

extern "C" void kernel_launch(void* const* d_in, const int* in_sizes, int n_in,
                              void* d_out, int out_size, void* d_ws, size_t ws_size,
                              hipStream_t stream) {
    const float* x     = (const float*)d_in[0];
    const int*   types = (const int*)d_in[1];
    const int*   ei    = (const int*)d_in[2];   // int64 in reference -> int32 on device
    const float* ew1 = (const float*)d_in[3];
    const float* eb1 = (const float*)d_in[4];
    const float* ew2 = (const float*)d_in[5];
    const float* eb2 = (const float*)d_in[6];
    const float* cw1 = (const float*)d_in[7];
    const float* cb1 = (const float*)d_in[8];
    const float* cw2 = (const float*)d_in[9];
    const float* cb2 = (const float*)d_in[10];
    const float* lin0 = (const float*)d_in[11];
    const float* as0  = (const float*)d_in[12];
    const float* ad0  = (const float*)d_in[13];
    const float* b0   = (const float*)d_in[14];
    const float* lin1 = (const float*)d_in[15];
    const float* as1  = (const float*)d_in[16];
    const float* ad1  = (const float*)d_in[17];
    const float* b1   = (const float*)d_in[18];
    const float* lin2 = (const float*)d_in[19];
    const float* as2  = (const float*)d_in[20];
    const float* ad2  = (const float*)d_in[21];
    const float* b2   = (const float*)d_in[22];
    const float* dw1 = (const float*)d_in[23];
    const float* db1 = (const float*)d_in[24];
    const float* dw2 = (const float*)d_in[25];
    const float* db2 = (const float*)d_in[26];
    const float* dw3 = (const float*)d_in[27];
    const float* db3 = (const float*)d_in[28];

    int N  = in_sizes[1];
    int E  = in_sizes[2] / 2;
    int E2 = E + N;

    float* ws = (float*)d_ws;
    size_t NF = (size_t)N * HIDDEN;
    float* bufA = ws;
    float* bufB = ws + NF;
    float* bufC = ws + 2 * NF;
    float* a_s  = ws + 3 * NF;
    float* a_d  = a_s + (size_t)N * 4;
    float* dinv = a_d + (size_t)N * 4;
    float* ex   = dinv + (size_t)N * 4;             // E2*4 floats
    int* rs      = (int*)(ex + (size_t)E2 * 4);
    int* cnt     = rs + N;
    int* cursor  = cnt + N;
    int* bsum    = cursor + N;          // up to 1024 entries
    int* srclist = bsum + 1024;         // E2 entries

    int nb = (N + 255) / 256;

    // ---- CSR build (edge structure shared by all 3 layers)
    zero2_kernel<<<nb, 256, 0, stream>>>(cnt, cursor, N);
    hist_kernel<<<(E2 + 255) / 256, 256, 0, stream>>>(ei, E, E2, cnt);
    scan1_kernel<<<nb, 256, 0, stream>>>(cnt, rs, bsum, N);
    scan2_kernel<<<1, 1024, 0, stream>>>(bsum, nb);
    scan3_kernel<<<nb, 256, 0, stream>>>(rs, cnt, bsum, N);
    scatter_kernel<<<(E2 + 255) / 256, 256, 0, stream>>>(ei, E, E2, rs, cursor, srclist);

    int gx = (N + 63) / 64;

    // ---- encoder -> bufA
    enc_h1_kernel<<<(N * HIDDEN + 255) / 256, 256, 0, stream>>>(x, ew1, eb1, cw1, cb1,
                                                               bufB, bufC, N);
    gemm_mfma_kernel<128><<<gx, 256, 0, stream>>>(bufB, ew2, eb2, nullptr, bufA, N, 1);
    gemm_mfma_kernel<128><<<gx, 256, 0, stream>>>(bufC, cw2, cb2, types, bufA, N, 2);

    // ---- GAT layers (out never aliases hl=bufB)
    // layer 0: h0 = relu(gat(h))            bufA -> bufA
    gat_layer<4>(bufA, lin0, as0, ad0, b0, nullptr, bufB, bufA,
                 a_s, a_d, ex, dinv, rs, cnt, srclist, N, stream);
    // layer 1: h1 = h0 + relu(gat(h0))      bufA -> bufC
    gat_layer<4>(bufA, lin1, as1, ad1, b1, bufA, bufB, bufC,
                 a_s, a_d, ex, dinv, rs, cnt, srclist, N, stream);
    // layer 2: h2 = h1 + relu(gat(h1))      bufC -> bufA  (1 head, mean=identity)
    gat_layer<1>(bufC, lin2, as2, ad2, b2, bufC, bufB, bufA,
                 a_s, a_d, ex, dinv, rs, cnt, srclist, N, stream);

    // ---- decoder
    gemm_mfma_kernel<128><<<gx, 256, 0, stream>>>(bufA, dw1, db1, nullptr, bufC, N, 1);
    gemm_mfma_kernel<64><<<gx, 256, 0, stream>>>(bufC, dw2, db2, nullptr, bufB, N, 1);
    dec_final_kernel<<<(N + 3) / 4, 256, 0, stream>>>(bufB, types, dw3, db3,
                                                      (float*)d_out, N);
}

// Round 8
// 703.160 us; speedup vs baseline: 7.7995x; 1.4050x over previous
//
#include <hip/hip_runtime.h>
#include <math.h>

#define HIDDEN 128
#define NEG_SLOPE 0.2f

typedef unsigned short u16;
typedef __attribute__((ext_vector_type(8))) short bf16x8;
typedef __attribute__((ext_vector_type(4))) float f32x4;

__device__ __forceinline__ u16 f2bf(float f) {
    unsigned u = __float_as_uint(f);
    unsigned r = (u + 0x7FFFu + ((u >> 16) & 1u)) >> 16;   // round-nearest-even
    return (u16)r;
}
__device__ __forceinline__ float bf2f(u16 u) {
    return __uint_as_float((unsigned)u << 16);
}
__device__ __forceinline__ unsigned pack2(float a, float b) {
    return (unsigned)f2bf(a) | ((unsigned)f2bf(b) << 16);
}

// ============ MFMA bf16 GEMM: out[N,OUT] = op(X[N,128] @ W[OUT,128]^T) ========
// X is bf16 [N,128]; W fp32 [OUT,128]; out bf16 [N,OUT].
// mode 0: raw   mode 1: relu(acc+bias)
// mode 2: relu(acc+bias) then: type==0 -> keep prev(out), type==1 -> v, else 0
template <int OUT>
__global__ __launch_bounds__(256) void gemm_mfma_kernel(
        const u16* __restrict__ X, const float* __restrict__ W,
        const float* __restrict__ bias, const int* __restrict__ types,
        u16* __restrict__ out, int N, int mode) {
    constexpr int NT = OUT / 16;
    __shared__ u16 Xs[64 * 136];
    __shared__ u16 Ws[OUT * 136];
    const int tid = threadIdx.x;
    const int n0 = blockIdx.x * 64;

    // stage X tile (64 rows x 128 bf16): straight 16B copies
#pragma unroll
    for (int r = 0; r < 4; r++) {
        int j = r * 256 + tid;            // 1024 chunks of 8 ushorts
        int row = j >> 4, c8 = (j & 15) << 3;
        int n = n0 + row;
        uint4 v = make_uint4(0u, 0u, 0u, 0u);
        if (n < N) v = *(const uint4*)&X[(size_t)n * 128 + c8];
        *(uint4*)&Xs[row * 136 + c8] = v;
    }
    // stage W (OUT rows x 128), fp32 -> bf16
#pragma unroll
    for (int r = 0; r < NT * 2; r++) {
        int j = r * 256 + tid;
        int row = j >> 5, c4 = (j & 31) << 2;
        float4 v = *(const float4*)&W[(size_t)row * 128 + c4];
        *(uint2*)&Ws[row * 136 + c4] = make_uint2(pack2(v.x, v.y), pack2(v.z, v.w));
    }
    __syncthreads();

    const int w = tid >> 6, lane = tid & 63;
    const int qd = lane >> 4, lr = lane & 15;

    f32x4 acc[NT];
#pragma unroll
    for (int j = 0; j < NT; j++) acc[j] = (f32x4){0.f, 0.f, 0.f, 0.f};

#pragma unroll
    for (int k = 0; k < 4; k++) {
        bf16x8 a = *(const bf16x8*)&Xs[(w * 16 + lr) * 136 + k * 32 + qd * 8];
#pragma unroll
        for (int j = 0; j < NT; j++) {
            bf16x8 b = *(const bf16x8*)&Ws[(j * 16 + lr) * 136 + k * 32 + qd * 8];
            acc[j] = __builtin_amdgcn_mfma_f32_16x16x32_bf16(a, b, acc[j], 0, 0, 0);
        }
    }

    // epilogue: D mapping col=lane&15, row=(lane>>4)*4+reg
#pragma unroll
    for (int r = 0; r < 4; r++) {
        int row = n0 + w * 16 + qd * 4 + r;
        if (row >= N) continue;
        int ty = (mode == 2) ? types[row] : 0;
        if (mode == 2 && ty == 0) continue;   // keep item value written earlier
#pragma unroll
        for (int j = 0; j < NT; j++) {
            int col = j * 16 + lr;
            float v = acc[j][r];
            if (mode >= 1) v = fmaxf(v + bias[col], 0.f);
            if (mode == 2 && ty != 1) v = 0.f;
            out[(size_t)row * OUT + col] = f2bf(v);
        }
    }
}

// ============ encoder layer-1 (elementwise, both types, bf16 out) =============
__global__ void enc_h1_kernel(const float* __restrict__ x,
                              const float* __restrict__ ew1, const float* __restrict__ eb1,
                              const float* __restrict__ cw1, const float* __restrict__ cb1,
                              u16* __restrict__ h1_item, u16* __restrict__ h1_con, int N) {
    int i = blockIdx.x * blockDim.x + threadIdx.x;
    if (i >= N * 64) return;
    int n = i >> 6, t = (i & 63) * 2;
    float x0 = x[2 * n], x1 = x[2 * n + 1];
    float i0 = fmaxf(ew1[2 * t] * x0 + ew1[2 * t + 1] * x1 + eb1[t], 0.f);
    float i1 = fmaxf(ew1[2 * t + 2] * x0 + ew1[2 * t + 3] * x1 + eb1[t + 1], 0.f);
    float c0 = fmaxf(cw1[t] * x0 + cb1[t], 0.f);
    float c1 = fmaxf(cw1[t + 1] * x0 + cb1[t + 1], 0.f);
    *(unsigned*)&h1_item[(size_t)n * 128 + t] = pack2(i0, i1);
    *(unsigned*)&h1_con[(size_t)n * 128 + t]  = pack2(c0, c1);
}

// ============ attention dots (bf16 hl) =========================================
template <int H>
__global__ void attn_dots_kernel(const u16* __restrict__ hl,
                                 const float* __restrict__ att_s, const float* __restrict__ att_d,
                                 float* __restrict__ a_s, float* __restrict__ a_d, int N) {
    int n = blockIdx.x * 4 + (threadIdx.x >> 6);
    int l = threadIdx.x & 63;
    if (n >= N) return;
    unsigned v = *(const unsigned*)&hl[(size_t)n * 128 + 2 * l];
    float f0 = bf2f((u16)v), f1 = bf2f((u16)(v >> 16));
    float s = f0 * att_s[2 * l] + f1 * att_s[2 * l + 1];
    float d = f0 * att_d[2 * l] + f1 * att_d[2 * l + 1];
    if (H == 1) {
#pragma unroll
        for (int m = 1; m < 64; m <<= 1) {
            s += __shfl_xor(s, m, 64);
            d += __shfl_xor(d, m, 64);
        }
        if (l == 0) { a_s[n] = s; a_d[n] = d; }
    } else {  // H=4: features 2l,2l+1 in head l>>4; reduce within 16-lane groups
#pragma unroll
        for (int m = 1; m < 16; m <<= 1) {
            s += __shfl_xor(s, m, 64);
            d += __shfl_xor(d, m, 64);
        }
        if ((l & 15) == 0) {
            int g = l >> 4;
            a_s[n * 4 + g] = s;
            a_d[n * 4 + g] = d;
        }
    }
}

// ============ CSR build ========================================================
__global__ void zero2_kernel(int* __restrict__ a, int* __restrict__ b, int N) {
    int i = blockIdx.x * blockDim.x + threadIdx.x;
    if (i < N) { a[i] = 0; b[i] = 0; }
}

__global__ void hist_kernel(const int* __restrict__ ei, int E, int E2, int* __restrict__ cnt) {
    int e = blockIdx.x * blockDim.x + threadIdx.x;
    if (e >= E2) return;
    int d = (e < E) ? ei[E + e] : e - E;
    atomicAdd(&cnt[d], 1);
}

__global__ void scan1_kernel(const int* __restrict__ cnt, int* __restrict__ rs,
                             int* __restrict__ bsum, int N) {
    __shared__ int s[256];
    int i = blockIdx.x * 256 + threadIdx.x;
    int v = (i < N) ? cnt[i] : 0;
    s[threadIdx.x] = v;
    __syncthreads();
    for (int off = 1; off < 256; off <<= 1) {
        int t = (threadIdx.x >= off) ? s[threadIdx.x - off] : 0;
        __syncthreads();
        s[threadIdx.x] += t;
        __syncthreads();
    }
    if (i < N) rs[i] = s[threadIdx.x];
    if (threadIdx.x == 255) bsum[blockIdx.x] = s[255];
}

__global__ void scan2_kernel(int* __restrict__ bsum, int nb) {
    __shared__ int s[1024];
    int i = threadIdx.x;
    int v = (i < nb) ? bsum[i] : 0;
    s[i] = v;
    __syncthreads();
    for (int off = 1; off < 1024; off <<= 1) {
        int t = (i >= off) ? s[i - off] : 0;
        __syncthreads();
        s[i] += t;
        __syncthreads();
    }
    if (i < nb) bsum[i] = s[i] - v;
}

__global__ void scan3_kernel(int* __restrict__ rs, const int* __restrict__ cnt,
                             const int* __restrict__ bsum, int N) {
    int i = blockIdx.x * 256 + threadIdx.x;
    if (i < N) rs[i] = rs[i] - cnt[i] + bsum[blockIdx.x];
}

__global__ void scatter_kernel(const int* __restrict__ ei, int E, int E2,
                               const int* __restrict__ rs, int* __restrict__ cursor,
                               int* __restrict__ srclist) {
    int e = blockIdx.x * blockDim.x + threadIdx.x;
    if (e >= E2) return;
    int s, d;
    if (e < E) { s = ei[e]; d = ei[E + e]; }
    else       { s = d = e - E; }
    int pos = atomicAdd(&cursor[d], 1);
    srclist[rs[d] + pos] = s;
}

// ============ attention coefficients: two-pass softmax per (node, head) ========
template <int H>
__global__ void att_kernel(const int* __restrict__ rs, const int* __restrict__ cnt,
                           const int* __restrict__ srclist,
                           const float* __restrict__ a_s, const float* __restrict__ a_d,
                           float* __restrict__ ex, float* __restrict__ dinv, int N) {
    int i = blockIdx.x * blockDim.x + threadIdx.x;
    if (i >= N * H) return;
    int n = (H == 1) ? i : (i >> 2);
    int h = (H == 1) ? 0 : (i & 3);
    int beg = rs[n], deg = cnt[n];
    float ad = a_d[i];
    float m = -INFINITY;
    for (int k = 0; k < deg; k++) {
        float al = a_s[srclist[beg + k] * H + h] + ad;
        al = (al > 0.f) ? al : NEG_SLOPE * al;
        m = fmaxf(m, al);
    }
    float l = 0.f;
    for (int k = 0; k < deg; k++) {
        float al = a_s[srclist[beg + k] * H + h] + ad;
        al = (al > 0.f) ? al : NEG_SLOPE * al;
        float p = expf(al - m);
        ex[(beg + k) * H + h] = p;
        l += p;
    }
    dinv[i] = 1.f / l;   // deg >= 1 (self-loop)
}

// ============ GAT aggregation: bf16 gather + fma ==============================
// block = 4 nodes x 64 lanes; lane l handles features {2l, 2l+1} (ushort2 load)
// NOTE: `out` must NEVER alias `hl`.
template <int H>
__global__ __launch_bounds__(256) void gat_agg_kernel(
        const int* __restrict__ rs, const int* __restrict__ cnt,
        const int* __restrict__ srclist, const u16* __restrict__ hl,
        const float* __restrict__ ex, const float* __restrict__ dinv,
        const float* __restrict__ bias, const u16* __restrict__ res,
        u16* __restrict__ out, int N) {
    int n = blockIdx.x * 4 + (threadIdx.x >> 6);
    int l = threadIdx.x & 63;
    if (n >= N) return;
    const int hh = (H == 1) ? 0 : (l >> 4);   // head of features 2l,2l+1
    const int beg = rs[n];
    const int deg = cnt[n];
    float a00 = 0.f, a01 = 0.f, a10 = 0.f, a11 = 0.f;
    int k = 0;
    for (; k + 1 < deg; k += 2) {
        int s0 = srclist[beg + k];
        int s1 = srclist[beg + k + 1];
        float p0 = ex[(beg + k) * H + hh];
        float p1 = ex[(beg + k + 1) * H + hh];
        unsigned v0 = *(const unsigned*)&hl[(size_t)s0 * 128 + 2 * l];
        unsigned v1 = *(const unsigned*)&hl[(size_t)s1 * 128 + 2 * l];
        a00 += p0 * bf2f((u16)v0); a01 += p0 * bf2f((u16)(v0 >> 16));
        a10 += p1 * bf2f((u16)v1); a11 += p1 * bf2f((u16)(v1 >> 16));
    }
    if (k < deg) {
        int s0 = srclist[beg + k];
        float p0 = ex[(beg + k) * H + hh];
        unsigned v0 = *(const unsigned*)&hl[(size_t)s0 * 128 + 2 * l];
        a00 += p0 * bf2f((u16)v0); a01 += p0 * bf2f((u16)(v0 >> 16));
    }
    float di = dinv[n * H + hh];
    float o0 = fmaxf((a00 + a10) * di + bias[2 * l], 0.f);
    float o1 = fmaxf((a01 + a11) * di + bias[2 * l + 1], 0.f);
    if (res) {
        unsigned rv = *(const unsigned*)&res[(size_t)n * 128 + 2 * l];
        o0 += bf2f((u16)rv);
        o1 += bf2f((u16)(rv >> 16));
    }
    *(unsigned*)&out[(size_t)n * 128 + 2 * l] = pack2(o0, o1);
}

// ============ decoder final dot + sigmoid + mask ==============================
__global__ void dec_final_kernel(const u16* __restrict__ d2, const int* __restrict__ types,
                                 const float* __restrict__ dw3, const float* __restrict__ db3,
                                 float* __restrict__ out, int N) {
    int n = blockIdx.x * 4 + (threadIdx.x >> 6);
    int l = threadIdx.x & 63;
    if (n >= N) return;
    float p = bf2f(d2[(size_t)n * 64 + l]) * dw3[l];
#pragma unroll
    for (int off = 32; off; off >>= 1) p += __shfl_down(p, off, 64);
    if (l == 0) {
        float prob = 1.f / (1.f + expf(-(p + db3[0])));
        out[n] = (types[n] == 0) ? prob : 0.f;
    }
}

// ============ host-side layer driver ==========================================
template <int H>
static void gat_layer(const u16* X, const float* lin, const float* as_, const float* ad_,
                      const float* bias, const u16* res, u16* hl, u16* outb,
                      float* a_s, float* a_d, float* ex, float* dinv,
                      const int* rs, const int* cnt, const int* srclist,
                      int N, hipStream_t stream) {
    int gx = (N + 63) / 64;
    gemm_mfma_kernel<128><<<gx, 256, 0, stream>>>(X, lin, nullptr, nullptr, hl, N, 0);
    attn_dots_kernel<H><<<(N + 3) / 4, 256, 0, stream>>>(hl, as_, ad_, a_s, a_d, N);
    att_kernel<H><<<(N * H + 255) / 256, 256, 0, stream>>>(rs, cnt, srclist, a_s, a_d,
                                                           ex, dinv, N);
    gat_agg_kernel<H><<<(N + 3) / 4, 256, 0, stream>>>(rs, cnt, srclist, hl, ex, dinv,
                                                       bias, res, outb, N);
}

extern "C" void kernel_launch(void* const* d_in, const int* in_sizes, int n_in,
                              void* d_out, int out_size, void* d_ws, size_t ws_size,
                              hipStream_t stream) {
    const float* x     = (const float*)d_in[0];
    const int*   types = (const int*)d_in[1];
    const int*   ei    = (const int*)d_in[2];   // int64 in reference -> int32 on device
    const float* ew1 = (const float*)d_in[3];
    const float* eb1 = (const float*)d_in[4];
    const float* ew2 = (const float*)d_in[5];
    const float* eb2 = (const float*)d_in[6];
    const float* cw1 = (const float*)d_in[7];
    const float* cb1 = (const float*)d_in[8];
    const float* cw2 = (const float*)d_in[9];
    const float* cb2 = (const float*)d_in[10];
    const float* lin0 = (const float*)d_in[11];
    const float* as0  = (const float*)d_in[12];
    const float* ad0  = (const float*)d_in[13];
    const float* b0   = (const float*)d_in[14];
    const float* lin1 = (const float*)d_in[15];
    const float* as1  = (const float*)d_in[16];
    const float* ad1  = (const float*)d_in[17];
    const float* b1   = (const float*)d_in[18];
    const float* lin2 = (const float*)d_in[19];
    const float* as2  = (const float*)d_in[20];
    const float* ad2  = (const float*)d_in[21];
    const float* b2   = (const float*)d_in[22];
    const float* dw1 = (const float*)d_in[23];
    const float* db1 = (const float*)d_in[24];
    const float* dw2 = (const float*)d_in[25];
    const float* db2 = (const float*)d_in[26];
    const float* dw3 = (const float*)d_in[27];
    const float* db3 = (const float*)d_in[28];

    int N  = in_sizes[1];
    int E  = in_sizes[2] / 2;
    int E2 = E + N;

    size_t NF = (size_t)N * HIDDEN;
    u16* bufA = (u16*)d_ws;          // bf16 feature buffers
    u16* bufB = bufA + NF;
    u16* bufC = bufB + NF;
    float* fbase = (float*)(bufC + NF);   // 16B-aligned (NF*2 bytes each, N*256)
    float* a_s  = fbase;
    float* a_d  = a_s + (size_t)N * 4;
    float* dinv = a_d + (size_t)N * 4;
    float* ex   = dinv + (size_t)N * 4;             // E2*4 floats
    int* rs      = (int*)(ex + (size_t)E2 * 4);
    int* cnt     = rs + N;
    int* cursor  = cnt + N;
    int* bsum    = cursor + N;          // up to 1024 entries
    int* srclist = bsum + 1024;         // E2 entries

    int nb = (N + 255) / 256;

    // ---- CSR build (edge structure shared by all 3 layers)
    zero2_kernel<<<nb, 256, 0, stream>>>(cnt, cursor, N);
    hist_kernel<<<(E2 + 255) / 256, 256, 0, stream>>>(ei, E, E2, cnt);
    scan1_kernel<<<nb, 256, 0, stream>>>(cnt, rs, bsum, N);
    scan2_kernel<<<1, 1024, 0, stream>>>(bsum, nb);
    scan3_kernel<<<nb, 256, 0, stream>>>(rs, cnt, bsum, N);
    scatter_kernel<<<(E2 + 255) / 256, 256, 0, stream>>>(ei, E, E2, rs, cursor, srclist);

    int gx = (N + 63) / 64;

    // ---- encoder -> bufA (item h1 -> bufB, con h1 -> bufC, both bf16)
    enc_h1_kernel<<<(N * 64 + 255) / 256, 256, 0, stream>>>(x, ew1, eb1, cw1, cb1,
                                                            bufB, bufC, N);
    gemm_mfma_kernel<128><<<gx, 256, 0, stream>>>(bufB, ew2, eb2, nullptr, bufA, N, 1);
    gemm_mfma_kernel<128><<<gx, 256, 0, stream>>>(bufC, cw2, cb2, types, bufA, N, 2);

    // ---- GAT layers (out never aliases hl=bufB)
    // layer 0: h0 = relu(gat(h))            bufA -> bufA
    gat_layer<4>(bufA, lin0, as0, ad0, b0, nullptr, bufB, bufA,
                 a_s, a_d, ex, dinv, rs, cnt, srclist, N, stream);
    // layer 1: h1 = h0 + relu(gat(h0))      bufA -> bufC
    gat_layer<4>(bufA, lin1, as1, ad1, b1, bufA, bufB, bufC,
                 a_s, a_d, ex, dinv, rs, cnt, srclist, N, stream);
    // layer 2: h2 = h1 + relu(gat(h1))      bufC -> bufA  (1 head, mean=identity)
    gat_layer<1>(bufC, lin2, as2, ad2, b2, bufC, bufB, bufA,
                 a_s, a_d, ex, dinv, rs, cnt, srclist, N, stream);

    // ---- decoder: d1 -> bufC, d2 -> bufB (bf16), final dot fp32 out
    gemm_mfma_kernel<128><<<gx, 256, 0, stream>>>(bufA, dw1, db1, nullptr, bufC, N, 1);
    gemm_mfma_kernel<64><<<gx, 256, 0, stream>>>(bufC, dw2, db2, nullptr, bufB, N, 1);
    dec_final_kernel<<<(N + 3) / 4, 256, 0, stream>>>(bufB, types, dw3, db3,
                                                      (float*)d_out, N);
}

// Round 9
// 634.033 us; speedup vs baseline: 8.6498x; 1.1090x over previous
//
#include <hip/hip_runtime.h>
#include <math.h>

#define HIDDEN 128
#define NEG_SLOPE 0.2f

typedef unsigned short u16;
typedef __attribute__((ext_vector_type(8))) short bf16x8;
typedef __attribute__((ext_vector_type(4))) float f32x4;

__device__ __forceinline__ u16 f2bf(float f) {
    unsigned u = __float_as_uint(f);
    unsigned r = (u + 0x7FFFu + ((u >> 16) & 1u)) >> 16;   // round-nearest-even
    return (u16)r;
}
__device__ __forceinline__ float bf2f(u16 u) {
    return __uint_as_float((unsigned)u << 16);
}
__device__ __forceinline__ unsigned pack2(float a, float b) {
    return (unsigned)f2bf(a) | ((unsigned)f2bf(b) << 16);
}

// ============ MFMA bf16 GEMM + fused epilogues ================================
// X bf16 [N,128]; W fp32 [OUT,128]; out bf16 [N,OUT].
// mode 0: raw store          mode 1: relu(acc+bias)
// mode 2: relu(acc+bias); type==0 -> keep prev(out), type==1 -> v, else 0
// mode 3 (OUT=64): relu(acc+bias) -> dot dw3 -> sigmoid -> mask -> fout[N] (no out store)
// DH > 0: additionally compute a_s/a_d attention dots (DH heads) from acc.
template <int OUT, int DH>
__global__ __launch_bounds__(256) void gemm_mfma_kernel(
        const u16* __restrict__ X, const float* __restrict__ W,
        const float* __restrict__ bias, const int* __restrict__ types,
        u16* __restrict__ out, float* __restrict__ a_s, float* __restrict__ a_d,
        const float* __restrict__ att_s, const float* __restrict__ att_d,
        const float* __restrict__ dw3, const float* __restrict__ db3,
        float* __restrict__ fout, int N, int mode) {
    constexpr int NT = OUT / 16;
    __shared__ u16 Xs[64 * 136];
    __shared__ u16 Ws[OUT * 136];
    const int tid = threadIdx.x;
    const int n0 = blockIdx.x * 64;

    // stage X tile (64 rows x 128 bf16): straight 16B copies
#pragma unroll
    for (int r = 0; r < 4; r++) {
        int j = r * 256 + tid;
        int row = j >> 4, c8 = (j & 15) << 3;
        int n = n0 + row;
        uint4 v = make_uint4(0u, 0u, 0u, 0u);
        if (n < N) v = *(const uint4*)&X[(size_t)n * 128 + c8];
        *(uint4*)&Xs[row * 136 + c8] = v;
    }
    // stage W (OUT rows x 128), fp32 -> bf16
#pragma unroll
    for (int r = 0; r < NT * 2; r++) {
        int j = r * 256 + tid;
        int row = j >> 5, c4 = (j & 31) << 2;
        float4 v = *(const float4*)&W[(size_t)row * 128 + c4];
        *(uint2*)&Ws[row * 136 + c4] = make_uint2(pack2(v.x, v.y), pack2(v.z, v.w));
    }
    __syncthreads();

    const int w = tid >> 6, lane = tid & 63;
    const int qd = lane >> 4, lr = lane & 15;

    f32x4 acc[NT];
#pragma unroll
    for (int j = 0; j < NT; j++) acc[j] = (f32x4){0.f, 0.f, 0.f, 0.f};

#pragma unroll
    for (int k = 0; k < 4; k++) {
        bf16x8 a = *(const bf16x8*)&Xs[(w * 16 + lr) * 136 + k * 32 + qd * 8];
#pragma unroll
        for (int j = 0; j < NT; j++) {
            bf16x8 b = *(const bf16x8*)&Ws[(j * 16 + lr) * 136 + k * 32 + qd * 8];
            acc[j] = __builtin_amdgcn_mfma_f32_16x16x32_bf16(a, b, acc[j], 0, 0, 0);
        }
    }

    // D mapping: col = j*16 + lr, row = n0 + w*16 + qd*4 + r
    if (mode == 3) {
        // decoder tail: relu(acc+bias) . dw3 -> sigmoid -> mask
        float pr[4] = {0.f, 0.f, 0.f, 0.f};
#pragma unroll
        for (int j = 0; j < NT; j++) {
            int col = j * 16 + lr;
            float b = bias[col], wv = dw3[col];
#pragma unroll
            for (int r = 0; r < 4; r++) pr[r] += fmaxf(acc[j][r] + b, 0.f) * wv;
        }
#pragma unroll
        for (int m = 1; m < 16; m <<= 1)
#pragma unroll
            for (int r = 0; r < 4; r++) pr[r] += __shfl_xor(pr[r], m, 64);
        if (lr == 0) {
            float b3 = db3[0];
#pragma unroll
            for (int r = 0; r < 4; r++) {
                int row = n0 + w * 16 + qd * 4 + r;
                if (row < N) {
                    float prob = 1.f / (1.f + expf(-(pr[r] + b3)));
                    fout[row] = (types[row] == 0) ? prob : 0.f;
                }
            }
        }
        return;
    }

    // attention dots epilogue (for hl GEMMs)
    if (DH > 0) {
        constexpr int NH = (DH == 4) ? 4 : 1;
        float sp[NH][4], dp[NH][4];
#pragma unroll
        for (int h = 0; h < NH; h++)
#pragma unroll
            for (int r = 0; r < 4; r++) { sp[h][r] = 0.f; dp[h][r] = 0.f; }
#pragma unroll
        for (int j = 0; j < NT; j++) {
            int col = j * 16 + lr;
            float as_ = att_s[col], ad_ = att_d[col];
            int h = (DH == 4) ? (j >> 1) : 0;
#pragma unroll
            for (int r = 0; r < 4; r++) {
                sp[h][r] += acc[j][r] * as_;
                dp[h][r] += acc[j][r] * ad_;
            }
        }
#pragma unroll
        for (int m = 1; m < 16; m <<= 1)
#pragma unroll
            for (int h = 0; h < NH; h++)
#pragma unroll
                for (int r = 0; r < 4; r++) {
                    sp[h][r] += __shfl_xor(sp[h][r], m, 64);
                    dp[h][r] += __shfl_xor(dp[h][r], m, 64);
                }
        if (lr == 0) {
#pragma unroll
            for (int r = 0; r < 4; r++) {
                int row = n0 + w * 16 + qd * 4 + r;
                if (row < N) {
#pragma unroll
                    for (int h = 0; h < NH; h++) {
                        a_s[row * DH + h] = sp[h][r];
                        a_d[row * DH + h] = dp[h][r];
                    }
                }
            }
        }
    }

    // store epilogue
#pragma unroll
    for (int r = 0; r < 4; r++) {
        int row = n0 + w * 16 + qd * 4 + r;
        if (row >= N) continue;
        int ty = (mode == 2) ? types[row] : 0;
        if (mode == 2 && ty == 0) continue;   // keep item value written earlier
#pragma unroll
        for (int j = 0; j < NT; j++) {
            int col = j * 16 + lr;
            float v = acc[j][r];
            if (mode >= 1) v = fmaxf(v + bias[col], 0.f);
            if (mode == 2 && ty != 1) v = 0.f;
            out[(size_t)row * OUT + col] = f2bf(v);
        }
    }
}

// ============ encoder layer-1 (elementwise, both types, bf16 out) =============
__global__ void enc_h1_kernel(const float* __restrict__ x,
                              const float* __restrict__ ew1, const float* __restrict__ eb1,
                              const float* __restrict__ cw1, const float* __restrict__ cb1,
                              u16* __restrict__ h1_item, u16* __restrict__ h1_con, int N) {
    int i = blockIdx.x * blockDim.x + threadIdx.x;
    if (i >= N * 64) return;
    int n = i >> 6, t = (i & 63) * 2;
    float x0 = x[2 * n], x1 = x[2 * n + 1];
    float i0 = fmaxf(ew1[2 * t] * x0 + ew1[2 * t + 1] * x1 + eb1[t], 0.f);
    float i1 = fmaxf(ew1[2 * t + 2] * x0 + ew1[2 * t + 3] * x1 + eb1[t + 1], 0.f);
    float c0 = fmaxf(cw1[t] * x0 + cb1[t], 0.f);
    float c1 = fmaxf(cw1[t + 1] * x0 + cb1[t + 1], 0.f);
    *(unsigned*)&h1_item[(size_t)n * 128 + t] = pack2(i0, i1);
    *(unsigned*)&h1_con[(size_t)n * 128 + t]  = pack2(c0, c1);
}

// ============ CSR build ========================================================
__global__ void zero2_kernel(int* __restrict__ a, int* __restrict__ b, int N) {
    int i = blockIdx.x * blockDim.x + threadIdx.x;
    if (i < N) { a[i] = 0; b[i] = 0; }
}

__global__ void hist_kernel(const int* __restrict__ ei, int E, int E2, int* __restrict__ cnt) {
    int e = blockIdx.x * blockDim.x + threadIdx.x;
    if (e >= E2) return;
    int d = (e < E) ? ei[E + e] : e - E;
    atomicAdd(&cnt[d], 1);
}

__global__ void scan1_kernel(const int* __restrict__ cnt, int* __restrict__ rs,
                             int* __restrict__ bsum, int N) {
    __shared__ int s[256];
    int i = blockIdx.x * 256 + threadIdx.x;
    int v = (i < N) ? cnt[i] : 0;
    s[threadIdx.x] = v;
    __syncthreads();
    for (int off = 1; off < 256; off <<= 1) {
        int t = (threadIdx.x >= off) ? s[threadIdx.x - off] : 0;
        __syncthreads();
        s[threadIdx.x] += t;
        __syncthreads();
    }
    if (i < N) rs[i] = s[threadIdx.x];
    if (threadIdx.x == 255) bsum[blockIdx.x] = s[255];
}

__global__ void scan2_kernel(int* __restrict__ bsum, int nb) {
    __shared__ int s[1024];
    int i = threadIdx.x;
    int v = (i < nb) ? bsum[i] : 0;
    s[i] = v;
    __syncthreads();
    for (int off = 1; off < 1024; off <<= 1) {
        int t = (i >= off) ? s[i - off] : 0;
        __syncthreads();
        s[i] += t;
        __syncthreads();
    }
    if (i < nb) bsum[i] = s[i] - v;
}

__global__ void scan3_kernel(int* __restrict__ rs, const int* __restrict__ cnt,
                             const int* __restrict__ bsum, int N) {
    int i = blockIdx.x * 256 + threadIdx.x;
    if (i < N) rs[i] = rs[i] - cnt[i] + bsum[blockIdx.x];
}

__global__ void scatter_kernel(const int* __restrict__ ei, int E, int E2,
                               const int* __restrict__ rs, int* __restrict__ cursor,
                               int* __restrict__ srclist) {
    int e = blockIdx.x * blockDim.x + threadIdx.x;
    if (e >= E2) return;
    int s, d;
    if (e < E) { s = ei[e]; d = ei[E + e]; }
    else       { s = d = e - E; }
    int pos = atomicAdd(&cursor[d], 1);
    srclist[rs[d] + pos] = s;
}

// ============ attention coefficients: two-pass softmax per (node, head) ========
template <int H>
__global__ void att_kernel(const int* __restrict__ rs, const int* __restrict__ cnt,
                           const int* __restrict__ srclist,
                           const float* __restrict__ a_s, const float* __restrict__ a_d,
                           float* __restrict__ ex, float* __restrict__ dinv, int N) {
    int i = blockIdx.x * blockDim.x + threadIdx.x;
    if (i >= N * H) return;
    int n = (H == 1) ? i : (i >> 2);
    int h = (H == 1) ? 0 : (i & 3);
    int beg = rs[n], deg = cnt[n];
    float ad = a_d[i];
    float m = -INFINITY;
    for (int k = 0; k < deg; k++) {
        float al = a_s[srclist[beg + k] * H + h] + ad;
        al = (al > 0.f) ? al : NEG_SLOPE * al;
        m = fmaxf(m, al);
    }
    float l = 0.f;
    for (int k = 0; k < deg; k++) {
        float al = a_s[srclist[beg + k] * H + h] + ad;
        al = (al > 0.f) ? al : NEG_SLOPE * al;
        float p = expf(al - m);
        ex[(beg + k) * H + h] = p;
        l += p;
    }
    dinv[i] = 1.f / l;   // deg >= 1 (self-loop)
}

// ============ GAT aggregation: bf16 gather, 4-deep unroll =====================
// block = 4 nodes x 64 lanes (wave = node); lane l -> features {2l, 2l+1}
// NOTE: `out` must NEVER alias `hl`.
template <int H>
__global__ __launch_bounds__(256) void gat_agg_kernel(
        const int* __restrict__ rs, const int* __restrict__ cnt,
        const int* __restrict__ srclist, const u16* __restrict__ hl,
        const float* __restrict__ ex, const float* __restrict__ dinv,
        const float* __restrict__ bias, const u16* __restrict__ res,
        u16* __restrict__ out, int N) {
    int n = blockIdx.x * 4 + (threadIdx.x >> 6);
    int l = threadIdx.x & 63;
    if (n >= N) return;
    const int hh = (H == 1) ? 0 : (l >> 4);   // head of features 2l,2l+1
    const int beg = rs[n];
    const int deg = cnt[n];
    float a0x = 0.f, a0y = 0.f, a1x = 0.f, a1y = 0.f;
    float a2x = 0.f, a2y = 0.f, a3x = 0.f, a3y = 0.f;
    int k = 0;
    for (; k + 3 < deg; k += 4) {
        int s0 = srclist[beg + k],     s1 = srclist[beg + k + 1];
        int s2 = srclist[beg + k + 2], s3 = srclist[beg + k + 3];
        float p0 = ex[(beg + k) * H + hh],     p1 = ex[(beg + k + 1) * H + hh];
        float p2 = ex[(beg + k + 2) * H + hh], p3 = ex[(beg + k + 3) * H + hh];
        unsigned v0 = *(const unsigned*)&hl[(size_t)s0 * 128 + 2 * l];
        unsigned v1 = *(const unsigned*)&hl[(size_t)s1 * 128 + 2 * l];
        unsigned v2 = *(const unsigned*)&hl[(size_t)s2 * 128 + 2 * l];
        unsigned v3 = *(const unsigned*)&hl[(size_t)s3 * 128 + 2 * l];
        a0x += p0 * bf2f((u16)v0); a0y += p0 * bf2f((u16)(v0 >> 16));
        a1x += p1 * bf2f((u16)v1); a1y += p1 * bf2f((u16)(v1 >> 16));
        a2x += p2 * bf2f((u16)v2); a2y += p2 * bf2f((u16)(v2 >> 16));
        a3x += p3 * bf2f((u16)v3); a3y += p3 * bf2f((u16)(v3 >> 16));
    }
    for (; k < deg; k++) {
        int s0 = srclist[beg + k];
        float p0 = ex[(beg + k) * H + hh];
        unsigned v0 = *(const unsigned*)&hl[(size_t)s0 * 128 + 2 * l];
        a0x += p0 * bf2f((u16)v0); a0y += p0 * bf2f((u16)(v0 >> 16));
    }
    float di = dinv[n * H + hh];
    float o0 = fmaxf(((a0x + a1x) + (a2x + a3x)) * di + bias[2 * l], 0.f);
    float o1 = fmaxf(((a0y + a1y) + (a2y + a3y)) * di + bias[2 * l + 1], 0.f);
    if (res) {
        unsigned rv = *(const unsigned*)&res[(size_t)n * 128 + 2 * l];
        o0 += bf2f((u16)rv);
        o1 += bf2f((u16)(rv >> 16));
    }
    *(unsigned*)&out[(size_t)n * 128 + 2 * l] = pack2(o0, o1);
}

// ============ host-side layer driver ==========================================
template <int H>
static void gat_layer(const u16* X, const float* lin, const float* as_, const float* ad_,
                      const float* bias, const u16* res, u16* hl, u16* outb,
                      float* a_s, float* a_d, float* ex, float* dinv,
                      const int* rs, const int* cnt, const int* srclist,
                      int N, hipStream_t stream) {
    int gx = (N + 63) / 64;
    gemm_mfma_kernel<128, H><<<gx, 256, 0, stream>>>(
        X, lin, nullptr, nullptr, hl, a_s, a_d, as_, ad_, nullptr, nullptr, nullptr, N, 0);
    att_kernel<H><<<(N * H + 255) / 256, 256, 0, stream>>>(rs, cnt, srclist, a_s, a_d,
                                                           ex, dinv, N);
    gat_agg_kernel<H><<<(N + 3) / 4, 256, 0, stream>>>(rs, cnt, srclist, hl, ex, dinv,
                                                       bias, res, outb, N);
}

extern "C" void kernel_launch(void* const* d_in, const int* in_sizes, int n_in,
                              void* d_out, int out_size, void* d_ws, size_t ws_size,
                              hipStream_t stream) {
    const float* x     = (const float*)d_in[0];
    const int*   types = (const int*)d_in[1];
    const int*   ei    = (const int*)d_in[2];   // int64 in reference -> int32 on device
    const float* ew1 = (const float*)d_in[3];
    const float* eb1 = (const float*)d_in[4];
    const float* ew2 = (const float*)d_in[5];
    const float* eb2 = (const float*)d_in[6];
    const float* cw1 = (const float*)d_in[7];
    const float* cb1 = (const float*)d_in[8];
    const float* cw2 = (const float*)d_in[9];
    const float* cb2 = (const float*)d_in[10];
    const float* lin0 = (const float*)d_in[11];
    const float* as0  = (const float*)d_in[12];
    const float* ad0  = (const float*)d_in[13];
    const float* b0   = (const float*)d_in[14];
    const float* lin1 = (const float*)d_in[15];
    const float* as1  = (const float*)d_in[16];
    const float* ad1  = (const float*)d_in[17];
    const float* b1   = (const float*)d_in[18];
    const float* lin2 = (const float*)d_in[19];
    const float* as2  = (const float*)d_in[20];
    const float* ad2  = (const float*)d_in[21];
    const float* b2   = (const float*)d_in[22];
    const float* dw1 = (const float*)d_in[23];
    const float* db1 = (const float*)d_in[24];
    const float* dw2 = (const float*)d_in[25];
    const float* db2 = (const float*)d_in[26];
    const float* dw3 = (const float*)d_in[27];
    const float* db3 = (const float*)d_in[28];

    int N  = in_sizes[1];
    int E  = in_sizes[2] / 2;
    int E2 = E + N;

    size_t NF = (size_t)N * HIDDEN;
    u16* bufA = (u16*)d_ws;          // bf16 feature buffers
    u16* bufB = bufA + NF;
    u16* bufC = bufB + NF;
    float* fbase = (float*)(bufC + NF);
    float* a_s  = fbase;
    float* a_d  = a_s + (size_t)N * 4;
    float* dinv = a_d + (size_t)N * 4;
    float* ex   = dinv + (size_t)N * 4;             // E2*4 floats
    int* rs      = (int*)(ex + (size_t)E2 * 4);
    int* cnt     = rs + N;
    int* cursor  = cnt + N;
    int* bsum    = cursor + N;          // up to 1024 entries
    int* srclist = bsum + 1024;         // E2 entries

    int nb = (N + 255) / 256;

    // ---- CSR build (edge structure shared by all 3 layers)
    zero2_kernel<<<nb, 256, 0, stream>>>(cnt, cursor, N);
    hist_kernel<<<(E2 + 255) / 256, 256, 0, stream>>>(ei, E, E2, cnt);
    scan1_kernel<<<nb, 256, 0, stream>>>(cnt, rs, bsum, N);
    scan2_kernel<<<1, 1024, 0, stream>>>(bsum, nb);
    scan3_kernel<<<nb, 256, 0, stream>>>(rs, cnt, bsum, N);
    scatter_kernel<<<(E2 + 255) / 256, 256, 0, stream>>>(ei, E, E2, rs, cursor, srclist);

    int gx = (N + 63) / 64;

    // ---- encoder -> bufA (item h1 -> bufB, con h1 -> bufC, both bf16)
    enc_h1_kernel<<<(N * 64 + 255) / 256, 256, 0, stream>>>(x, ew1, eb1, cw1, cb1,
                                                            bufB, bufC, N);
    gemm_mfma_kernel<128, 0><<<gx, 256, 0, stream>>>(
        bufB, ew2, eb2, nullptr, bufA, nullptr, nullptr, nullptr, nullptr,
        nullptr, nullptr, nullptr, N, 1);
    gemm_mfma_kernel<128, 0><<<gx, 256, 0, stream>>>(
        bufC, cw2, cb2, types, bufA, nullptr, nullptr, nullptr, nullptr,
        nullptr, nullptr, nullptr, N, 2);

    // ---- GAT layers (out never aliases hl=bufB)
    // layer 0: h0 = relu(gat(h))            bufA -> bufA
    gat_layer<4>(bufA, lin0, as0, ad0, b0, nullptr, bufB, bufA,
                 a_s, a_d, ex, dinv, rs, cnt, srclist, N, stream);
    // layer 1: h1 = h0 + relu(gat(h0))      bufA -> bufC
    gat_layer<4>(bufA, lin1, as1, ad1, b1, bufA, bufB, bufC,
                 a_s, a_d, ex, dinv, rs, cnt, srclist, N, stream);
    // layer 2: h2 = h1 + relu(gat(h1))      bufC -> bufA  (1 head, mean=identity)
    gat_layer<1>(bufC, lin2, as2, ad2, b2, bufC, bufB, bufA,
                 a_s, a_d, ex, dinv, rs, cnt, srclist, N, stream);

    // ---- decoder: d1 -> bufC ; d2 GEMM fused with final dot/sigmoid/mask
    gemm_mfma_kernel<128, 0><<<gx, 256, 0, stream>>>(
        bufA, dw1, db1, nullptr, bufC, nullptr, nullptr, nullptr, nullptr,
        nullptr, nullptr, nullptr, N, 1);
    gemm_mfma_kernel<64, 0><<<gx, 256, 0, stream>>>(
        bufC, dw2, db2, types, nullptr, nullptr, nullptr, nullptr, nullptr,
        dw3, db3, (float*)d_out, N, 3);
}

// Round 10
// 626.887 us; speedup vs baseline: 8.7484x; 1.0114x over previous
//
#include <hip/hip_runtime.h>
#include <math.h>

#define HIDDEN 128
#define NEG_SLOPE 0.2f

typedef unsigned short u16;
typedef __attribute__((ext_vector_type(8))) short bf16x8;
typedef __attribute__((ext_vector_type(4))) float f32x4;

__device__ __forceinline__ u16 f2bf(float f) {
    unsigned u = __float_as_uint(f);
    unsigned r = (u + 0x7FFFu + ((u >> 16) & 1u)) >> 16;   // round-nearest-even
    return (u16)r;
}
__device__ __forceinline__ float bf2f(u16 u) {
    return __uint_as_float((unsigned)u << 16);
}
__device__ __forceinline__ unsigned pack2(float a, float b) {
    return (unsigned)f2bf(a) | ((unsigned)f2bf(b) << 16);
}
__device__ __forceinline__ float lo16f(unsigned v) { return bf2f((u16)v); }
__device__ __forceinline__ float hi16f(unsigned v) { return bf2f((u16)(v >> 16)); }

// ============ MFMA bf16 GEMM + fused epilogues ================================
// X bf16 [N,128]; W fp32 [OUT,128]; out bf16 [N,OUT].
// mode 0: raw store          mode 1: relu(acc+bias)
// mode 2: relu(acc+bias); type==0 -> keep prev(out), type==1 -> v, else 0
// mode 3 (OUT=64): relu(acc+bias) -> dot dw3 -> sigmoid -> mask -> fout[N] (no out store)
// DH > 0: additionally compute a_s/a_d attention dots (DH heads) from acc.
template <int OUT, int DH>
__global__ __launch_bounds__(256) void gemm_mfma_kernel(
        const u16* __restrict__ X, const float* __restrict__ W,
        const float* __restrict__ bias, const int* __restrict__ types,
        u16* __restrict__ out, float* __restrict__ a_s, float* __restrict__ a_d,
        const float* __restrict__ att_s, const float* __restrict__ att_d,
        const float* __restrict__ dw3, const float* __restrict__ db3,
        float* __restrict__ fout, int N, int mode) {
    constexpr int NT = OUT / 16;
    __shared__ u16 Xs[64 * 136];
    __shared__ u16 Ws[OUT * 136];
    const int tid = threadIdx.x;
    const int n0 = blockIdx.x * 64;

    // stage X tile (64 rows x 128 bf16): straight 16B copies
#pragma unroll
    for (int r = 0; r < 4; r++) {
        int j = r * 256 + tid;
        int row = j >> 4, c8 = (j & 15) << 3;
        int n = n0 + row;
        uint4 v = make_uint4(0u, 0u, 0u, 0u);
        if (n < N) v = *(const uint4*)&X[(size_t)n * 128 + c8];
        *(uint4*)&Xs[row * 136 + c8] = v;
    }
    // stage W (OUT rows x 128), fp32 -> bf16
#pragma unroll
    for (int r = 0; r < NT * 2; r++) {
        int j = r * 256 + tid;
        int row = j >> 5, c4 = (j & 31) << 2;
        float4 v = *(const float4*)&W[(size_t)row * 128 + c4];
        *(uint2*)&Ws[row * 136 + c4] = make_uint2(pack2(v.x, v.y), pack2(v.z, v.w));
    }
    __syncthreads();

    const int w = tid >> 6, lane = tid & 63;
    const int qd = lane >> 4, lr = lane & 15;

    f32x4 acc[NT];
#pragma unroll
    for (int j = 0; j < NT; j++) acc[j] = (f32x4){0.f, 0.f, 0.f, 0.f};

#pragma unroll
    for (int k = 0; k < 4; k++) {
        bf16x8 a = *(const bf16x8*)&Xs[(w * 16 + lr) * 136 + k * 32 + qd * 8];
#pragma unroll
        for (int j = 0; j < NT; j++) {
            bf16x8 b = *(const bf16x8*)&Ws[(j * 16 + lr) * 136 + k * 32 + qd * 8];
            acc[j] = __builtin_amdgcn_mfma_f32_16x16x32_bf16(a, b, acc[j], 0, 0, 0);
        }
    }

    // D mapping: col = j*16 + lr, row = n0 + w*16 + qd*4 + r
    if (mode == 3) {
        float pr[4] = {0.f, 0.f, 0.f, 0.f};
#pragma unroll
        for (int j = 0; j < NT; j++) {
            int col = j * 16 + lr;
            float b = bias[col], wv = dw3[col];
#pragma unroll
            for (int r = 0; r < 4; r++) pr[r] += fmaxf(acc[j][r] + b, 0.f) * wv;
        }
#pragma unroll
        for (int m = 1; m < 16; m <<= 1)
#pragma unroll
            for (int r = 0; r < 4; r++) pr[r] += __shfl_xor(pr[r], m, 64);
        if (lr == 0) {
            float b3 = db3[0];
#pragma unroll
            for (int r = 0; r < 4; r++) {
                int row = n0 + w * 16 + qd * 4 + r;
                if (row < N) {
                    float prob = 1.f / (1.f + expf(-(pr[r] + b3)));
                    fout[row] = (types[row] == 0) ? prob : 0.f;
                }
            }
        }
        return;
    }

    // attention dots epilogue (for hl GEMMs)
    if (DH > 0) {
        constexpr int NH = (DH == 4) ? 4 : 1;
        float sp[NH][4], dp[NH][4];
#pragma unroll
        for (int h = 0; h < NH; h++)
#pragma unroll
            for (int r = 0; r < 4; r++) { sp[h][r] = 0.f; dp[h][r] = 0.f; }
#pragma unroll
        for (int j = 0; j < NT; j++) {
            int col = j * 16 + lr;
            float as_ = att_s[col], ad_ = att_d[col];
            int h = (DH == 4) ? (j >> 1) : 0;
#pragma unroll
            for (int r = 0; r < 4; r++) {
                sp[h][r] += acc[j][r] * as_;
                dp[h][r] += acc[j][r] * ad_;
            }
        }
#pragma unroll
        for (int m = 1; m < 16; m <<= 1)
#pragma unroll
            for (int h = 0; h < NH; h++)
#pragma unroll
                for (int r = 0; r < 4; r++) {
                    sp[h][r] += __shfl_xor(sp[h][r], m, 64);
                    dp[h][r] += __shfl_xor(dp[h][r], m, 64);
                }
        if (lr == 0) {
#pragma unroll
            for (int r = 0; r < 4; r++) {
                int row = n0 + w * 16 + qd * 4 + r;
                if (row < N) {
#pragma unroll
                    for (int h = 0; h < NH; h++) {
                        a_s[row * DH + h] = sp[h][r];
                        a_d[row * DH + h] = dp[h][r];
                    }
                }
            }
        }
    }

    // store epilogue
#pragma unroll
    for (int r = 0; r < 4; r++) {
        int row = n0 + w * 16 + qd * 4 + r;
        if (row >= N) continue;
        int ty = (mode == 2) ? types[row] : 0;
        if (mode == 2 && ty == 0) continue;   // keep item value written earlier
#pragma unroll
        for (int j = 0; j < NT; j++) {
            int col = j * 16 + lr;
            float v = acc[j][r];
            if (mode >= 1) v = fmaxf(v + bias[col], 0.f);
            if (mode == 2 && ty != 1) v = 0.f;
            out[(size_t)row * OUT + col] = f2bf(v);
        }
    }
}

// ============ encoder layer-1 (elementwise, both types, bf16 out) =============
__global__ void enc_h1_kernel(const float* __restrict__ x,
                              const float* __restrict__ ew1, const float* __restrict__ eb1,
                              const float* __restrict__ cw1, const float* __restrict__ cb1,
                              u16* __restrict__ h1_item, u16* __restrict__ h1_con, int N) {
    int i = blockIdx.x * blockDim.x + threadIdx.x;
    if (i >= N * 64) return;
    int n = i >> 6, t = (i & 63) * 2;
    float x0 = x[2 * n], x1 = x[2 * n + 1];
    float i0 = fmaxf(ew1[2 * t] * x0 + ew1[2 * t + 1] * x1 + eb1[t], 0.f);
    float i1 = fmaxf(ew1[2 * t + 2] * x0 + ew1[2 * t + 3] * x1 + eb1[t + 1], 0.f);
    float c0 = fmaxf(cw1[t] * x0 + cb1[t], 0.f);
    float c1 = fmaxf(cw1[t + 1] * x0 + cb1[t + 1], 0.f);
    *(unsigned*)&h1_item[(size_t)n * 128 + t] = pack2(i0, i1);
    *(unsigned*)&h1_con[(size_t)n * 128 + t]  = pack2(c0, c1);
}

// ============ CSR build ========================================================
__global__ void zero2_kernel(int* __restrict__ a, int* __restrict__ b, int N) {
    int i = blockIdx.x * blockDim.x + threadIdx.x;
    if (i < N) { a[i] = 0; b[i] = 0; }
}

__global__ void hist_kernel(const int* __restrict__ ei, int E, int E2, int* __restrict__ cnt) {
    int e = blockIdx.x * blockDim.x + threadIdx.x;
    if (e >= E2) return;
    int d = (e < E) ? ei[E + e] : e - E;
    atomicAdd(&cnt[d], 1);
}

__global__ void scan1_kernel(const int* __restrict__ cnt, int* __restrict__ rs,
                             int* __restrict__ bsum, int N) {
    __shared__ int s[256];
    int i = blockIdx.x * 256 + threadIdx.x;
    int v = (i < N) ? cnt[i] : 0;
    s[threadIdx.x] = v;
    __syncthreads();
    for (int off = 1; off < 256; off <<= 1) {
        int t = (threadIdx.x >= off) ? s[threadIdx.x - off] : 0;
        __syncthreads();
        s[threadIdx.x] += t;
        __syncthreads();
    }
    if (i < N) rs[i] = s[threadIdx.x];
    if (threadIdx.x == 255) bsum[blockIdx.x] = s[255];
}

__global__ void scan2_kernel(int* __restrict__ bsum, int nb) {
    __shared__ int s[1024];
    int i = threadIdx.x;
    int v = (i < nb) ? bsum[i] : 0;
    s[i] = v;
    __syncthreads();
    for (int off = 1; off < 1024; off <<= 1) {
        int t = (i >= off) ? s[i - off] : 0;
        __syncthreads();
        s[i] += t;
        __syncthreads();
    }
    if (i < nb) bsum[i] = s[i] - v;
}

__global__ void scan3_kernel(int* __restrict__ rs, const int* __restrict__ cnt,
                             const int* __restrict__ bsum, int N) {
    int i = blockIdx.x * 256 + threadIdx.x;
    if (i < N) rs[i] = rs[i] - cnt[i] + bsum[blockIdx.x];
}

__global__ void scatter_kernel(const int* __restrict__ ei, int E, int E2,
                               const int* __restrict__ rs, int* __restrict__ cursor,
                               int* __restrict__ srclist) {
    int e = blockIdx.x * blockDim.x + threadIdx.x;
    if (e >= E2) return;
    int s, d;
    if (e < E) { s = ei[e]; d = ei[E + e]; }
    else       { s = d = e - E; }
    int pos = atomicAdd(&cursor[d], 1);
    srclist[rs[d] + pos] = s;
}

// ============ attention coefficients: two-pass softmax per (node, head) ========
template <int H>
__global__ void att_kernel(const int* __restrict__ rs, const int* __restrict__ cnt,
                           const int* __restrict__ srclist,
                           const float* __restrict__ a_s, const float* __restrict__ a_d,
                           float* __restrict__ ex, float* __restrict__ dinv, int N) {
    int i = blockIdx.x * blockDim.x + threadIdx.x;
    if (i >= N * H) return;
    int n = (H == 1) ? i : (i >> 2);
    int h = (H == 1) ? 0 : (i & 3);
    int beg = rs[n], deg = cnt[n];
    float ad = a_d[i];
    float m = -INFINITY;
    for (int k = 0; k < deg; k++) {
        float al = a_s[srclist[beg + k] * H + h] + ad;
        al = (al > 0.f) ? al : NEG_SLOPE * al;
        m = fmaxf(m, al);
    }
    float l = 0.f;
    for (int k = 0; k < deg; k++) {
        float al = a_s[srclist[beg + k] * H + h] + ad;
        al = (al > 0.f) ? al : NEG_SLOPE * al;
        float p = expf(al - m);
        ex[(beg + k) * H + h] = p;
        l += p;
    }
    dinv[i] = 1.f / l;   // deg >= 1 (self-loop)
}

// ============ GAT aggregation: 16B/lane gather, 4 edges per wave-step =========
// wave = node. lane l: edge-group g=l>>4, feature-chunk c=l&15 (8 bf16 = 16B).
// Each iteration the wave pulls 4 full 256B rows. Cross-group reduce via
// shfl_xor(16|32); lanes 0..15 write the output row (16B each).
// NOTE: `out` must NEVER alias `hl`.
template <int H>
__global__ __launch_bounds__(256) void gat_agg_kernel(
        const int* __restrict__ rs, const int* __restrict__ cnt,
        const int* __restrict__ srclist, const u16* __restrict__ hl,
        const float* __restrict__ ex, const float* __restrict__ dinv,
        const float* __restrict__ bias, const u16* __restrict__ res,
        u16* __restrict__ out, int N) {
    int n = blockIdx.x * 4 + (threadIdx.x >> 6);
    int l = threadIdx.x & 63;
    if (n >= N) return;
    const int g = l >> 4;          // edge group 0..3
    const int c = l & 15;          // feature chunk (features 8c..8c+7)
    const int head = (H == 1) ? 0 : (c >> 2);
    const int beg = rs[n];
    const int deg = cnt[n];
    float acc[8];
#pragma unroll
    for (int j = 0; j < 8; j++) acc[j] = 0.f;

    for (int k = 0; k < deg; k += 4) {
        int idx = k + g;
        bool valid = idx < deg;
        int e = beg + (valid ? idx : 0);
        float p = ex[e * H + head];
        if (!valid) p = 0.f;
        int s = srclist[e];
        uint4 v = *(const uint4*)&hl[(size_t)s * 128 + 8 * c];
        acc[0] += p * lo16f(v.x); acc[1] += p * hi16f(v.x);
        acc[2] += p * lo16f(v.y); acc[3] += p * hi16f(v.y);
        acc[4] += p * lo16f(v.z); acc[5] += p * hi16f(v.z);
        acc[6] += p * lo16f(v.w); acc[7] += p * hi16f(v.w);
    }
#pragma unroll
    for (int j = 0; j < 8; j++) {
        acc[j] += __shfl_xor(acc[j], 16, 64);
        acc[j] += __shfl_xor(acc[j], 32, 64);
    }
    if (g == 0) {   // lanes 0..15 hold the full sums for their 8 features
        float di = dinv[n * H + head];
        float4 b0 = *(const float4*)&bias[8 * c];
        float4 b1 = *(const float4*)&bias[8 * c + 4];
        float o[8];
        o[0] = fmaxf(acc[0] * di + b0.x, 0.f);
        o[1] = fmaxf(acc[1] * di + b0.y, 0.f);
        o[2] = fmaxf(acc[2] * di + b0.z, 0.f);
        o[3] = fmaxf(acc[3] * di + b0.w, 0.f);
        o[4] = fmaxf(acc[4] * di + b1.x, 0.f);
        o[5] = fmaxf(acc[5] * di + b1.y, 0.f);
        o[6] = fmaxf(acc[6] * di + b1.z, 0.f);
        o[7] = fmaxf(acc[7] * di + b1.w, 0.f);
        if (res) {
            uint4 rv = *(const uint4*)&res[(size_t)n * 128 + 8 * c];
            o[0] += lo16f(rv.x); o[1] += hi16f(rv.x);
            o[2] += lo16f(rv.y); o[3] += hi16f(rv.y);
            o[4] += lo16f(rv.z); o[5] += hi16f(rv.z);
            o[6] += lo16f(rv.w); o[7] += hi16f(rv.w);
        }
        uint4 ov = make_uint4(pack2(o[0], o[1]), pack2(o[2], o[3]),
                              pack2(o[4], o[5]), pack2(o[6], o[7]));
        *(uint4*)&out[(size_t)n * 128 + 8 * c] = ov;
    }
}

// ============ host-side layer driver ==========================================
template <int H>
static void gat_layer(const u16* X, const float* lin, const float* as_, const float* ad_,
                      const float* bias, const u16* res, u16* hl, u16* outb,
                      float* a_s, float* a_d, float* ex, float* dinv,
                      const int* rs, const int* cnt, const int* srclist,
                      int N, hipStream_t stream) {
    int gx = (N + 63) / 64;
    gemm_mfma_kernel<128, H><<<gx, 256, 0, stream>>>(
        X, lin, nullptr, nullptr, hl, a_s, a_d, as_, ad_, nullptr, nullptr, nullptr, N, 0);
    att_kernel<H><<<(N * H + 255) / 256, 256, 0, stream>>>(rs, cnt, srclist, a_s, a_d,
                                                           ex, dinv, N);
    gat_agg_kernel<H><<<(N + 3) / 4, 256, 0, stream>>>(rs, cnt, srclist, hl, ex, dinv,
                                                       bias, res, outb, N);
}

extern "C" void kernel_launch(void* const* d_in, const int* in_sizes, int n_in,
                              void* d_out, int out_size, void* d_ws, size_t ws_size,
                              hipStream_t stream) {
    const float* x     = (const float*)d_in[0];
    const int*   types = (const int*)d_in[1];
    const int*   ei    = (const int*)d_in[2];   // int64 in reference -> int32 on device
    const float* ew1 = (const float*)d_in[3];
    const float* eb1 = (const float*)d_in[4];
    const float* ew2 = (const float*)d_in[5];
    const float* eb2 = (const float*)d_in[6];
    const float* cw1 = (const float*)d_in[7];
    const float* cb1 = (const float*)d_in[8];
    const float* cw2 = (const float*)d_in[9];
    const float* cb2 = (const float*)d_in[10];
    const float* lin0 = (const float*)d_in[11];
    const float* as0  = (const float*)d_in[12];
    const float* ad0  = (const float*)d_in[13];
    const float* b0   = (const float*)d_in[14];
    const float* lin1 = (const float*)d_in[15];
    const float* as1  = (const float*)d_in[16];
    const float* ad1  = (const float*)d_in[17];
    const float* b1   = (const float*)d_in[18];
    const float* lin2 = (const float*)d_in[19];
    const float* as2  = (const float*)d_in[20];
    const float* ad2  = (const float*)d_in[21];
    const float* b2   = (const float*)d_in[22];
    const float* dw1 = (const float*)d_in[23];
    const float* db1 = (const float*)d_in[24];
    const float* dw2 = (const float*)d_in[25];
    const float* db2 = (const float*)d_in[26];
    const float* dw3 = (const float*)d_in[27];
    const float* db3 = (const float*)d_in[28];

    int N  = in_sizes[1];
    int E  = in_sizes[2] / 2;
    int E2 = E + N;

    size_t NF = (size_t)N * HIDDEN;
    u16* bufA = (u16*)d_ws;          // bf16 feature buffers
    u16* bufB = bufA + NF;
    u16* bufC = bufB + NF;
    float* fbase = (float*)(bufC + NF);
    float* a_s  = fbase;
    float* a_d  = a_s + (size_t)N * 4;
    float* dinv = a_d + (size_t)N * 4;
    float* ex   = dinv + (size_t)N * 4;             // E2*4 floats
    int* rs      = (int*)(ex + (size_t)E2 * 4);
    int* cnt     = rs + N;
    int* cursor  = cnt + N;
    int* bsum    = cursor + N;          // up to 1024 entries
    int* srclist = bsum + 1024;         // E2 entries

    int nb = (N + 255) / 256;

    // ---- CSR build (edge structure shared by all 3 layers)
    zero2_kernel<<<nb, 256, 0, stream>>>(cnt, cursor, N);
    hist_kernel<<<(E2 + 255) / 256, 256, 0, stream>>>(ei, E, E2, cnt);
    scan1_kernel<<<nb, 256, 0, stream>>>(cnt, rs, bsum, N);
    scan2_kernel<<<1, 1024, 0, stream>>>(bsum, nb);
    scan3_kernel<<<nb, 256, 0, stream>>>(rs, cnt, bsum, N);
    scatter_kernel<<<(E2 + 255) / 256, 256, 0, stream>>>(ei, E, E2, rs, cursor, srclist);

    int gx = (N + 63) / 64;

    // ---- encoder -> bufA (item h1 -> bufB, con h1 -> bufC, both bf16)
    enc_h1_kernel<<<(N * 64 + 255) / 256, 256, 0, stream>>>(x, ew1, eb1, cw1, cb1,
                                                            bufB, bufC, N);
    gemm_mfma_kernel<128, 0><<<gx, 256, 0, stream>>>(
        bufB, ew2, eb2, nullptr, bufA, nullptr, nullptr, nullptr, nullptr,
        nullptr, nullptr, nullptr, N, 1);
    gemm_mfma_kernel<128, 0><<<gx, 256, 0, stream>>>(
        bufC, cw2, cb2, types, bufA, nullptr, nullptr, nullptr, nullptr,
        nullptr, nullptr, nullptr, N, 2);

    // ---- GAT layers (out never aliases hl=bufB)
    // layer 0: h0 = relu(gat(h))            bufA -> bufA
    gat_layer<4>(bufA, lin0, as0, ad0, b0, nullptr, bufB, bufA,
                 a_s, a_d, ex, dinv, rs, cnt, srclist, N, stream);
    // layer 1: h1 = h0 + relu(gat(h0))      bufA -> bufC
    gat_layer<4>(bufA, lin1, as1, ad1, b1, bufA, bufB, bufC,
                 a_s, a_d, ex, dinv, rs, cnt, srclist, N, stream);
    // layer 2: h2 = h1 + relu(gat(h1))      bufC -> bufA  (1 head, mean=identity)
    gat_layer<1>(bufC, lin2, as2, ad2, b2, bufC, bufB, bufA,
                 a_s, a_d, ex, dinv, rs, cnt, srclist, N, stream);

    // ---- decoder: d1 -> bufC ; d2 GEMM fused with final dot/sigmoid/mask
    gemm_mfma_kernel<128, 0><<<gx, 256, 0, stream>>>(
        bufA, dw1, db1, nullptr, bufC, nullptr, nullptr, nullptr, nullptr,
        nullptr, nullptr, nullptr, N, 1);
    gemm_mfma_kernel<64, 0><<<gx, 256, 0, stream>>>(
        bufC, dw2, db2, types, nullptr, nullptr, nullptr, nullptr, nullptr,
        dw3, db3, (float*)d_out, N, 3);
}

// Round 11
// 564.589 us; speedup vs baseline: 9.7137x; 1.1103x over previous
//
#include <hip/hip_runtime.h>
#include <math.h>

#define HIDDEN 128
#define NEG_SLOPE 0.2f

typedef unsigned short u16;
typedef __attribute__((ext_vector_type(8))) short bf16x8;
typedef __attribute__((ext_vector_type(4))) float f32x4;

__device__ __forceinline__ u16 f2bf(float f) {
    unsigned u = __float_as_uint(f);
    unsigned r = (u + 0x7FFFu + ((u >> 16) & 1u)) >> 16;   // round-nearest-even
    return (u16)r;
}
__device__ __forceinline__ float bf2f(u16 u) {
    return __uint_as_float((unsigned)u << 16);
}
__device__ __forceinline__ unsigned pack2(float a, float b) {
    return (unsigned)f2bf(a) | ((unsigned)f2bf(b) << 16);
}
__device__ __forceinline__ float lo16f(unsigned v) { return bf2f((u16)v); }
__device__ __forceinline__ float hi16f(unsigned v) { return bf2f((u16)(v >> 16)); }

// ============ MFMA bf16 GEMM + fused epilogues ================================
// X bf16 [N,128]; W fp32 [OUT,128]; out bf16 [N,OUT].
// mode 0: raw store          mode 1: relu(acc+bias)
// mode 2: relu(acc+bias); type==0 -> keep prev(out), type==1 -> v, else 0
// mode 3 (OUT=64): relu(acc+bias) -> dot dw3 -> sigmoid -> mask -> fout[N] (no out store)
// DH > 0: additionally compute a_s/a_d attention dots (DH heads) from acc.
template <int OUT, int DH>
__global__ __launch_bounds__(256) void gemm_mfma_kernel(
        const u16* __restrict__ X, const float* __restrict__ W,
        const float* __restrict__ bias, const int* __restrict__ types,
        u16* __restrict__ out, float* __restrict__ a_s, float* __restrict__ a_d,
        const float* __restrict__ att_s, const float* __restrict__ att_d,
        const float* __restrict__ dw3, const float* __restrict__ db3,
        float* __restrict__ fout, int N, int mode) {
    constexpr int NT = OUT / 16;
    __shared__ u16 Xs[64 * 136];
    __shared__ u16 Ws[OUT * 136];
    const int tid = threadIdx.x;
    const int n0 = blockIdx.x * 64;

    // stage X tile (64 rows x 128 bf16): straight 16B copies
#pragma unroll
    for (int r = 0; r < 4; r++) {
        int j = r * 256 + tid;
        int row = j >> 4, c8 = (j & 15) << 3;
        int n = n0 + row;
        uint4 v = make_uint4(0u, 0u, 0u, 0u);
        if (n < N) v = *(const uint4*)&X[(size_t)n * 128 + c8];
        *(uint4*)&Xs[row * 136 + c8] = v;
    }
    // stage W (OUT rows x 128), fp32 -> bf16
#pragma unroll
    for (int r = 0; r < NT * 2; r++) {
        int j = r * 256 + tid;
        int row = j >> 5, c4 = (j & 31) << 2;
        float4 v = *(const float4*)&W[(size_t)row * 128 + c4];
        *(uint2*)&Ws[row * 136 + c4] = make_uint2(pack2(v.x, v.y), pack2(v.z, v.w));
    }
    __syncthreads();

    const int w = tid >> 6, lane = tid & 63;
    const int qd = lane >> 4, lr = lane & 15;

    f32x4 acc[NT];
#pragma unroll
    for (int j = 0; j < NT; j++) acc[j] = (f32x4){0.f, 0.f, 0.f, 0.f};

#pragma unroll
    for (int k = 0; k < 4; k++) {
        bf16x8 a = *(const bf16x8*)&Xs[(w * 16 + lr) * 136 + k * 32 + qd * 8];
#pragma unroll
        for (int j = 0; j < NT; j++) {
            bf16x8 b = *(const bf16x8*)&Ws[(j * 16 + lr) * 136 + k * 32 + qd * 8];
            acc[j] = __builtin_amdgcn_mfma_f32_16x16x32_bf16(a, b, acc[j], 0, 0, 0);
        }
    }

    // D mapping: col = j*16 + lr, row = n0 + w*16 + qd*4 + r
    if (mode == 3) {
        float pr[4] = {0.f, 0.f, 0.f, 0.f};
#pragma unroll
        for (int j = 0; j < NT; j++) {
            int col = j * 16 + lr;
            float b = bias[col], wv = dw3[col];
#pragma unroll
            for (int r = 0; r < 4; r++) pr[r] += fmaxf(acc[j][r] + b, 0.f) * wv;
        }
#pragma unroll
        for (int m = 1; m < 16; m <<= 1)
#pragma unroll
            for (int r = 0; r < 4; r++) pr[r] += __shfl_xor(pr[r], m, 64);
        if (lr == 0) {
            float b3 = db3[0];
#pragma unroll
            for (int r = 0; r < 4; r++) {
                int row = n0 + w * 16 + qd * 4 + r;
                if (row < N) {
                    float prob = 1.f / (1.f + expf(-(pr[r] + b3)));
                    fout[row] = (types[row] == 0) ? prob : 0.f;
                }
            }
        }
        return;
    }

    // attention dots epilogue (for hl GEMMs)
    if (DH > 0) {
        constexpr int NH = (DH == 4) ? 4 : 1;
        float sp[NH][4], dp[NH][4];
#pragma unroll
        for (int h = 0; h < NH; h++)
#pragma unroll
            for (int r = 0; r < 4; r++) { sp[h][r] = 0.f; dp[h][r] = 0.f; }
#pragma unroll
        for (int j = 0; j < NT; j++) {
            int col = j * 16 + lr;
            float as_ = att_s[col], ad_ = att_d[col];
            int h = (DH == 4) ? (j >> 1) : 0;
#pragma unroll
            for (int r = 0; r < 4; r++) {
                sp[h][r] += acc[j][r] * as_;
                dp[h][r] += acc[j][r] * ad_;
            }
        }
#pragma unroll
        for (int m = 1; m < 16; m <<= 1)
#pragma unroll
            for (int h = 0; h < NH; h++)
#pragma unroll
                for (int r = 0; r < 4; r++) {
                    sp[h][r] += __shfl_xor(sp[h][r], m, 64);
                    dp[h][r] += __shfl_xor(dp[h][r], m, 64);
                }
        if (lr == 0) {
#pragma unroll
            for (int r = 0; r < 4; r++) {
                int row = n0 + w * 16 + qd * 4 + r;
                if (row < N) {
#pragma unroll
                    for (int h = 0; h < NH; h++) {
                        a_s[row * DH + h] = sp[h][r];
                        a_d[row * DH + h] = dp[h][r];
                    }
                }
            }
        }
    }

    // store epilogue
#pragma unroll
    for (int r = 0; r < 4; r++) {
        int row = n0 + w * 16 + qd * 4 + r;
        if (row >= N) continue;
        int ty = (mode == 2) ? types[row] : 0;
        if (mode == 2 && ty == 0) continue;   // keep item value written earlier
#pragma unroll
        for (int j = 0; j < NT; j++) {
            int col = j * 16 + lr;
            float v = acc[j][r];
            if (mode >= 1) v = fmaxf(v + bias[col], 0.f);
            if (mode == 2 && ty != 1) v = 0.f;
            out[(size_t)row * OUT + col] = f2bf(v);
        }
    }
}

// ============ encoder layer-1 (elementwise, both types, bf16 out) =============
__global__ void enc_h1_kernel(const float* __restrict__ x,
                              const float* __restrict__ ew1, const float* __restrict__ eb1,
                              const float* __restrict__ cw1, const float* __restrict__ cb1,
                              u16* __restrict__ h1_item, u16* __restrict__ h1_con, int N) {
    int i = blockIdx.x * blockDim.x + threadIdx.x;
    if (i >= N * 64) return;
    int n = i >> 6, t = (i & 63) * 2;
    float x0 = x[2 * n], x1 = x[2 * n + 1];
    float i0 = fmaxf(ew1[2 * t] * x0 + ew1[2 * t + 1] * x1 + eb1[t], 0.f);
    float i1 = fmaxf(ew1[2 * t + 2] * x0 + ew1[2 * t + 3] * x1 + eb1[t + 1], 0.f);
    float c0 = fmaxf(cw1[t] * x0 + cb1[t], 0.f);
    float c1 = fmaxf(cw1[t + 1] * x0 + cb1[t + 1], 0.f);
    *(unsigned*)&h1_item[(size_t)n * 128 + t] = pack2(i0, i1);
    *(unsigned*)&h1_con[(size_t)n * 128 + t]  = pack2(c0, c1);
}

// ============ CSR build ========================================================
__global__ void zero1_kernel(int* __restrict__ a, int N) {
    int i = blockIdx.x * blockDim.x + threadIdx.x;
    if (i < N) a[i] = 0;
}

// histogram + per-edge slot index (the only atomic pass)
__global__ void hist_kernel(const int* __restrict__ ei, int E, int E2,
                            int* __restrict__ cnt, int* __restrict__ pos) {
    int e = blockIdx.x * blockDim.x + threadIdx.x;
    if (e >= E2) return;
    int d = (e < E) ? ei[E + e] : e - E;
    pos[e] = atomicAdd(&cnt[d], 1);
}

__global__ void scan1_kernel(const int* __restrict__ cnt, int* __restrict__ rs,
                             int* __restrict__ bsum, int N) {
    __shared__ int s[256];
    int i = blockIdx.x * 256 + threadIdx.x;
    int v = (i < N) ? cnt[i] : 0;
    s[threadIdx.x] = v;
    __syncthreads();
    for (int off = 1; off < 256; off <<= 1) {
        int t = (threadIdx.x >= off) ? s[threadIdx.x - off] : 0;
        __syncthreads();
        s[threadIdx.x] += t;
        __syncthreads();
    }
    if (i < N) rs[i] = s[threadIdx.x];
    if (threadIdx.x == 255) bsum[blockIdx.x] = s[255];
}

__global__ void scan2_kernel(int* __restrict__ bsum, int nb) {
    __shared__ int s[1024];
    int i = threadIdx.x;
    int v = (i < nb) ? bsum[i] : 0;
    s[i] = v;
    __syncthreads();
    for (int off = 1; off < 1024; off <<= 1) {
        int t = (i >= off) ? s[i - off] : 0;
        __syncthreads();
        s[i] += t;
        __syncthreads();
    }
    if (i < nb) bsum[i] = s[i] - v;
}

__global__ void scan3_kernel(int* __restrict__ rs, const int* __restrict__ cnt,
                             const int* __restrict__ bsum, int N) {
    int i = blockIdx.x * 256 + threadIdx.x;
    if (i < N) rs[i] = rs[i] - cnt[i] + bsum[blockIdx.x];
}

// atomic-free scatter using precomputed slot indices
__global__ void scatter_kernel(const int* __restrict__ ei, int E, int E2,
                               const int* __restrict__ rs, const int* __restrict__ pos,
                               int* __restrict__ srclist) {
    int e = blockIdx.x * blockDim.x + threadIdx.x;
    if (e >= E2) return;
    int s, d;
    if (e < E) { s = ei[e]; d = ei[E + e]; }
    else       { s = d = e - E; }
    srclist[rs[d] + pos[e]] = s;
}

// ============ attention coefficients: single-pass (shift-invariant softmax) ====
// alpha is O(1) here (encoder outputs ~0.1 scale); clamp at 80 for exp safety.
template <int H>
__global__ void att_kernel(const int* __restrict__ rs, const int* __restrict__ cnt,
                           const int* __restrict__ srclist,
                           const float* __restrict__ a_s, const float* __restrict__ a_d,
                           float* __restrict__ ex, float* __restrict__ dinv, int N) {
    int i = blockIdx.x * blockDim.x + threadIdx.x;
    if (i >= N * H) return;
    int n = (H == 1) ? i : (i >> 2);
    int h = (H == 1) ? 0 : (i & 3);
    int beg = rs[n], deg = cnt[n];
    float ad = a_d[i];
    float l = 0.f;
    for (int k = 0; k < deg; k++) {
        float al = a_s[srclist[beg + k] * H + h] + ad;
        al = (al > 0.f) ? al : NEG_SLOPE * al;
        float p = expf(fminf(al, 80.f));
        ex[(beg + k) * H + h] = p;
        l += p;
    }
    dinv[i] = 1.f / l;   // deg >= 1 (self-loop)
}

// ============ GAT aggregation: 16B/lane gather, 8 edges per wave-step =========
// wave = node. lane l: edge-group g=l>>4, feature-chunk c=l&15 (8 bf16 = 16B).
// Two independent row loads per lane per iteration (edges k+g and k+4+g).
// Cross-group reduce via shfl_xor(16|32); lanes 0..15 write the output row.
// NOTE: `out` must NEVER alias `hl`.
template <int H>
__global__ __launch_bounds__(256) void gat_agg_kernel(
        const int* __restrict__ rs, const int* __restrict__ cnt,
        const int* __restrict__ srclist, const u16* __restrict__ hl,
        const float* __restrict__ ex, const float* __restrict__ dinv,
        const float* __restrict__ bias, const u16* __restrict__ res,
        u16* __restrict__ out, int N) {
    int n = blockIdx.x * 4 + (threadIdx.x >> 6);
    int l = threadIdx.x & 63;
    if (n >= N) return;
    const int g = l >> 4;          // edge group 0..3
    const int c = l & 15;          // feature chunk (features 8c..8c+7)
    const int head = (H == 1) ? 0 : (c >> 2);
    const int beg = rs[n];
    const int deg = cnt[n];
    float acc0[8], acc1[8];
#pragma unroll
    for (int j = 0; j < 8; j++) { acc0[j] = 0.f; acc1[j] = 0.f; }

    for (int k = 0; k < deg; k += 8) {
        int i0 = k + g;
        int i1 = k + 4 + g;
        int e0 = beg + min(i0, deg - 1);
        int e1 = beg + min(i1, deg - 1);
        int s0 = srclist[e0];
        int s1 = srclist[e1];
        float p0 = ex[e0 * H + head];
        float p1 = ex[e1 * H + head];
        if (i0 >= deg) p0 = 0.f;
        if (i1 >= deg) p1 = 0.f;
        uint4 v0 = *(const uint4*)&hl[(size_t)s0 * 128 + 8 * c];
        uint4 v1 = *(const uint4*)&hl[(size_t)s1 * 128 + 8 * c];
        acc0[0] += p0 * lo16f(v0.x); acc0[1] += p0 * hi16f(v0.x);
        acc0[2] += p0 * lo16f(v0.y); acc0[3] += p0 * hi16f(v0.y);
        acc0[4] += p0 * lo16f(v0.z); acc0[5] += p0 * hi16f(v0.z);
        acc0[6] += p0 * lo16f(v0.w); acc0[7] += p0 * hi16f(v0.w);
        acc1[0] += p1 * lo16f(v1.x); acc1[1] += p1 * hi16f(v1.x);
        acc1[2] += p1 * lo16f(v1.y); acc1[3] += p1 * hi16f(v1.y);
        acc1[4] += p1 * lo16f(v1.z); acc1[5] += p1 * hi16f(v1.z);
        acc1[6] += p1 * lo16f(v1.w); acc1[7] += p1 * hi16f(v1.w);
    }
#pragma unroll
    for (int j = 0; j < 8; j++) {
        float a = acc0[j] + acc1[j];
        a += __shfl_xor(a, 16, 64);
        a += __shfl_xor(a, 32, 64);
        acc0[j] = a;
    }
    if (g == 0) {   // lanes 0..15 hold the full sums for their 8 features
        float di = dinv[n * H + head];
        float4 b0 = *(const float4*)&bias[8 * c];
        float4 b1 = *(const float4*)&bias[8 * c + 4];
        float o[8];
        o[0] = fmaxf(acc0[0] * di + b0.x, 0.f);
        o[1] = fmaxf(acc0[1] * di + b0.y, 0.f);
        o[2] = fmaxf(acc0[2] * di + b0.z, 0.f);
        o[3] = fmaxf(acc0[3] * di + b0.w, 0.f);
        o[4] = fmaxf(acc0[4] * di + b1.x, 0.f);
        o[5] = fmaxf(acc0[5] * di + b1.y, 0.f);
        o[6] = fmaxf(acc0[6] * di + b1.z, 0.f);
        o[7] = fmaxf(acc0[7] * di + b1.w, 0.f);
        if (res) {
            uint4 rv = *(const uint4*)&res[(size_t)n * 128 + 8 * c];
            o[0] += lo16f(rv.x); o[1] += hi16f(rv.x);
            o[2] += lo16f(rv.y); o[3] += hi16f(rv.y);
            o[4] += lo16f(rv.z); o[5] += hi16f(rv.z);
            o[6] += lo16f(rv.w); o[7] += hi16f(rv.w);
        }
        uint4 ov = make_uint4(pack2(o[0], o[1]), pack2(o[2], o[3]),
                              pack2(o[4], o[5]), pack2(o[6], o[7]));
        *(uint4*)&out[(size_t)n * 128 + 8 * c] = ov;
    }
}

// ============ host-side layer driver ==========================================
template <int H>
static void gat_layer(const u16* X, const float* lin, const float* as_, const float* ad_,
                      const float* bias, const u16* res, u16* hl, u16* outb,
                      float* a_s, float* a_d, float* ex, float* dinv,
                      const int* rs, const int* cnt, const int* srclist,
                      int N, hipStream_t stream) {
    int gx = (N + 63) / 64;
    gemm_mfma_kernel<128, H><<<gx, 256, 0, stream>>>(
        X, lin, nullptr, nullptr, hl, a_s, a_d, as_, ad_, nullptr, nullptr, nullptr, N, 0);
    att_kernel<H><<<(N * H + 255) / 256, 256, 0, stream>>>(rs, cnt, srclist, a_s, a_d,
                                                           ex, dinv, N);
    gat_agg_kernel<H><<<(N + 3) / 4, 256, 0, stream>>>(rs, cnt, srclist, hl, ex, dinv,
                                                       bias, res, outb, N);
}

extern "C" void kernel_launch(void* const* d_in, const int* in_sizes, int n_in,
                              void* d_out, int out_size, void* d_ws, size_t ws_size,
                              hipStream_t stream) {
    const float* x     = (const float*)d_in[0];
    const int*   types = (const int*)d_in[1];
    const int*   ei    = (const int*)d_in[2];   // int64 in reference -> int32 on device
    const float* ew1 = (const float*)d_in[3];
    const float* eb1 = (const float*)d_in[4];
    const float* ew2 = (const float*)d_in[5];
    const float* eb2 = (const float*)d_in[6];
    const float* cw1 = (const float*)d_in[7];
    const float* cb1 = (const float*)d_in[8];
    const float* cw2 = (const float*)d_in[9];
    const float* cb2 = (const float*)d_in[10];
    const float* lin0 = (const float*)d_in[11];
    const float* as0  = (const float*)d_in[12];
    const float* ad0  = (const float*)d_in[13];
    const float* b0   = (const float*)d_in[14];
    const float* lin1 = (const float*)d_in[15];
    const float* as1  = (const float*)d_in[16];
    const float* ad1  = (const float*)d_in[17];
    const float* b1   = (const float*)d_in[18];
    const float* lin2 = (const float*)d_in[19];
    const float* as2  = (const float*)d_in[20];
    const float* ad2  = (const float*)d_in[21];
    const float* b2   = (const float*)d_in[22];
    const float* dw1 = (const float*)d_in[23];
    const float* db1 = (const float*)d_in[24];
    const float* dw2 = (const float*)d_in[25];
    const float* db2 = (const float*)d_in[26];
    const float* dw3 = (const float*)d_in[27];
    const float* db3 = (const float*)d_in[28];

    int N  = in_sizes[1];
    int E  = in_sizes[2] / 2;
    int E2 = E + N;

    size_t NF = (size_t)N * HIDDEN;
    u16* bufA = (u16*)d_ws;          // bf16 feature buffers
    u16* bufB = bufA + NF;
    u16* bufC = bufB + NF;
    float* fbase = (float*)(bufC + NF);
    float* a_s  = fbase;
    float* a_d  = a_s + (size_t)N * 4;
    float* dinv = a_d + (size_t)N * 4;
    float* ex   = dinv + (size_t)N * 4;             // E2*4 floats
    int* rs      = (int*)(ex + (size_t)E2 * 4);
    int* cnt     = rs + N;
    int* pos     = cnt + N;             // E2 entries (per-edge slot in segment)
    int* bsum    = pos + E2;            // up to 1024 entries
    int* srclist = bsum + 1024;         // E2 entries

    int nb = (N + 255) / 256;

    // ---- CSR build (edge structure shared by all 3 layers)
    zero1_kernel<<<nb, 256, 0, stream>>>(cnt, N);
    hist_kernel<<<(E2 + 255) / 256, 256, 0, stream>>>(ei, E, E2, cnt, pos);
    scan1_kernel<<<nb, 256, 0, stream>>>(cnt, rs, bsum, N);
    scan2_kernel<<<1, 1024, 0, stream>>>(bsum, nb);
    scan3_kernel<<<nb, 256, 0, stream>>>(rs, cnt, bsum, N);
    scatter_kernel<<<(E2 + 255) / 256, 256, 0, stream>>>(ei, E, E2, rs, pos, srclist);

    int gx = (N + 63) / 64;

    // ---- encoder -> bufA (item h1 -> bufB, con h1 -> bufC, both bf16)
    enc_h1_kernel<<<(N * 64 + 255) / 256, 256, 0, stream>>>(x, ew1, eb1, cw1, cb1,
                                                            bufB, bufC, N);
    gemm_mfma_kernel<128, 0><<<gx, 256, 0, stream>>>(
        bufB, ew2, eb2, nullptr, bufA, nullptr, nullptr, nullptr, nullptr,
        nullptr, nullptr, nullptr, N, 1);
    gemm_mfma_kernel<128, 0><<<gx, 256, 0, stream>>>(
        bufC, cw2, cb2, types, bufA, nullptr, nullptr, nullptr, nullptr,
        nullptr, nullptr, nullptr, N, 2);

    // ---- GAT layers (out never aliases hl=bufB)
    // layer 0: h0 = relu(gat(h))            bufA -> bufA
    gat_layer<4>(bufA, lin0, as0, ad0, b0, nullptr, bufB, bufA,
                 a_s, a_d, ex, dinv, rs, cnt, srclist, N, stream);
    // layer 1: h1 = h0 + relu(gat(h0))      bufA -> bufC
    gat_layer<4>(bufA, lin1, as1, ad1, b1, bufA, bufB, bufC,
                 a_s, a_d, ex, dinv, rs, cnt, srclist, N, stream);
    // layer 2: h2 = h1 + relu(gat(h1))      bufC -> bufA  (1 head, mean=identity)
    gat_layer<1>(bufC, lin2, as2, ad2, b2, bufC, bufB, bufA,
                 a_s, a_d, ex, dinv, rs, cnt, srclist, N, stream);

    // ---- decoder: d1 -> bufC ; d2 GEMM fused with final dot/sigmoid/mask
    gemm_mfma_kernel<128, 0><<<gx, 256, 0, stream>>>(
        bufA, dw1, db1, nullptr, bufC, nullptr, nullptr, nullptr, nullptr,
        nullptr, nullptr, nullptr, N, 1);
    gemm_mfma_kernel<64, 0><<<gx, 256, 0, stream>>>(
        bufC, dw2, db2, types, nullptr, nullptr, nullptr, nullptr, nullptr,
        dw3, db3, (float*)d_out, N, 3);
}

// Round 12
// 550.583 us; speedup vs baseline: 9.9608x; 1.0254x over previous
//
#include <hip/hip_runtime.h>
#include <math.h>

#define HIDDEN 128
#define NEG_SLOPE 0.2f

typedef unsigned short u16;
typedef __attribute__((ext_vector_type(8))) short bf16x8;
typedef __attribute__((ext_vector_type(4))) float f32x4;

__device__ __forceinline__ u16 f2bf(float f) {
    unsigned u = __float_as_uint(f);
    unsigned r = (u + 0x7FFFu + ((u >> 16) & 1u)) >> 16;   // round-nearest-even
    return (u16)r;
}
__device__ __forceinline__ float bf2f(u16 u) {
    return __uint_as_float((unsigned)u << 16);
}
__device__ __forceinline__ unsigned pack2(float a, float b) {
    return (unsigned)f2bf(a) | ((unsigned)f2bf(b) << 16);
}
__device__ __forceinline__ float lo16f(unsigned v) { return bf2f((u16)v); }
__device__ __forceinline__ float hi16f(unsigned v) { return bf2f((u16)(v >> 16)); }

// ============ one-shot fp32 -> bf16 weight conversion =========================
// 6 matrices of 16384 elements (ew2,cw2,lin0,lin1,lin2,dw1) + dw2 (8192),
// concatenated into wb. Processed as u32 pairs.
struct WPtrs { const float* p[7]; };
__global__ void convw_kernel(WPtrs wp, unsigned* __restrict__ wb, int totalPairs) {
    int i = blockIdx.x * blockDim.x + threadIdx.x;   // pair index
    if (i >= totalPairs) return;
    int e = i * 2;
    int seg, off;
    if (e < 98304) { seg = e >> 14; off = e & 16383; }
    else           { seg = 6;       off = e - 98304; }
    const float* s = wp.p[seg];
    wb[i] = pack2(s[off], s[off + 1]);
}

// ============ MFMA bf16 GEMM + fused epilogues ================================
// X bf16 [N,128]; Wb bf16 [OUT,128] (pre-converted); out bf16 [N,OUT].
// mode 0: raw store          mode 1: relu(acc+bias)
// mode 2: relu(acc+bias); type==0 -> keep prev(out), type==1 -> v, else 0
// mode 3 (OUT=64): relu(acc+bias) -> dot dw3 -> sigmoid -> mask -> fout[N]
// DH > 0: additionally compute a_s/a_d attention dots (DH heads) from acc.
template <int OUT, int DH>
__global__ __launch_bounds__(256) void gemm_mfma_kernel(
        const u16* __restrict__ X, const u16* __restrict__ Wb,
        const float* __restrict__ bias, const int* __restrict__ types,
        u16* __restrict__ out, float* __restrict__ a_s, float* __restrict__ a_d,
        const float* __restrict__ att_s, const float* __restrict__ att_d,
        const float* __restrict__ dw3, const float* __restrict__ db3,
        float* __restrict__ fout, int N, int mode) {
    constexpr int NT = OUT / 16;
    __shared__ u16 Xs[64 * 136];
    __shared__ u16 Ws[OUT * 136];
    const int tid = threadIdx.x;
    const int n0 = blockIdx.x * 64;

    // stage X tile (64 rows x 128 bf16): straight 16B copies
#pragma unroll
    for (int r = 0; r < 4; r++) {
        int j = r * 256 + tid;
        int row = j >> 4, c8 = (j & 15) << 3;
        int n = n0 + row;
        uint4 v = make_uint4(0u, 0u, 0u, 0u);
        if (n < N) v = *(const uint4*)&X[(size_t)n * 128 + c8];
        *(uint4*)&Xs[row * 136 + c8] = v;
    }
    // stage W (OUT rows x 128 bf16): straight 16B copies
#pragma unroll
    for (int r = 0; r < NT; r++) {
        int j = r * 256 + tid;
        int row = j >> 4, c8 = (j & 15) << 3;
        *(uint4*)&Ws[row * 136 + c8] = *(const uint4*)&Wb[(size_t)row * 128 + c8];
    }
    __syncthreads();

    const int w = tid >> 6, lane = tid & 63;
    const int qd = lane >> 4, lr = lane & 15;

    f32x4 acc[NT];
#pragma unroll
    for (int j = 0; j < NT; j++) acc[j] = (f32x4){0.f, 0.f, 0.f, 0.f};

#pragma unroll
    for (int k = 0; k < 4; k++) {
        bf16x8 a = *(const bf16x8*)&Xs[(w * 16 + lr) * 136 + k * 32 + qd * 8];
#pragma unroll
        for (int j = 0; j < NT; j++) {
            bf16x8 b = *(const bf16x8*)&Ws[(j * 16 + lr) * 136 + k * 32 + qd * 8];
            acc[j] = __builtin_amdgcn_mfma_f32_16x16x32_bf16(a, b, acc[j], 0, 0, 0);
        }
    }

    // D mapping: col = j*16 + lr, row = n0 + w*16 + qd*4 + r
    if (mode == 3) {
        float pr[4] = {0.f, 0.f, 0.f, 0.f};
#pragma unroll
        for (int j = 0; j < NT; j++) {
            int col = j * 16 + lr;
            float b = bias[col], wv = dw3[col];
#pragma unroll
            for (int r = 0; r < 4; r++) pr[r] += fmaxf(acc[j][r] + b, 0.f) * wv;
        }
#pragma unroll
        for (int m = 1; m < 16; m <<= 1)
#pragma unroll
            for (int r = 0; r < 4; r++) pr[r] += __shfl_xor(pr[r], m, 64);
        if (lr == 0) {
            float b3 = db3[0];
#pragma unroll
            for (int r = 0; r < 4; r++) {
                int row = n0 + w * 16 + qd * 4 + r;
                if (row < N) {
                    float prob = 1.f / (1.f + expf(-(pr[r] + b3)));
                    fout[row] = (types[row] == 0) ? prob : 0.f;
                }
            }
        }
        return;
    }

    // attention dots epilogue (for hl GEMMs)
    if (DH > 0) {
        constexpr int NH = (DH == 4) ? 4 : 1;
        float sp[NH][4], dp[NH][4];
#pragma unroll
        for (int h = 0; h < NH; h++)
#pragma unroll
            for (int r = 0; r < 4; r++) { sp[h][r] = 0.f; dp[h][r] = 0.f; }
#pragma unroll
        for (int j = 0; j < NT; j++) {
            int col = j * 16 + lr;
            float as_ = att_s[col], ad_ = att_d[col];
            int h = (DH == 4) ? (j >> 1) : 0;
#pragma unroll
            for (int r = 0; r < 4; r++) {
                sp[h][r] += acc[j][r] * as_;
                dp[h][r] += acc[j][r] * ad_;
            }
        }
#pragma unroll
        for (int m = 1; m < 16; m <<= 1)
#pragma unroll
            for (int h = 0; h < NH; h++)
#pragma unroll
                for (int r = 0; r < 4; r++) {
                    sp[h][r] += __shfl_xor(sp[h][r], m, 64);
                    dp[h][r] += __shfl_xor(dp[h][r], m, 64);
                }
        if (lr == 0) {
#pragma unroll
            for (int r = 0; r < 4; r++) {
                int row = n0 + w * 16 + qd * 4 + r;
                if (row < N) {
#pragma unroll
                    for (int h = 0; h < NH; h++) {
                        a_s[row * DH + h] = sp[h][r];
                        a_d[row * DH + h] = dp[h][r];
                    }
                }
            }
        }
    }

    // store epilogue
#pragma unroll
    for (int r = 0; r < 4; r++) {
        int row = n0 + w * 16 + qd * 4 + r;
        if (row >= N) continue;
        int ty = (mode == 2) ? types[row] : 0;
        if (mode == 2 && ty == 0) continue;   // keep item value written earlier
#pragma unroll
        for (int j = 0; j < NT; j++) {
            int col = j * 16 + lr;
            float v = acc[j][r];
            if (mode >= 1) v = fmaxf(v + bias[col], 0.f);
            if (mode == 2 && ty != 1) v = 0.f;
            out[(size_t)row * OUT + col] = f2bf(v);
        }
    }
}

// ============ encoder layer-1 (elementwise, both types, bf16 out) =============
__global__ void enc_h1_kernel(const float* __restrict__ x,
                              const float* __restrict__ ew1, const float* __restrict__ eb1,
                              const float* __restrict__ cw1, const float* __restrict__ cb1,
                              u16* __restrict__ h1_item, u16* __restrict__ h1_con, int N) {
    int i = blockIdx.x * blockDim.x + threadIdx.x;
    if (i >= N * 64) return;
    int n = i >> 6, t = (i & 63) * 2;
    float x0 = x[2 * n], x1 = x[2 * n + 1];
    float i0 = fmaxf(ew1[2 * t] * x0 + ew1[2 * t + 1] * x1 + eb1[t], 0.f);
    float i1 = fmaxf(ew1[2 * t + 2] * x0 + ew1[2 * t + 3] * x1 + eb1[t + 1], 0.f);
    float c0 = fmaxf(cw1[t] * x0 + cb1[t], 0.f);
    float c1 = fmaxf(cw1[t + 1] * x0 + cb1[t + 1], 0.f);
    *(unsigned*)&h1_item[(size_t)n * 128 + t] = pack2(i0, i1);
    *(unsigned*)&h1_con[(size_t)n * 128 + t]  = pack2(c0, c1);
}

// ============ CSR build ========================================================
__global__ void zero1_kernel(int* __restrict__ a, int N) {
    int i = blockIdx.x * blockDim.x + threadIdx.x;
    if (i < N) a[i] = 0;
}

__global__ void hist_kernel(const int* __restrict__ ei, int E, int E2,
                            int* __restrict__ cnt, int* __restrict__ pos) {
    int e = blockIdx.x * blockDim.x + threadIdx.x;
    if (e >= E2) return;
    int d = (e < E) ? ei[E + e] : e - E;
    pos[e] = atomicAdd(&cnt[d], 1);
}

__global__ void scan1_kernel(const int* __restrict__ cnt, int* __restrict__ rs,
                             int* __restrict__ bsum, int N) {
    __shared__ int s[256];
    int i = blockIdx.x * 256 + threadIdx.x;
    int v = (i < N) ? cnt[i] : 0;
    s[threadIdx.x] = v;
    __syncthreads();
    for (int off = 1; off < 256; off <<= 1) {
        int t = (threadIdx.x >= off) ? s[threadIdx.x - off] : 0;
        __syncthreads();
        s[threadIdx.x] += t;
        __syncthreads();
    }
    if (i < N) rs[i] = s[threadIdx.x];
    if (threadIdx.x == 255) bsum[blockIdx.x] = s[255];
}

__global__ void scan2_kernel(int* __restrict__ bsum, int nb) {
    __shared__ int s[1024];
    int i = threadIdx.x;
    int v = (i < nb) ? bsum[i] : 0;
    s[i] = v;
    __syncthreads();
    for (int off = 1; off < 1024; off <<= 1) {
        int t = (i >= off) ? s[i - off] : 0;
        __syncthreads();
        s[i] += t;
        __syncthreads();
    }
    if (i < nb) bsum[i] = s[i] - v;
}

__global__ void scan3_kernel(int* __restrict__ rs, const int* __restrict__ cnt,
                             const int* __restrict__ bsum, int N) {
    int i = blockIdx.x * 256 + threadIdx.x;
    if (i < N) rs[i] = rs[i] - cnt[i] + bsum[blockIdx.x];
}

__global__ void scatter_kernel(const int* __restrict__ ei, int E, int E2,
                               const int* __restrict__ rs, const int* __restrict__ pos,
                               int* __restrict__ srclist) {
    int e = blockIdx.x * blockDim.x + threadIdx.x;
    if (e >= E2) return;
    int s, d;
    if (e < E) { s = ei[e]; d = ei[E + e]; }
    else       { s = d = e - E; }
    srclist[rs[d] + pos[e]] = s;
}

// ============ attention coefficients: single-pass (shift-invariant softmax) ====
template <int H>
__global__ void att_kernel(const int* __restrict__ rs, const int* __restrict__ cnt,
                           const int* __restrict__ srclist,
                           const float* __restrict__ a_s, const float* __restrict__ a_d,
                           float* __restrict__ ex, float* __restrict__ dinv, int N) {
    int i = blockIdx.x * blockDim.x + threadIdx.x;
    if (i >= N * H) return;
    int n = (H == 1) ? i : (i >> 2);
    int h = (H == 1) ? 0 : (i & 3);
    int beg = rs[n], deg = cnt[n];
    float ad = a_d[i];
    float l = 0.f;
    for (int k = 0; k < deg; k++) {
        float al = a_s[srclist[beg + k] * H + h] + ad;
        al = (al > 0.f) ? al : NEG_SLOPE * al;
        float p = expf(fminf(al, 80.f));
        ex[(beg + k) * H + h] = p;
        l += p;
    }
    dinv[i] = 1.f / l;   // deg >= 1 (self-loop)
}

// ============ GAT aggregation: 16B/lane gather, 8 edges per wave-step =========
// wave = node. lane l: edge-group g=l>>4, feature-chunk c=l&15 (8 bf16 = 16B).
// NOTE: `out` must NEVER alias `hl`.
template <int H>
__global__ __launch_bounds__(256) void gat_agg_kernel(
        const int* __restrict__ rs, const int* __restrict__ cnt,
        const int* __restrict__ srclist, const u16* __restrict__ hl,
        const float* __restrict__ ex, const float* __restrict__ dinv,
        const float* __restrict__ bias, const u16* __restrict__ res,
        u16* __restrict__ out, int N) {
    int n = blockIdx.x * 4 + (threadIdx.x >> 6);
    int l = threadIdx.x & 63;
    if (n >= N) return;
    const int g = l >> 4;          // edge group 0..3
    const int c = l & 15;          // feature chunk (features 8c..8c+7)
    const int head = (H == 1) ? 0 : (c >> 2);
    const int beg = rs[n];
    const int deg = cnt[n];
    float acc0[8], acc1[8];
#pragma unroll
    for (int j = 0; j < 8; j++) { acc0[j] = 0.f; acc1[j] = 0.f; }

    for (int k = 0; k < deg; k += 8) {
        int i0 = k + g;
        int i1 = k + 4 + g;
        int e0 = beg + min(i0, deg - 1);
        int e1 = beg + min(i1, deg - 1);
        int s0 = srclist[e0];
        int s1 = srclist[e1];
        float p0 = ex[e0 * H + head];
        float p1 = ex[e1 * H + head];
        if (i0 >= deg) p0 = 0.f;
        if (i1 >= deg) p1 = 0.f;
        uint4 v0 = *(const uint4*)&hl[(size_t)s0 * 128 + 8 * c];
        uint4 v1 = *(const uint4*)&hl[(size_t)s1 * 128 + 8 * c];
        acc0[0] += p0 * lo16f(v0.x); acc0[1] += p0 * hi16f(v0.x);
        acc0[2] += p0 * lo16f(v0.y); acc0[3] += p0 * hi16f(v0.y);
        acc0[4] += p0 * lo16f(v0.z); acc0[5] += p0 * hi16f(v0.z);
        acc0[6] += p0 * lo16f(v0.w); acc0[7] += p0 * hi16f(v0.w);
        acc1[0] += p1 * lo16f(v1.x); acc1[1] += p1 * hi16f(v1.x);
        acc1[2] += p1 * lo16f(v1.y); acc1[3] += p1 * hi16f(v1.y);
        acc1[4] += p1 * lo16f(v1.z); acc1[5] += p1 * hi16f(v1.z);
        acc1[6] += p1 * lo16f(v1.w); acc1[7] += p1 * hi16f(v1.w);
    }
#pragma unroll
    for (int j = 0; j < 8; j++) {
        float a = acc0[j] + acc1[j];
        a += __shfl_xor(a, 16, 64);
        a += __shfl_xor(a, 32, 64);
        acc0[j] = a;
    }
    if (g == 0) {   // lanes 0..15 hold the full sums for their 8 features
        float di = dinv[n * H + head];
        float4 b0 = *(const float4*)&bias[8 * c];
        float4 b1 = *(const float4*)&bias[8 * c + 4];
        float o[8];
        o[0] = fmaxf(acc0[0] * di + b0.x, 0.f);
        o[1] = fmaxf(acc0[1] * di + b0.y, 0.f);
        o[2] = fmaxf(acc0[2] * di + b0.z, 0.f);
        o[3] = fmaxf(acc0[3] * di + b0.w, 0.f);
        o[4] = fmaxf(acc0[4] * di + b1.x, 0.f);
        o[5] = fmaxf(acc0[5] * di + b1.y, 0.f);
        o[6] = fmaxf(acc0[6] * di + b1.z, 0.f);
        o[7] = fmaxf(acc0[7] * di + b1.w, 0.f);
        if (res) {
            uint4 rv = *(const uint4*)&res[(size_t)n * 128 + 8 * c];
            o[0] += lo16f(rv.x); o[1] += hi16f(rv.x);
            o[2] += lo16f(rv.y); o[3] += hi16f(rv.y);
            o[4] += lo16f(rv.z); o[5] += hi16f(rv.z);
            o[6] += lo16f(rv.w); o[7] += hi16f(rv.w);
        }
        uint4 ov = make_uint4(pack2(o[0], o[1]), pack2(o[2], o[3]),
                              pack2(o[4], o[5]), pack2(o[6], o[7]));
        *(uint4*)&out[(size_t)n * 128 + 8 * c] = ov;
    }
}

// ============ host-side layer driver ==========================================
template <int H>
static void gat_layer(const u16* X, const u16* lin, const float* as_, const float* ad_,
                      const float* bias, const u16* res, u16* hl, u16* outb,
                      float* a_s, float* a_d, float* ex, float* dinv,
                      const int* rs, const int* cnt, const int* srclist,
                      int N, hipStream_t stream) {
    int gx = (N + 63) / 64;
    gemm_mfma_kernel<128, H><<<gx, 256, 0, stream>>>(
        X, lin, nullptr, nullptr, hl, a_s, a_d, as_, ad_, nullptr, nullptr, nullptr, N, 0);
    att_kernel<H><<<(N * H + 255) / 256, 256, 0, stream>>>(rs, cnt, srclist, a_s, a_d,
                                                           ex, dinv, N);
    gat_agg_kernel<H><<<(N + 3) / 4, 256, 0, stream>>>(rs, cnt, srclist, hl, ex, dinv,
                                                       bias, res, outb, N);
}

extern "C" void kernel_launch(void* const* d_in, const int* in_sizes, int n_in,
                              void* d_out, int out_size, void* d_ws, size_t ws_size,
                              hipStream_t stream) {
    const float* x     = (const float*)d_in[0];
    const int*   types = (const int*)d_in[1];
    const int*   ei    = (const int*)d_in[2];   // int64 in reference -> int32 on device
    const float* ew1 = (const float*)d_in[3];
    const float* eb1 = (const float*)d_in[4];
    const float* ew2 = (const float*)d_in[5];
    const float* eb2 = (const float*)d_in[6];
    const float* cw1 = (const float*)d_in[7];
    const float* cb1 = (const float*)d_in[8];
    const float* cw2 = (const float*)d_in[9];
    const float* cb2 = (const float*)d_in[10];
    const float* lin0 = (const float*)d_in[11];
    const float* as0  = (const float*)d_in[12];
    const float* ad0  = (const float*)d_in[13];
    const float* b0   = (const float*)d_in[14];
    const float* lin1 = (const float*)d_in[15];
    const float* as1  = (const float*)d_in[16];
    const float* ad1  = (const float*)d_in[17];
    const float* b1   = (const float*)d_in[18];
    const float* lin2 = (const float*)d_in[19];
    const float* as2  = (const float*)d_in[20];
    const float* ad2  = (const float*)d_in[21];
    const float* b2   = (const float*)d_in[22];
    const float* dw1 = (const float*)d_in[23];
    const float* db1 = (const float*)d_in[24];
    const float* dw2 = (const float*)d_in[25];
    const float* db2 = (const float*)d_in[26];
    const float* dw3 = (const float*)d_in[27];
    const float* db3 = (const float*)d_in[28];

    int N  = in_sizes[1];
    int E  = in_sizes[2] / 2;
    int E2 = E + N;

    size_t NF = (size_t)N * HIDDEN;
    u16* bufA = (u16*)d_ws;          // bf16 feature buffers
    u16* bufB = bufA + NF;
    u16* bufC = bufB + NF;
    float* fbase = (float*)(bufC + NF);
    float* a_s  = fbase;
    float* a_d  = a_s + (size_t)N * 4;
    float* dinv = a_d + (size_t)N * 4;
    float* ex   = dinv + (size_t)N * 4;             // E2*4 floats
    int* rs      = (int*)(ex + (size_t)E2 * 4);
    int* cnt     = rs + N;
    int* pos     = cnt + N;             // E2 entries
    int* bsum    = pos + E2;            // up to 1024 entries
    int* srclist = bsum + 1024;         // E2 entries
    u16* wb      = (u16*)(srclist + E2);  // 106496 bf16 pre-converted weights
    u16* wb_ew2  = wb;
    u16* wb_cw2  = wb + 16384;
    u16* wb_lin0 = wb + 32768;
    u16* wb_lin1 = wb + 49152;
    u16* wb_lin2 = wb + 65536;
    u16* wb_dw1  = wb + 81920;
    u16* wb_dw2  = wb + 98304;

    int nb = (N + 255) / 256;

    // ---- weight pre-convert (one dispatch, 53248 u32 pairs)
    WPtrs wp;
    wp.p[0] = ew2; wp.p[1] = cw2; wp.p[2] = lin0; wp.p[3] = lin1;
    wp.p[4] = lin2; wp.p[5] = dw1; wp.p[6] = dw2;
    convw_kernel<<<(53248 + 255) / 256, 256, 0, stream>>>(wp, (unsigned*)wb, 53248);

    // ---- CSR build (edge structure shared by all 3 layers)
    zero1_kernel<<<nb, 256, 0, stream>>>(cnt, N);
    hist_kernel<<<(E2 + 255) / 256, 256, 0, stream>>>(ei, E, E2, cnt, pos);
    scan1_kernel<<<nb, 256, 0, stream>>>(cnt, rs, bsum, N);
    scan2_kernel<<<1, 1024, 0, stream>>>(bsum, nb);
    scan3_kernel<<<nb, 256, 0, stream>>>(rs, cnt, bsum, N);
    scatter_kernel<<<(E2 + 255) / 256, 256, 0, stream>>>(ei, E, E2, rs, pos, srclist);

    int gx = (N + 63) / 64;

    // ---- encoder -> bufA (item h1 -> bufB, con h1 -> bufC, both bf16)
    enc_h1_kernel<<<(N * 64 + 255) / 256, 256, 0, stream>>>(x, ew1, eb1, cw1, cb1,
                                                            bufB, bufC, N);
    gemm_mfma_kernel<128, 0><<<gx, 256, 0, stream>>>(
        bufB, wb_ew2, eb2, nullptr, bufA, nullptr, nullptr, nullptr, nullptr,
        nullptr, nullptr, nullptr, N, 1);
    gemm_mfma_kernel<128, 0><<<gx, 256, 0, stream>>>(
        bufC, wb_cw2, cb2, types, bufA, nullptr, nullptr, nullptr, nullptr,
        nullptr, nullptr, nullptr, N, 2);

    // ---- GAT layers (out never aliases hl=bufB)
    // layer 0: h0 = relu(gat(h))            bufA -> bufA
    gat_layer<4>(bufA, wb_lin0, as0, ad0, b0, nullptr, bufB, bufA,
                 a_s, a_d, ex, dinv, rs, cnt, srclist, N, stream);
    // layer 1: h1 = h0 + relu(gat(h0))      bufA -> bufC
    gat_layer<4>(bufA, wb_lin1, as1, ad1, b1, bufA, bufB, bufC,
                 a_s, a_d, ex, dinv, rs, cnt, srclist, N, stream);
    // layer 2: h2 = h1 + relu(gat(h1))      bufC -> bufA  (1 head, mean=identity)
    gat_layer<1>(bufC, wb_lin2, as2, ad2, b2, bufC, bufB, bufA,
                 a_s, a_d, ex, dinv, rs, cnt, srclist, N, stream);

    // ---- decoder: d1 -> bufC ; d2 GEMM fused with final dot/sigmoid/mask
    gemm_mfma_kernel<128, 0><<<gx, 256, 0, stream>>>(
        bufA, wb_dw1, db1, nullptr, bufC, nullptr, nullptr, nullptr, nullptr,
        nullptr, nullptr, nullptr, N, 1);
    gemm_mfma_kernel<64, 0><<<gx, 256, 0, stream>>>(
        bufC, wb_dw2, db2, types, nullptr, nullptr, nullptr, nullptr, nullptr,
        dw3, db3, (float*)d_out, N, 3);
}

// Round 13
// 512.457 us; speedup vs baseline: 10.7019x; 1.0744x over previous
//
#include <hip/hip_runtime.h>
#include <math.h>

#define HIDDEN 128
#define NEG_SLOPE 0.2f

typedef unsigned short u16;
typedef __attribute__((ext_vector_type(8))) short bf16x8;
typedef __attribute__((ext_vector_type(4))) float f32x4;

__device__ __forceinline__ u16 f2bf(float f) {
    unsigned u = __float_as_uint(f);
    unsigned r = (u + 0x7FFFu + ((u >> 16) & 1u)) >> 16;   // round-nearest-even
    return (u16)r;
}
__device__ __forceinline__ float bf2f(u16 u) {
    return __uint_as_float((unsigned)u << 16);
}
__device__ __forceinline__ unsigned pack2(float a, float b) {
    return (unsigned)f2bf(a) | ((unsigned)f2bf(b) << 16);
}
__device__ __forceinline__ float lo16f(unsigned v) { return bf2f((u16)v); }
__device__ __forceinline__ float hi16f(unsigned v) { return bf2f((u16)(v >> 16)); }

// ============ fp32->bf16 weight conversion + cnt zeroing (one dispatch) =======
struct WPtrs { const float* p[7]; };
__global__ void convw_zero_kernel(WPtrs wp, unsigned* __restrict__ wb, int totalPairs,
                                  int* __restrict__ cnt, int N) {
    int i = blockIdx.x * blockDim.x + threadIdx.x;
    if (i < N) cnt[i] = 0;
    if (i < totalPairs) {
        int e = i * 2;
        int seg, off;
        if (e < 98304) { seg = e >> 14; off = e & 16383; }
        else           { seg = 6;       off = e - 98304; }
        const float* s = wp.p[seg];
        wb[i] = pack2(s[off], s[off + 1]);
    }
}

// ============ fused encoder: x -> h1(item/con) -> GEMM both -> type select ====
// One block = 64 nodes. Two sequential MFMA passes sharing LDS.
__global__ __launch_bounds__(256) void encoder_kernel(
        const float* __restrict__ x, const int* __restrict__ types,
        const float* __restrict__ ew1, const float* __restrict__ eb1,
        const float* __restrict__ cw1, const float* __restrict__ cb1,
        const u16* __restrict__ wb_ew2, const u16* __restrict__ wb_cw2,
        const float* __restrict__ eb2, const float* __restrict__ cb2,
        u16* __restrict__ out, int N) {
    __shared__ u16 Xs[64 * 136];
    __shared__ u16 Ws[128 * 136];
    __shared__ float xsh[128];
    __shared__ float w1sh[640];   // ew1(256) eb1(128) cw1(128) cb1(128)
    const int tid = threadIdx.x;
    const int n0 = blockIdx.x * 64;

    if (tid < 128) {
        int n = n0 + (tid >> 1);
        xsh[tid] = (n < N) ? x[2 * n + (tid & 1)] : 0.f;
    }
    if (tid < 256) w1sh[tid] = ew1[tid];
    if (tid < 128) { w1sh[256 + tid] = eb1[tid]; w1sh[384 + tid] = cw1[tid];
                     w1sh[512 + tid] = cb1[tid]; }
    __syncthreads();

    // ---- pass 1: item path
#pragma unroll
    for (int r = 0; r < 32; r++) {
        int j = tid + 256 * r;
        int row = j >> 7, t = j & 127;
        float v = fmaxf(w1sh[2 * t] * xsh[2 * row] + w1sh[2 * t + 1] * xsh[2 * row + 1]
                        + w1sh[256 + t], 0.f);
        Xs[row * 136 + t] = f2bf(v);
    }
#pragma unroll
    for (int r = 0; r < 8; r++) {
        int j = r * 256 + tid;
        int row = j >> 4, c8 = (j & 15) << 3;
        *(uint4*)&Ws[row * 136 + c8] = *(const uint4*)&wb_ew2[(size_t)row * 128 + c8];
    }
    __syncthreads();

    const int w = tid >> 6, lane = tid & 63;
    const int qd = lane >> 4, lr = lane & 15;

    f32x4 acc_i[8], acc_c[8];
#pragma unroll
    for (int j = 0; j < 8; j++) acc_i[j] = (f32x4){0.f, 0.f, 0.f, 0.f};
#pragma unroll
    for (int k = 0; k < 4; k++) {
        bf16x8 a = *(const bf16x8*)&Xs[(w * 16 + lr) * 136 + k * 32 + qd * 8];
#pragma unroll
        for (int j = 0; j < 8; j++) {
            bf16x8 b = *(const bf16x8*)&Ws[(j * 16 + lr) * 136 + k * 32 + qd * 8];
            acc_i[j] = __builtin_amdgcn_mfma_f32_16x16x32_bf16(a, b, acc_i[j], 0, 0, 0);
        }
    }
    __syncthreads();   // all MFMA reads done before LDS reuse

    // ---- pass 2: con path
#pragma unroll
    for (int r = 0; r < 32; r++) {
        int j = tid + 256 * r;
        int row = j >> 7, t = j & 127;
        float v = fmaxf(w1sh[384 + t] * xsh[2 * row] + w1sh[512 + t], 0.f);
        Xs[row * 136 + t] = f2bf(v);
    }
#pragma unroll
    for (int r = 0; r < 8; r++) {
        int j = r * 256 + tid;
        int row = j >> 4, c8 = (j & 15) << 3;
        *(uint4*)&Ws[row * 136 + c8] = *(const uint4*)&wb_cw2[(size_t)row * 128 + c8];
    }
    __syncthreads();
#pragma unroll
    for (int j = 0; j < 8; j++) acc_c[j] = (f32x4){0.f, 0.f, 0.f, 0.f};
#pragma unroll
    for (int k = 0; k < 4; k++) {
        bf16x8 a = *(const bf16x8*)&Xs[(w * 16 + lr) * 136 + k * 32 + qd * 8];
#pragma unroll
        for (int j = 0; j < 8; j++) {
            bf16x8 b = *(const bf16x8*)&Ws[(j * 16 + lr) * 136 + k * 32 + qd * 8];
            acc_c[j] = __builtin_amdgcn_mfma_f32_16x16x32_bf16(a, b, acc_c[j], 0, 0, 0);
        }
    }

    // ---- epilogue: per-row type select
#pragma unroll
    for (int r = 0; r < 4; r++) {
        int row = n0 + w * 16 + qd * 4 + r;
        if (row >= N) continue;
        int ty = types[row];
#pragma unroll
        for (int j = 0; j < 8; j++) {
            int col = j * 16 + lr;
            float v;
            if (ty == 0)      v = fmaxf(acc_i[j][r] + eb2[col], 0.f);
            else if (ty == 1) v = fmaxf(acc_c[j][r] + cb2[col], 0.f);
            else              v = 0.f;
            out[(size_t)row * HIDDEN + col] = f2bf(v);
        }
    }
}

// ============ MFMA bf16 GEMM + fused epilogues ================================
// mode 0: raw store  mode 1: relu(acc+bias)
// mode 3 (OUT=64): relu(acc+bias) -> dot dw3 -> sigmoid -> mask -> fout[N]
// DH > 0: also compute a_s/a_d attention dots (DH heads) from acc.
template <int OUT, int DH>
__global__ __launch_bounds__(256) void gemm_mfma_kernel(
        const u16* __restrict__ X, const u16* __restrict__ Wb,
        const float* __restrict__ bias, const int* __restrict__ types,
        u16* __restrict__ out, float* __restrict__ a_s, float* __restrict__ a_d,
        const float* __restrict__ att_s, const float* __restrict__ att_d,
        const float* __restrict__ dw3, const float* __restrict__ db3,
        float* __restrict__ fout, int N, int mode) {
    constexpr int NT = OUT / 16;
    __shared__ u16 Xs[64 * 136];
    __shared__ u16 Ws[OUT * 136];
    const int tid = threadIdx.x;
    const int n0 = blockIdx.x * 64;

#pragma unroll
    for (int r = 0; r < 4; r++) {
        int j = r * 256 + tid;
        int row = j >> 4, c8 = (j & 15) << 3;
        int n = n0 + row;
        uint4 v = make_uint4(0u, 0u, 0u, 0u);
        if (n < N) v = *(const uint4*)&X[(size_t)n * 128 + c8];
        *(uint4*)&Xs[row * 136 + c8] = v;
    }
#pragma unroll
    for (int r = 0; r < NT; r++) {
        int j = r * 256 + tid;
        int row = j >> 4, c8 = (j & 15) << 3;
        *(uint4*)&Ws[row * 136 + c8] = *(const uint4*)&Wb[(size_t)row * 128 + c8];
    }
    __syncthreads();

    const int w = tid >> 6, lane = tid & 63;
    const int qd = lane >> 4, lr = lane & 15;

    f32x4 acc[NT];
#pragma unroll
    for (int j = 0; j < NT; j++) acc[j] = (f32x4){0.f, 0.f, 0.f, 0.f};

#pragma unroll
    for (int k = 0; k < 4; k++) {
        bf16x8 a = *(const bf16x8*)&Xs[(w * 16 + lr) * 136 + k * 32 + qd * 8];
#pragma unroll
        for (int j = 0; j < NT; j++) {
            bf16x8 b = *(const bf16x8*)&Ws[(j * 16 + lr) * 136 + k * 32 + qd * 8];
            acc[j] = __builtin_amdgcn_mfma_f32_16x16x32_bf16(a, b, acc[j], 0, 0, 0);
        }
    }

    // D mapping: col = j*16 + lr, row = n0 + w*16 + qd*4 + r
    if (mode == 3) {
        float pr[4] = {0.f, 0.f, 0.f, 0.f};
#pragma unroll
        for (int j = 0; j < NT; j++) {
            int col = j * 16 + lr;
            float b = bias[col], wv = dw3[col];
#pragma unroll
            for (int r = 0; r < 4; r++) pr[r] += fmaxf(acc[j][r] + b, 0.f) * wv;
        }
#pragma unroll
        for (int m = 1; m < 16; m <<= 1)
#pragma unroll
            for (int r = 0; r < 4; r++) pr[r] += __shfl_xor(pr[r], m, 64);
        if (lr == 0) {
            float b3 = db3[0];
#pragma unroll
            for (int r = 0; r < 4; r++) {
                int row = n0 + w * 16 + qd * 4 + r;
                if (row < N) {
                    float prob = 1.f / (1.f + expf(-(pr[r] + b3)));
                    fout[row] = (types[row] == 0) ? prob : 0.f;
                }
            }
        }
        return;
    }

    if (DH > 0) {
        constexpr int NH = (DH == 4) ? 4 : 1;
        float sp[NH][4], dp[NH][4];
#pragma unroll
        for (int h = 0; h < NH; h++)
#pragma unroll
            for (int r = 0; r < 4; r++) { sp[h][r] = 0.f; dp[h][r] = 0.f; }
#pragma unroll
        for (int j = 0; j < NT; j++) {
            int col = j * 16 + lr;
            float as_ = att_s[col], ad_ = att_d[col];
            int h = (DH == 4) ? (j >> 1) : 0;
#pragma unroll
            for (int r = 0; r < 4; r++) {
                sp[h][r] += acc[j][r] * as_;
                dp[h][r] += acc[j][r] * ad_;
            }
        }
#pragma unroll
        for (int m = 1; m < 16; m <<= 1)
#pragma unroll
            for (int h = 0; h < NH; h++)
#pragma unroll
                for (int r = 0; r < 4; r++) {
                    sp[h][r] += __shfl_xor(sp[h][r], m, 64);
                    dp[h][r] += __shfl_xor(dp[h][r], m, 64);
                }
        if (lr == 0) {
#pragma unroll
            for (int r = 0; r < 4; r++) {
                int row = n0 + w * 16 + qd * 4 + r;
                if (row < N) {
#pragma unroll
                    for (int h = 0; h < NH; h++) {
                        a_s[row * DH + h] = sp[h][r];
                        a_d[row * DH + h] = dp[h][r];
                    }
                }
            }
        }
    }

#pragma unroll
    for (int r = 0; r < 4; r++) {
        int row = n0 + w * 16 + qd * 4 + r;
        if (row >= N) continue;
#pragma unroll
        for (int j = 0; j < NT; j++) {
            int col = j * 16 + lr;
            float v = acc[j][r];
            if (mode >= 1) v = fmaxf(v + bias[col], 0.f);
            out[(size_t)row * OUT + col] = f2bf(v);
        }
    }
}

// ============ CSR build ========================================================
__global__ void hist_kernel(const int* __restrict__ ei, int E, int E2,
                            int* __restrict__ cnt, int* __restrict__ pos) {
    int e = blockIdx.x * blockDim.x + threadIdx.x;
    if (e >= E2) return;
    int d = (e < E) ? ei[E + e] : e - E;
    pos[e] = atomicAdd(&cnt[d], 1);
}

__global__ void scan1_kernel(const int* __restrict__ cnt, int* __restrict__ rs,
                             int* __restrict__ bsum, int N) {
    __shared__ int s[256];
    int i = blockIdx.x * 256 + threadIdx.x;
    int v = (i < N) ? cnt[i] : 0;
    s[threadIdx.x] = v;
    __syncthreads();
    for (int off = 1; off < 256; off <<= 1) {
        int t = (threadIdx.x >= off) ? s[threadIdx.x - off] : 0;
        __syncthreads();
        s[threadIdx.x] += t;
        __syncthreads();
    }
    if (i < N) rs[i] = s[threadIdx.x];
    if (threadIdx.x == 255) bsum[blockIdx.x] = s[255];
}

// block b: prefix = sum(bsum[0..b-1]); rs[i] = rs_incl[i] - cnt[i] + prefix
__global__ void scan23_kernel(int* __restrict__ rs, const int* __restrict__ cnt,
                              const int* __restrict__ bsum, int N) {
    __shared__ int sdata[256];
    int b = blockIdx.x;
    int partial = 0;
    for (int i = threadIdx.x; i < b; i += 256) partial += bsum[i];
    sdata[threadIdx.x] = partial;
    __syncthreads();
    for (int off = 128; off; off >>= 1) {
        if (threadIdx.x < off) sdata[threadIdx.x] += sdata[threadIdx.x + off];
        __syncthreads();
    }
    int pre = sdata[0];
    int i = b * 256 + threadIdx.x;
    if (i < N) rs[i] = rs[i] - cnt[i] + pre;
}

__global__ void scatter_kernel(const int* __restrict__ ei, int E, int E2,
                               const int* __restrict__ rs, const int* __restrict__ pos,
                               int* __restrict__ srclist) {
    int e = blockIdx.x * blockDim.x + threadIdx.x;
    if (e >= E2) return;
    int s, d;
    if (e < E) { s = ei[e]; d = ei[E + e]; }
    else       { s = d = e - E; }
    srclist[rs[d] + pos[e]] = s;
}

// ============ attention coefficients: single-pass softmax =====================
template <int H>
__global__ void att_kernel(const int* __restrict__ rs, const int* __restrict__ cnt,
                           const int* __restrict__ srclist,
                           const float* __restrict__ a_s, const float* __restrict__ a_d,
                           float* __restrict__ ex, float* __restrict__ dinv, int N) {
    int i = blockIdx.x * blockDim.x + threadIdx.x;
    if (i >= N * H) return;
    int n = (H == 1) ? i : (i >> 2);
    int h = (H == 1) ? 0 : (i & 3);
    int beg = rs[n], deg = cnt[n];
    float ad = a_d[i];
    float l = 0.f;
    for (int k = 0; k < deg; k++) {
        float al = a_s[srclist[beg + k] * H + h] + ad;
        al = (al > 0.f) ? al : NEG_SLOPE * al;
        float p = expf(fminf(al, 80.f));
        ex[(beg + k) * H + h] = p;
        l += p;
    }
    dinv[i] = 1.f / l;   // deg >= 1 (self-loop)
}

// ============ GAT aggregation: 16B/lane gather, 12 edges per wave-step ========
// wave = node. lane l: edge-group g=l>>4, feature-chunk c=l&15 (8 bf16 = 16B).
// Three independent row loads per lane per iteration (most nodes: 1 iteration).
// NOTE: `out` must NEVER alias `hl`.
template <int H>
__global__ __launch_bounds__(256) void gat_agg_kernel(
        const int* __restrict__ rs, const int* __restrict__ cnt,
        const int* __restrict__ srclist, const u16* __restrict__ hl,
        const float* __restrict__ ex, const float* __restrict__ dinv,
        const float* __restrict__ bias, const u16* __restrict__ res,
        u16* __restrict__ out, int N) {
    int n = blockIdx.x * 4 + (threadIdx.x >> 6);
    int l = threadIdx.x & 63;
    if (n >= N) return;
    const int g = l >> 4;          // edge group 0..3
    const int c = l & 15;          // feature chunk (features 8c..8c+7)
    const int head = (H == 1) ? 0 : (c >> 2);
    const int beg = rs[n];
    const int deg = cnt[n];
    float acc0[8], acc1[8], acc2[8];
#pragma unroll
    for (int j = 0; j < 8; j++) { acc0[j] = 0.f; acc1[j] = 0.f; acc2[j] = 0.f; }

    for (int k = 0; k < deg; k += 12) {
        int i0 = k + g, i1 = k + 4 + g, i2 = k + 8 + g;
        int e0 = beg + min(i0, deg - 1);
        int e1 = beg + min(i1, deg - 1);
        int e2 = beg + min(i2, deg - 1);
        int s0 = srclist[e0], s1 = srclist[e1], s2 = srclist[e2];
        float p0 = ex[e0 * H + head];
        float p1 = ex[e1 * H + head];
        float p2 = ex[e2 * H + head];
        if (i0 >= deg) p0 = 0.f;
        if (i1 >= deg) p1 = 0.f;
        if (i2 >= deg) p2 = 0.f;
        uint4 v0 = *(const uint4*)&hl[(size_t)s0 * 128 + 8 * c];
        uint4 v1 = *(const uint4*)&hl[(size_t)s1 * 128 + 8 * c];
        uint4 v2 = *(const uint4*)&hl[(size_t)s2 * 128 + 8 * c];
        acc0[0] += p0 * lo16f(v0.x); acc0[1] += p0 * hi16f(v0.x);
        acc0[2] += p0 * lo16f(v0.y); acc0[3] += p0 * hi16f(v0.y);
        acc0[4] += p0 * lo16f(v0.z); acc0[5] += p0 * hi16f(v0.z);
        acc0[6] += p0 * lo16f(v0.w); acc0[7] += p0 * hi16f(v0.w);
        acc1[0] += p1 * lo16f(v1.x); acc1[1] += p1 * hi16f(v1.x);
        acc1[2] += p1 * lo16f(v1.y); acc1[3] += p1 * hi16f(v1.y);
        acc1[4] += p1 * lo16f(v1.z); acc1[5] += p1 * hi16f(v1.z);
        acc1[6] += p1 * lo16f(v1.w); acc1[7] += p1 * hi16f(v1.w);
        acc2[0] += p2 * lo16f(v2.x); acc2[1] += p2 * hi16f(v2.x);
        acc2[2] += p2 * lo16f(v2.y); acc2[3] += p2 * hi16f(v2.y);
        acc2[4] += p2 * lo16f(v2.z); acc2[5] += p2 * hi16f(v2.z);
        acc2[6] += p2 * lo16f(v2.w); acc2[7] += p2 * hi16f(v2.w);
    }
#pragma unroll
    for (int j = 0; j < 8; j++) {
        float a = acc0[j] + acc1[j] + acc2[j];
        a += __shfl_xor(a, 16, 64);
        a += __shfl_xor(a, 32, 64);
        acc0[j] = a;
    }
    if (g == 0) {   // lanes 0..15 hold the full sums for their 8 features
        float di = dinv[n * H + head];
        float4 b0 = *(const float4*)&bias[8 * c];
        float4 b1 = *(const float4*)&bias[8 * c + 4];
        float o[8];
        o[0] = fmaxf(acc0[0] * di + b0.x, 0.f);
        o[1] = fmaxf(acc0[1] * di + b0.y, 0.f);
        o[2] = fmaxf(acc0[2] * di + b0.z, 0.f);
        o[3] = fmaxf(acc0[3] * di + b0.w, 0.f);
        o[4] = fmaxf(acc0[4] * di + b1.x, 0.f);
        o[5] = fmaxf(acc0[5] * di + b1.y, 0.f);
        o[6] = fmaxf(acc0[6] * di + b1.z, 0.f);
        o[7] = fmaxf(acc0[7] * di + b1.w, 0.f);
        if (res) {
            uint4 rv = *(const uint4*)&res[(size_t)n * 128 + 8 * c];
            o[0] += lo16f(rv.x); o[1] += hi16f(rv.x);
            o[2] += lo16f(rv.y); o[3] += hi16f(rv.y);
            o[4] += lo16f(rv.z); o[5] += hi16f(rv.z);
            o[6] += lo16f(rv.w); o[7] += hi16f(rv.w);
        }
        uint4 ov = make_uint4(pack2(o[0], o[1]), pack2(o[2], o[3]),
                              pack2(o[4], o[5]), pack2(o[6], o[7]));
        *(uint4*)&out[(size_t)n * 128 + 8 * c] = ov;
    }
}

// ============ host-side layer driver ==========================================
template <int H>
static void gat_layer(const u16* X, const u16* lin, const float* as_, const float* ad_,
                      const float* bias, const u16* res, u16* hl, u16* outb,
                      float* a_s, float* a_d, float* ex, float* dinv,
                      const int* rs, const int* cnt, const int* srclist,
                      int N, hipStream_t stream) {
    int gx = (N + 63) / 64;
    gemm_mfma_kernel<128, H><<<gx, 256, 0, stream>>>(
        X, lin, nullptr, nullptr, hl, a_s, a_d, as_, ad_, nullptr, nullptr, nullptr, N, 0);
    att_kernel<H><<<(N * H + 255) / 256, 256, 0, stream>>>(rs, cnt, srclist, a_s, a_d,
                                                           ex, dinv, N);
    gat_agg_kernel<H><<<(N + 3) / 4, 256, 0, stream>>>(rs, cnt, srclist, hl, ex, dinv,
                                                       bias, res, outb, N);
}

extern "C" void kernel_launch(void* const* d_in, const int* in_sizes, int n_in,
                              void* d_out, int out_size, void* d_ws, size_t ws_size,
                              hipStream_t stream) {
    const float* x     = (const float*)d_in[0];
    const int*   types = (const int*)d_in[1];
    const int*   ei    = (const int*)d_in[2];   // int64 in reference -> int32 on device
    const float* ew1 = (const float*)d_in[3];
    const float* eb1 = (const float*)d_in[4];
    const float* ew2 = (const float*)d_in[5];
    const float* eb2 = (const float*)d_in[6];
    const float* cw1 = (const float*)d_in[7];
    const float* cb1 = (const float*)d_in[8];
    const float* cw2 = (const float*)d_in[9];
    const float* cb2 = (const float*)d_in[10];
    const float* lin0 = (const float*)d_in[11];
    const float* as0  = (const float*)d_in[12];
    const float* ad0  = (const float*)d_in[13];
    const float* b0   = (const float*)d_in[14];
    const float* lin1 = (const float*)d_in[15];
    const float* as1  = (const float*)d_in[16];
    const float* ad1  = (const float*)d_in[17];
    const float* b1   = (const float*)d_in[18];
    const float* lin2 = (const float*)d_in[19];
    const float* as2  = (const float*)d_in[20];
    const float* ad2  = (const float*)d_in[21];
    const float* b2   = (const float*)d_in[22];
    const float* dw1 = (const float*)d_in[23];
    const float* db1 = (const float*)d_in[24];
    const float* dw2 = (const float*)d_in[25];
    const float* db2 = (const float*)d_in[26];
    const float* dw3 = (const float*)d_in[27];
    const float* db3 = (const float*)d_in[28];

    int N  = in_sizes[1];
    int E  = in_sizes[2] / 2;
    int E2 = E + N;

    size_t NF = (size_t)N * HIDDEN;
    u16* bufA = (u16*)d_ws;          // bf16 feature buffers
    u16* bufB = bufA + NF;
    u16* bufC = bufB + NF;
    float* fbase = (float*)(bufC + NF);
    float* a_s  = fbase;
    float* a_d  = a_s + (size_t)N * 4;
    float* dinv = a_d + (size_t)N * 4;
    float* ex   = dinv + (size_t)N * 4;             // E2*4 floats
    int* rs      = (int*)(ex + (size_t)E2 * 4);
    int* cnt     = rs + N;
    int* pos     = cnt + N;             // E2 entries
    int* bsum    = pos + E2;            // up to 1024 entries
    int* srclist = bsum + 1024;         // E2 entries
    u16* wb      = (u16*)(srclist + E2);  // 106496 bf16 pre-converted weights
    u16* wb_ew2  = wb;
    u16* wb_cw2  = wb + 16384;
    u16* wb_lin0 = wb + 32768;
    u16* wb_lin1 = wb + 49152;
    u16* wb_lin2 = wb + 65536;
    u16* wb_dw1  = wb + 81920;
    u16* wb_dw2  = wb + 98304;

    int nb = (N + 255) / 256;

    // ---- weight pre-convert + cnt zero (one dispatch)
    WPtrs wp;
    wp.p[0] = ew2; wp.p[1] = cw2; wp.p[2] = lin0; wp.p[3] = lin1;
    wp.p[4] = lin2; wp.p[5] = dw1; wp.p[6] = dw2;
    int cz = max(N, 53248);
    convw_zero_kernel<<<(cz + 255) / 256, 256, 0, stream>>>(wp, (unsigned*)wb, 53248,
                                                            cnt, N);

    // ---- CSR build
    hist_kernel<<<(E2 + 255) / 256, 256, 0, stream>>>(ei, E, E2, cnt, pos);
    scan1_kernel<<<nb, 256, 0, stream>>>(cnt, rs, bsum, N);
    scan23_kernel<<<nb, 256, 0, stream>>>(rs, cnt, bsum, N);
    scatter_kernel<<<(E2 + 255) / 256, 256, 0, stream>>>(ei, E, E2, rs, pos, srclist);

    int gx = (N + 63) / 64;

    // ---- fused encoder -> bufA
    encoder_kernel<<<gx, 256, 0, stream>>>(x, types, ew1, eb1, cw1, cb1,
                                           wb_ew2, wb_cw2, eb2, cb2, bufA, N);

    // ---- GAT layers (out never aliases hl=bufB)
    // layer 0: h0 = relu(gat(h))            bufA -> bufA
    gat_layer<4>(bufA, wb_lin0, as0, ad0, b0, nullptr, bufB, bufA,
                 a_s, a_d, ex, dinv, rs, cnt, srclist, N, stream);
    // layer 1: h1 = h0 + relu(gat(h0))      bufA -> bufC
    gat_layer<4>(bufA, wb_lin1, as1, ad1, b1, bufA, bufB, bufC,
                 a_s, a_d, ex, dinv, rs, cnt, srclist, N, stream);
    // layer 2: h2 = h1 + relu(gat(h1))      bufC -> bufA  (1 head, mean=identity)
    gat_layer<1>(bufC, wb_lin2, as2, ad2, b2, bufC, bufB, bufA,
                 a_s, a_d, ex, dinv, rs, cnt, srclist, N, stream);

    // ---- decoder: d1 -> bufC ; d2 GEMM fused with final dot/sigmoid/mask
    gemm_mfma_kernel<128, 0><<<gx, 256, 0, stream>>>(
        bufA, wb_dw1, db1, nullptr, bufC, nullptr, nullptr, nullptr, nullptr,
        nullptr, nullptr, nullptr, N, 1);
    gemm_mfma_kernel<64, 0><<<gx, 256, 0, stream>>>(
        bufC, wb_dw2, db2, types, nullptr, nullptr, nullptr, nullptr, nullptr,
        dw3, db3, (float*)d_out, N, 3);
}

// Round 14
// 509.978 us; speedup vs baseline: 10.7539x; 1.0049x over previous
//
#include <hip/hip_runtime.h>
#include <math.h>

#define HIDDEN 128
#define NEG_SLOPE 0.2f

typedef unsigned short u16;
typedef __attribute__((ext_vector_type(8))) short bf16x8;
typedef __attribute__((ext_vector_type(4))) float f32x4;

__device__ __forceinline__ u16 f2bf(float f) {
    unsigned u = __float_as_uint(f);
    unsigned r = (u + 0x7FFFu + ((u >> 16) & 1u)) >> 16;   // round-nearest-even
    return (u16)r;
}
__device__ __forceinline__ float bf2f(u16 u) {
    return __uint_as_float((unsigned)u << 16);
}
__device__ __forceinline__ unsigned pack2(float a, float b) {
    return (unsigned)f2bf(a) | ((unsigned)f2bf(b) << 16);
}
__device__ __forceinline__ float lo16f(unsigned v) { return bf2f((u16)v); }
__device__ __forceinline__ float hi16f(unsigned v) { return bf2f((u16)(v >> 16)); }

// ============ fp32->bf16 weight conversion + cnt zeroing (one dispatch) =======
struct WPtrs { const float* p[7]; };
__global__ void convw_zero_kernel(WPtrs wp, unsigned* __restrict__ wb, int totalPairs,
                                  int* __restrict__ cnt, int N) {
    int i = blockIdx.x * blockDim.x + threadIdx.x;
    if (i < N) cnt[i] = 0;
    if (i < totalPairs) {
        int e = i * 2;
        int seg, off;
        if (e < 98304) { seg = e >> 14; off = e & 16383; }
        else           { seg = 6;       off = e - 98304; }
        const float* s = wp.p[seg];
        wb[i] = pack2(s[off], s[off + 1]);
    }
}

// ============ fused encoder: A-frags computed in registers (no Xs LDS) ========
// One block = 64 nodes. h1 values are closed-form per element, so each MFMA
// lane computes its own A-fragment: t = kstep*32 + qd*8 + j, row = w*16 + lr.
// w1sh reads are 16-lane broadcasts (free). Two passes (item/con) share Ws LDS.
__global__ __launch_bounds__(256) void encoder_kernel(
        const float* __restrict__ x, const int* __restrict__ types,
        const float* __restrict__ ew1, const float* __restrict__ eb1,
        const float* __restrict__ cw1, const float* __restrict__ cb1,
        const u16* __restrict__ wb_ew2, const u16* __restrict__ wb_cw2,
        const float* __restrict__ eb2, const float* __restrict__ cb2,
        u16* __restrict__ out, int N) {
    __shared__ u16 Ws[128 * 136];
    __shared__ float xsh[128];
    __shared__ float w1sh[640];   // ew1(256) eb1(128) cw1(128) cb1(128)
    const int tid = threadIdx.x;
    const int n0 = blockIdx.x * 64;

    if (tid < 128) {
        int n = n0 + (tid >> 1);
        xsh[tid] = (n < N) ? x[2 * n + (tid & 1)] : 0.f;
    }
    if (tid < 256) w1sh[tid] = ew1[tid];
    if (tid < 128) { w1sh[256 + tid] = eb1[tid]; w1sh[384 + tid] = cw1[tid];
                     w1sh[512 + tid] = cb1[tid]; }
    // stage Ws = ew2 (pass 1)
#pragma unroll
    for (int r = 0; r < 8; r++) {
        int j = r * 256 + tid;
        int row = j >> 4, c8 = (j & 15) << 3;
        *(uint4*)&Ws[row * 136 + c8] = *(const uint4*)&wb_ew2[(size_t)row * 128 + c8];
    }
    __syncthreads();

    const int w = tid >> 6, lane = tid & 63;
    const int qd = lane >> 4, lr = lane & 15;
    const int row = w * 16 + lr;
    const float x0 = xsh[2 * row], x1 = xsh[2 * row + 1];

    f32x4 acc_i[8], acc_c[8];
#pragma unroll
    for (int j = 0; j < 8; j++) acc_i[j] = (f32x4){0.f, 0.f, 0.f, 0.f};

    // ---- pass 1: item path (A in registers)
#pragma unroll
    for (int k = 0; k < 4; k++) {
        bf16x8 a;
#pragma unroll
        for (int j = 0; j < 8; j++) {
            int t = k * 32 + qd * 8 + j;
            float v = fmaxf(w1sh[2 * t] * x0 + w1sh[2 * t + 1] * x1 + w1sh[256 + t], 0.f);
            a[j] = (short)f2bf(v);
        }
#pragma unroll
        for (int j = 0; j < 8; j++) {
            bf16x8 b = *(const bf16x8*)&Ws[(j * 16 + lr) * 136 + k * 32 + qd * 8];
            acc_i[j] = __builtin_amdgcn_mfma_f32_16x16x32_bf16(a, b, acc_i[j], 0, 0, 0);
        }
    }
    __syncthreads();   // pass-1 Ws reads complete before restage

    // stage Ws = cw2 (pass 2)
#pragma unroll
    for (int r = 0; r < 8; r++) {
        int j = r * 256 + tid;
        int rw = j >> 4, c8 = (j & 15) << 3;
        *(uint4*)&Ws[rw * 136 + c8] = *(const uint4*)&wb_cw2[(size_t)rw * 128 + c8];
    }
    __syncthreads();

#pragma unroll
    for (int j = 0; j < 8; j++) acc_c[j] = (f32x4){0.f, 0.f, 0.f, 0.f};
#pragma unroll
    for (int k = 0; k < 4; k++) {
        bf16x8 a;
#pragma unroll
        for (int j = 0; j < 8; j++) {
            int t = k * 32 + qd * 8 + j;
            float v = fmaxf(w1sh[384 + t] * x0 + w1sh[512 + t], 0.f);
            a[j] = (short)f2bf(v);
        }
#pragma unroll
        for (int j = 0; j < 8; j++) {
            bf16x8 b = *(const bf16x8*)&Ws[(j * 16 + lr) * 136 + k * 32 + qd * 8];
            acc_c[j] = __builtin_amdgcn_mfma_f32_16x16x32_bf16(a, b, acc_c[j], 0, 0, 0);
        }
    }

    // ---- epilogue: per-row type select  (D: col=j*16+lr, row=n0+w*16+qd*4+r)
#pragma unroll
    for (int r = 0; r < 4; r++) {
        int orow = n0 + w * 16 + qd * 4 + r;
        if (orow >= N) continue;
        int ty = types[orow];
#pragma unroll
        for (int j = 0; j < 8; j++) {
            int col = j * 16 + lr;
            float v;
            if (ty == 0)      v = fmaxf(acc_i[j][r] + eb2[col], 0.f);
            else if (ty == 1) v = fmaxf(acc_c[j][r] + cb2[col], 0.f);
            else              v = 0.f;
            out[(size_t)orow * HIDDEN + col] = f2bf(v);
        }
    }
}

// ============ MFMA bf16 GEMM + fused epilogues ================================
// mode 0: raw store  mode 1: relu(acc+bias)
// mode 3 (OUT=64): relu(acc+bias) -> dot dw3 -> sigmoid -> mask -> fout[N]
// DH > 0: also compute a_s/a_d attention dots (DH heads) from acc.
template <int OUT, int DH>
__global__ __launch_bounds__(256) void gemm_mfma_kernel(
        const u16* __restrict__ X, const u16* __restrict__ Wb,
        const float* __restrict__ bias, const int* __restrict__ types,
        u16* __restrict__ out, float* __restrict__ a_s, float* __restrict__ a_d,
        const float* __restrict__ att_s, const float* __restrict__ att_d,
        const float* __restrict__ dw3, const float* __restrict__ db3,
        float* __restrict__ fout, int N, int mode) {
    constexpr int NT = OUT / 16;
    __shared__ u16 Xs[64 * 136];
    __shared__ u16 Ws[OUT * 136];
    const int tid = threadIdx.x;
    const int n0 = blockIdx.x * 64;

#pragma unroll
    for (int r = 0; r < 4; r++) {
        int j = r * 256 + tid;
        int row = j >> 4, c8 = (j & 15) << 3;
        int n = n0 + row;
        uint4 v = make_uint4(0u, 0u, 0u, 0u);
        if (n < N) v = *(const uint4*)&X[(size_t)n * 128 + c8];
        *(uint4*)&Xs[row * 136 + c8] = v;
    }
#pragma unroll
    for (int r = 0; r < NT; r++) {
        int j = r * 256 + tid;
        int row = j >> 4, c8 = (j & 15) << 3;
        *(uint4*)&Ws[row * 136 + c8] = *(const uint4*)&Wb[(size_t)row * 128 + c8];
    }
    __syncthreads();

    const int w = tid >> 6, lane = tid & 63;
    const int qd = lane >> 4, lr = lane & 15;

    f32x4 acc[NT];
#pragma unroll
    for (int j = 0; j < NT; j++) acc[j] = (f32x4){0.f, 0.f, 0.f, 0.f};

#pragma unroll
    for (int k = 0; k < 4; k++) {
        bf16x8 a = *(const bf16x8*)&Xs[(w * 16 + lr) * 136 + k * 32 + qd * 8];
#pragma unroll
        for (int j = 0; j < NT; j++) {
            bf16x8 b = *(const bf16x8*)&Ws[(j * 16 + lr) * 136 + k * 32 + qd * 8];
            acc[j] = __builtin_amdgcn_mfma_f32_16x16x32_bf16(a, b, acc[j], 0, 0, 0);
        }
    }

    // D mapping: col = j*16 + lr, row = n0 + w*16 + qd*4 + r
    if (mode == 3) {
        float pr[4] = {0.f, 0.f, 0.f, 0.f};
#pragma unroll
        for (int j = 0; j < NT; j++) {
            int col = j * 16 + lr;
            float b = bias[col], wv = dw3[col];
#pragma unroll
            for (int r = 0; r < 4; r++) pr[r] += fmaxf(acc[j][r] + b, 0.f) * wv;
        }
#pragma unroll
        for (int m = 1; m < 16; m <<= 1)
#pragma unroll
            for (int r = 0; r < 4; r++) pr[r] += __shfl_xor(pr[r], m, 64);
        if (lr == 0) {
            float b3 = db3[0];
#pragma unroll
            for (int r = 0; r < 4; r++) {
                int row = n0 + w * 16 + qd * 4 + r;
                if (row < N) {
                    float prob = 1.f / (1.f + expf(-(pr[r] + b3)));
                    fout[row] = (types[row] == 0) ? prob : 0.f;
                }
            }
        }
        return;
    }

    if (DH > 0) {
        constexpr int NH = (DH == 4) ? 4 : 1;
        float sp[NH][4], dp[NH][4];
#pragma unroll
        for (int h = 0; h < NH; h++)
#pragma unroll
            for (int r = 0; r < 4; r++) { sp[h][r] = 0.f; dp[h][r] = 0.f; }
#pragma unroll
        for (int j = 0; j < NT; j++) {
            int col = j * 16 + lr;
            float as_ = att_s[col], ad_ = att_d[col];
            int h = (DH == 4) ? (j >> 1) : 0;
#pragma unroll
            for (int r = 0; r < 4; r++) {
                sp[h][r] += acc[j][r] * as_;
                dp[h][r] += acc[j][r] * ad_;
            }
        }
#pragma unroll
        for (int m = 1; m < 16; m <<= 1)
#pragma unroll
            for (int h = 0; h < NH; h++)
#pragma unroll
                for (int r = 0; r < 4; r++) {
                    sp[h][r] += __shfl_xor(sp[h][r], m, 64);
                    dp[h][r] += __shfl_xor(dp[h][r], m, 64);
                }
        if (lr == 0) {
#pragma unroll
            for (int r = 0; r < 4; r++) {
                int row = n0 + w * 16 + qd * 4 + r;
                if (row < N) {
#pragma unroll
                    for (int h = 0; h < NH; h++) {
                        a_s[row * DH + h] = sp[h][r];
                        a_d[row * DH + h] = dp[h][r];
                    }
                }
            }
        }
    }

#pragma unroll
    for (int r = 0; r < 4; r++) {
        int row = n0 + w * 16 + qd * 4 + r;
        if (row >= N) continue;
#pragma unroll
        for (int j = 0; j < NT; j++) {
            int col = j * 16 + lr;
            float v = acc[j][r];
            if (mode >= 1) v = fmaxf(v + bias[col], 0.f);
            out[(size_t)row * OUT + col] = f2bf(v);
        }
    }
}

// ============ CSR build ========================================================
__global__ void hist_kernel(const int* __restrict__ ei, int E, int E2,
                            int* __restrict__ cnt, int* __restrict__ pos) {
    int e = blockIdx.x * blockDim.x + threadIdx.x;
    if (e >= E2) return;
    int d = (e < E) ? ei[E + e] : e - E;
    pos[e] = atomicAdd(&cnt[d], 1);
}

__global__ void scan1_kernel(const int* __restrict__ cnt, int* __restrict__ rs,
                             int* __restrict__ bsum, int N) {
    __shared__ int s[256];
    int i = blockIdx.x * 256 + threadIdx.x;
    int v = (i < N) ? cnt[i] : 0;
    s[threadIdx.x] = v;
    __syncthreads();
    for (int off = 1; off < 256; off <<= 1) {
        int t = (threadIdx.x >= off) ? s[threadIdx.x - off] : 0;
        __syncthreads();
        s[threadIdx.x] += t;
        __syncthreads();
    }
    if (i < N) rs[i] = s[threadIdx.x];
    if (threadIdx.x == 255) bsum[blockIdx.x] = s[255];
}

// block b: prefix = sum(bsum[0..b-1]); rs[i] = rs_incl[i] - cnt[i] + prefix
__global__ void scan23_kernel(int* __restrict__ rs, const int* __restrict__ cnt,
                              const int* __restrict__ bsum, int N) {
    __shared__ int sdata[256];
    int b = blockIdx.x;
    int partial = 0;
    for (int i = threadIdx.x; i < b; i += 256) partial += bsum[i];
    sdata[threadIdx.x] = partial;
    __syncthreads();
    for (int off = 128; off; off >>= 1) {
        if (threadIdx.x < off) sdata[threadIdx.x] += sdata[threadIdx.x + off];
        __syncthreads();
    }
    int pre = sdata[0];
    int i = b * 256 + threadIdx.x;
    if (i < N) rs[i] = rs[i] - cnt[i] + pre;
}

__global__ void scatter_kernel(const int* __restrict__ ei, int E, int E2,
                               const int* __restrict__ rs, const int* __restrict__ pos,
                               int* __restrict__ srclist) {
    int e = blockIdx.x * blockDim.x + threadIdx.x;
    if (e >= E2) return;
    int s, d;
    if (e < E) { s = ei[e]; d = ei[E + e]; }
    else       { s = d = e - E; }
    srclist[rs[d] + pos[e]] = s;
}

// ============ attention coefficients: single-pass softmax =====================
template <int H>
__global__ void att_kernel(const int* __restrict__ rs, const int* __restrict__ cnt,
                           const int* __restrict__ srclist,
                           const float* __restrict__ a_s, const float* __restrict__ a_d,
                           float* __restrict__ ex, float* __restrict__ dinv, int N) {
    int i = blockIdx.x * blockDim.x + threadIdx.x;
    if (i >= N * H) return;
    int n = (H == 1) ? i : (i >> 2);
    int h = (H == 1) ? 0 : (i & 3);
    int beg = rs[n], deg = cnt[n];
    float ad = a_d[i];
    float l = 0.f;
    for (int k = 0; k < deg; k++) {
        float al = a_s[srclist[beg + k] * H + h] + ad;
        al = (al > 0.f) ? al : NEG_SLOPE * al;
        float p = expf(fminf(al, 80.f));
        ex[(beg + k) * H + h] = p;
        l += p;
    }
    dinv[i] = 1.f / l;   // deg >= 1 (self-loop)
}

// ============ GAT aggregation: 16B/lane gather, 12 edges per wave-step ========
// wave = node. lane l: edge-group g=l>>4, feature-chunk c=l&15 (8 bf16 = 16B).
// NOTE: `out` must NEVER alias `hl`.
template <int H>
__global__ __launch_bounds__(256) void gat_agg_kernel(
        const int* __restrict__ rs, const int* __restrict__ cnt,
        const int* __restrict__ srclist, const u16* __restrict__ hl,
        const float* __restrict__ ex, const float* __restrict__ dinv,
        const float* __restrict__ bias, const u16* __restrict__ res,
        u16* __restrict__ out, int N) {
    int n = blockIdx.x * 4 + (threadIdx.x >> 6);
    int l = threadIdx.x & 63;
    if (n >= N) return;
    const int g = l >> 4;          // edge group 0..3
    const int c = l & 15;          // feature chunk (features 8c..8c+7)
    const int head = (H == 1) ? 0 : (c >> 2);
    const int beg = rs[n];
    const int deg = cnt[n];
    float acc0[8], acc1[8], acc2[8];
#pragma unroll
    for (int j = 0; j < 8; j++) { acc0[j] = 0.f; acc1[j] = 0.f; acc2[j] = 0.f; }

    for (int k = 0; k < deg; k += 12) {
        int i0 = k + g, i1 = k + 4 + g, i2 = k + 8 + g;
        int e0 = beg + min(i0, deg - 1);
        int e1 = beg + min(i1, deg - 1);
        int e2 = beg + min(i2, deg - 1);
        int s0 = srclist[e0], s1 = srclist[e1], s2 = srclist[e2];
        float p0 = ex[e0 * H + head];
        float p1 = ex[e1 * H + head];
        float p2 = ex[e2 * H + head];
        if (i0 >= deg) p0 = 0.f;
        if (i1 >= deg) p1 = 0.f;
        if (i2 >= deg) p2 = 0.f;
        uint4 v0 = *(const uint4*)&hl[(size_t)s0 * 128 + 8 * c];
        uint4 v1 = *(const uint4*)&hl[(size_t)s1 * 128 + 8 * c];
        uint4 v2 = *(const uint4*)&hl[(size_t)s2 * 128 + 8 * c];
        acc0[0] += p0 * lo16f(v0.x); acc0[1] += p0 * hi16f(v0.x);
        acc0[2] += p0 * lo16f(v0.y); acc0[3] += p0 * hi16f(v0.y);
        acc0[4] += p0 * lo16f(v0.z); acc0[5] += p0 * hi16f(v0.z);
        acc0[6] += p0 * lo16f(v0.w); acc0[7] += p0 * hi16f(v0.w);
        acc1[0] += p1 * lo16f(v1.x); acc1[1] += p1 * hi16f(v1.x);
        acc1[2] += p1 * lo16f(v1.y); acc1[3] += p1 * hi16f(v1.y);
        acc1[4] += p1 * lo16f(v1.z); acc1[5] += p1 * hi16f(v1.z);
        acc1[6] += p1 * lo16f(v1.w); acc1[7] += p1 * hi16f(v1.w);
        acc2[0] += p2 * lo16f(v2.x); acc2[1] += p2 * hi16f(v2.x);
        acc2[2] += p2 * lo16f(v2.y); acc2[3] += p2 * hi16f(v2.y);
        acc2[4] += p2 * lo16f(v2.z); acc2[5] += p2 * hi16f(v2.z);
        acc2[6] += p2 * lo16f(v2.w); acc2[7] += p2 * hi16f(v2.w);
    }
#pragma unroll
    for (int j = 0; j < 8; j++) {
        float a = acc0[j] + acc1[j] + acc2[j];
        a += __shfl_xor(a, 16, 64);
        a += __shfl_xor(a, 32, 64);
        acc0[j] = a;
    }
    if (g == 0) {   // lanes 0..15 hold the full sums for their 8 features
        float di = dinv[n * H + head];
        float4 b0 = *(const float4*)&bias[8 * c];
        float4 b1 = *(const float4*)&bias[8 * c + 4];
        float o[8];
        o[0] = fmaxf(acc0[0] * di + b0.x, 0.f);
        o[1] = fmaxf(acc0[1] * di + b0.y, 0.f);
        o[2] = fmaxf(acc0[2] * di + b0.z, 0.f);
        o[3] = fmaxf(acc0[3] * di + b0.w, 0.f);
        o[4] = fmaxf(acc0[4] * di + b1.x, 0.f);
        o[5] = fmaxf(acc0[5] * di + b1.y, 0.f);
        o[6] = fmaxf(acc0[6] * di + b1.z, 0.f);
        o[7] = fmaxf(acc0[7] * di + b1.w, 0.f);
        if (res) {
            uint4 rv = *(const uint4*)&res[(size_t)n * 128 + 8 * c];
            o[0] += lo16f(rv.x); o[1] += hi16f(rv.x);
            o[2] += lo16f(rv.y); o[3] += hi16f(rv.y);
            o[4] += lo16f(rv.z); o[5] += hi16f(rv.z);
            o[6] += lo16f(rv.w); o[7] += hi16f(rv.w);
        }
        uint4 ov = make_uint4(pack2(o[0], o[1]), pack2(o[2], o[3]),
                              pack2(o[4], o[5]), pack2(o[6], o[7]));
        *(uint4*)&out[(size_t)n * 128 + 8 * c] = ov;
    }
}

// ============ host-side layer driver ==========================================
template <int H>
static void gat_layer(const u16* X, const u16* lin, const float* as_, const float* ad_,
                      const float* bias, const u16* res, u16* hl, u16* outb,
                      float* a_s, float* a_d, float* ex, float* dinv,
                      const int* rs, const int* cnt, const int* srclist,
                      int N, hipStream_t stream) {
    int gx = (N + 63) / 64;
    gemm_mfma_kernel<128, H><<<gx, 256, 0, stream>>>(
        X, lin, nullptr, nullptr, hl, a_s, a_d, as_, ad_, nullptr, nullptr, nullptr, N, 0);
    att_kernel<H><<<(N * H + 255) / 256, 256, 0, stream>>>(rs, cnt, srclist, a_s, a_d,
                                                           ex, dinv, N);
    gat_agg_kernel<H><<<(N + 3) / 4, 256, 0, stream>>>(rs, cnt, srclist, hl, ex, dinv,
                                                       bias, res, outb, N);
}

extern "C" void kernel_launch(void* const* d_in, const int* in_sizes, int n_in,
                              void* d_out, int out_size, void* d_ws, size_t ws_size,
                              hipStream_t stream) {
    const float* x     = (const float*)d_in[0];
    const int*   types = (const int*)d_in[1];
    const int*   ei    = (const int*)d_in[2];   // int64 in reference -> int32 on device
    const float* ew1 = (const float*)d_in[3];
    const float* eb1 = (const float*)d_in[4];
    const float* ew2 = (const float*)d_in[5];
    const float* eb2 = (const float*)d_in[6];
    const float* cw1 = (const float*)d_in[7];
    const float* cb1 = (const float*)d_in[8];
    const float* cw2 = (const float*)d_in[9];
    const float* cb2 = (const float*)d_in[10];
    const float* lin0 = (const float*)d_in[11];
    const float* as0  = (const float*)d_in[12];
    const float* ad0  = (const float*)d_in[13];
    const float* b0   = (const float*)d_in[14];
    const float* lin1 = (const float*)d_in[15];
    const float* as1  = (const float*)d_in[16];
    const float* ad1  = (const float*)d_in[17];
    const float* b1   = (const float*)d_in[18];
    const float* lin2 = (const float*)d_in[19];
    const float* as2  = (const float*)d_in[20];
    const float* ad2  = (const float*)d_in[21];
    const float* b2   = (const float*)d_in[22];
    const float* dw1 = (const float*)d_in[23];
    const float* db1 = (const float*)d_in[24];
    const float* dw2 = (const float*)d_in[25];
    const float* db2 = (const float*)d_in[26];
    const float* dw3 = (const float*)d_in[27];
    const float* db3 = (const float*)d_in[28];

    int N  = in_sizes[1];
    int E  = in_sizes[2] / 2;
    int E2 = E + N;

    size_t NF = (size_t)N * HIDDEN;
    u16* bufA = (u16*)d_ws;          // bf16 feature buffers
    u16* bufB = bufA + NF;
    u16* bufC = bufB + NF;
    float* fbase = (float*)(bufC + NF);
    float* a_s  = fbase;
    float* a_d  = a_s + (size_t)N * 4;
    float* dinv = a_d + (size_t)N * 4;
    float* ex   = dinv + (size_t)N * 4;             // E2*4 floats
    int* rs      = (int*)(ex + (size_t)E2 * 4);
    int* cnt     = rs + N;
    int* pos     = cnt + N;             // E2 entries
    int* bsum    = pos + E2;            // up to 1024 entries
    int* srclist = bsum + 1024;         // E2 entries
    u16* wb      = (u16*)(srclist + E2);  // 106496 bf16 pre-converted weights
    u16* wb_ew2  = wb;
    u16* wb_cw2  = wb + 16384;
    u16* wb_lin0 = wb + 32768;
    u16* wb_lin1 = wb + 49152;
    u16* wb_lin2 = wb + 65536;
    u16* wb_dw1  = wb + 81920;
    u16* wb_dw2  = wb + 98304;

    int nb = (N + 255) / 256;

    // ---- weight pre-convert + cnt zero (one dispatch)
    WPtrs wp;
    wp.p[0] = ew2; wp.p[1] = cw2; wp.p[2] = lin0; wp.p[3] = lin1;
    wp.p[4] = lin2; wp.p[5] = dw1; wp.p[6] = dw2;
    int cz = max(N, 53248);
    convw_zero_kernel<<<(cz + 255) / 256, 256, 0, stream>>>(wp, (unsigned*)wb, 53248,
                                                            cnt, N);

    // ---- CSR build
    hist_kernel<<<(E2 + 255) / 256, 256, 0, stream>>>(ei, E, E2, cnt, pos);
    scan1_kernel<<<nb, 256, 0, stream>>>(cnt, rs, bsum, N);
    scan23_kernel<<<nb, 256, 0, stream>>>(rs, cnt, bsum, N);
    scatter_kernel<<<(E2 + 255) / 256, 256, 0, stream>>>(ei, E, E2, rs, pos, srclist);

    int gx = (N + 63) / 64;

    // ---- fused encoder -> bufA
    encoder_kernel<<<gx, 256, 0, stream>>>(x, types, ew1, eb1, cw1, cb1,
                                           wb_ew2, wb_cw2, eb2, cb2, bufA, N);

    // ---- GAT layers (out never aliases hl=bufB)
    // layer 0: h0 = relu(gat(h))            bufA -> bufA
    gat_layer<4>(bufA, wb_lin0, as0, ad0, b0, nullptr, bufB, bufA,
                 a_s, a_d, ex, dinv, rs, cnt, srclist, N, stream);
    // layer 1: h1 = h0 + relu(gat(h0))      bufA -> bufC
    gat_layer<4>(bufA, wb_lin1, as1, ad1, b1, bufA, bufB, bufC,
                 a_s, a_d, ex, dinv, rs, cnt, srclist, N, stream);
    // layer 2: h2 = h1 + relu(gat(h1))      bufC -> bufA  (1 head, mean=identity)
    gat_layer<1>(bufC, wb_lin2, as2, ad2, b2, bufC, bufB, bufA,
                 a_s, a_d, ex, dinv, rs, cnt, srclist, N, stream);

    // ---- decoder: d1 -> bufC ; d2 GEMM fused with final dot/sigmoid/mask
    gemm_mfma_kernel<128, 0><<<gx, 256, 0, stream>>>(
        bufA, wb_dw1, db1, nullptr, bufC, nullptr, nullptr, nullptr, nullptr,
        nullptr, nullptr, nullptr, N, 1);
    gemm_mfma_kernel<64, 0><<<gx, 256, 0, stream>>>(
        bufC, wb_dw2, db2, types, nullptr, nullptr, nullptr, nullptr, nullptr,
        dw3, db3, (float*)d_out, N, 3);
}

// Round 15
// 483.599 us; speedup vs baseline: 11.3405x; 1.0545x over previous
//
#include <hip/hip_runtime.h>
#include <math.h>

#define HIDDEN 128
#define NEG_SLOPE 0.2f

typedef unsigned short u16;
typedef __attribute__((ext_vector_type(8))) short bf16x8;
typedef __attribute__((ext_vector_type(4))) float f32x4;

__device__ __forceinline__ u16 f2bf(float f) {
    unsigned u = __float_as_uint(f);
    unsigned r = (u + 0x7FFFu + ((u >> 16) & 1u)) >> 16;   // round-nearest-even
    return (u16)r;
}
__device__ __forceinline__ float bf2f(u16 u) {
    return __uint_as_float((unsigned)u << 16);
}
__device__ __forceinline__ unsigned pack2(float a, float b) {
    return (unsigned)f2bf(a) | ((unsigned)f2bf(b) << 16);
}
__device__ __forceinline__ float lo16f(unsigned v) { return bf2f((u16)v); }
__device__ __forceinline__ float hi16f(unsigned v) { return bf2f((u16)(v >> 16)); }

// ============ fp32->bf16 weight conversion + cnt zeroing (one dispatch) =======
struct WPtrs { const float* p[7]; };
__global__ void convw_zero_kernel(WPtrs wp, unsigned* __restrict__ wb, int totalPairs,
                                  int* __restrict__ cnt, int N) {
    int i = blockIdx.x * blockDim.x + threadIdx.x;
    if (i < N) cnt[i] = 0;
    if (i < totalPairs) {
        int e = i * 2;
        int seg, off;
        if (e < 98304) { seg = e >> 14; off = e & 16383; }
        else           { seg = 6;       off = e - 98304; }
        const float* s = wp.p[seg];
        wb[i] = pack2(s[off], s[off + 1]);
    }
}

// ============ fused encoder: A-frags computed in registers (no Xs LDS) ========
__global__ __launch_bounds__(256) void encoder_kernel(
        const float* __restrict__ x, const int* __restrict__ types,
        const float* __restrict__ ew1, const float* __restrict__ eb1,
        const float* __restrict__ cw1, const float* __restrict__ cb1,
        const u16* __restrict__ wb_ew2, const u16* __restrict__ wb_cw2,
        const float* __restrict__ eb2, const float* __restrict__ cb2,
        u16* __restrict__ out, int N) {
    __shared__ u16 Ws[128 * 136];
    __shared__ float xsh[128];
    __shared__ float w1sh[640];   // ew1(256) eb1(128) cw1(128) cb1(128)
    const int tid = threadIdx.x;
    const int n0 = blockIdx.x * 64;

    if (tid < 128) {
        int n = n0 + (tid >> 1);
        xsh[tid] = (n < N) ? x[2 * n + (tid & 1)] : 0.f;
    }
    if (tid < 256) w1sh[tid] = ew1[tid];
    if (tid < 128) { w1sh[256 + tid] = eb1[tid]; w1sh[384 + tid] = cw1[tid];
                     w1sh[512 + tid] = cb1[tid]; }
#pragma unroll
    for (int r = 0; r < 8; r++) {
        int j = r * 256 + tid;
        int row = j >> 4, c8 = (j & 15) << 3;
        *(uint4*)&Ws[row * 136 + c8] = *(const uint4*)&wb_ew2[(size_t)row * 128 + c8];
    }
    __syncthreads();

    const int w = tid >> 6, lane = tid & 63;
    const int qd = lane >> 4, lr = lane & 15;
    const int row = w * 16 + lr;
    const float x0 = xsh[2 * row], x1 = xsh[2 * row + 1];

    f32x4 acc_i[8], acc_c[8];
#pragma unroll
    for (int j = 0; j < 8; j++) acc_i[j] = (f32x4){0.f, 0.f, 0.f, 0.f};

#pragma unroll
    for (int k = 0; k < 4; k++) {
        bf16x8 a;
#pragma unroll
        for (int j = 0; j < 8; j++) {
            int t = k * 32 + qd * 8 + j;
            float v = fmaxf(w1sh[2 * t] * x0 + w1sh[2 * t + 1] * x1 + w1sh[256 + t], 0.f);
            a[j] = (short)f2bf(v);
        }
#pragma unroll
        for (int j = 0; j < 8; j++) {
            bf16x8 b = *(const bf16x8*)&Ws[(j * 16 + lr) * 136 + k * 32 + qd * 8];
            acc_i[j] = __builtin_amdgcn_mfma_f32_16x16x32_bf16(a, b, acc_i[j], 0, 0, 0);
        }
    }
    __syncthreads();

#pragma unroll
    for (int r = 0; r < 8; r++) {
        int j = r * 256 + tid;
        int rw = j >> 4, c8 = (j & 15) << 3;
        *(uint4*)&Ws[rw * 136 + c8] = *(const uint4*)&wb_cw2[(size_t)rw * 128 + c8];
    }
    __syncthreads();

#pragma unroll
    for (int j = 0; j < 8; j++) acc_c[j] = (f32x4){0.f, 0.f, 0.f, 0.f};
#pragma unroll
    for (int k = 0; k < 4; k++) {
        bf16x8 a;
#pragma unroll
        for (int j = 0; j < 8; j++) {
            int t = k * 32 + qd * 8 + j;
            float v = fmaxf(w1sh[384 + t] * x0 + w1sh[512 + t], 0.f);
            a[j] = (short)f2bf(v);
        }
#pragma unroll
        for (int j = 0; j < 8; j++) {
            bf16x8 b = *(const bf16x8*)&Ws[(j * 16 + lr) * 136 + k * 32 + qd * 8];
            acc_c[j] = __builtin_amdgcn_mfma_f32_16x16x32_bf16(a, b, acc_c[j], 0, 0, 0);
        }
    }

#pragma unroll
    for (int r = 0; r < 4; r++) {
        int orow = n0 + w * 16 + qd * 4 + r;
        if (orow >= N) continue;
        int ty = types[orow];
#pragma unroll
        for (int j = 0; j < 8; j++) {
            int col = j * 16 + lr;
            float v;
            if (ty == 0)      v = fmaxf(acc_i[j][r] + eb2[col], 0.f);
            else if (ty == 1) v = fmaxf(acc_c[j][r] + cb2[col], 0.f);
            else              v = 0.f;
            out[(size_t)orow * HIDDEN + col] = f2bf(v);
        }
    }
}

// ============ MFMA bf16 GEMM + fused epilogues ================================
// mode 0: raw store  mode 1: relu(acc+bias)
// mode 3 (OUT=64): relu(acc+bias) -> dot dw3 -> sigmoid -> mask -> fout[N]
// DH > 0: also compute a_s/a_d attention dots (DH heads) from acc.
template <int OUT, int DH>
__global__ __launch_bounds__(256) void gemm_mfma_kernel(
        const u16* __restrict__ X, const u16* __restrict__ Wb,
        const float* __restrict__ bias, const int* __restrict__ types,
        u16* __restrict__ out, float* __restrict__ a_s, float* __restrict__ a_d,
        const float* __restrict__ att_s, const float* __restrict__ att_d,
        const float* __restrict__ dw3, const float* __restrict__ db3,
        float* __restrict__ fout, int N, int mode) {
    constexpr int NT = OUT / 16;
    __shared__ u16 Xs[64 * 136];
    __shared__ u16 Ws[OUT * 136];
    const int tid = threadIdx.x;
    const int n0 = blockIdx.x * 64;

#pragma unroll
    for (int r = 0; r < 4; r++) {
        int j = r * 256 + tid;
        int row = j >> 4, c8 = (j & 15) << 3;
        int n = n0 + row;
        uint4 v = make_uint4(0u, 0u, 0u, 0u);
        if (n < N) v = *(const uint4*)&X[(size_t)n * 128 + c8];
        *(uint4*)&Xs[row * 136 + c8] = v;
    }
#pragma unroll
    for (int r = 0; r < NT; r++) {
        int j = r * 256 + tid;
        int row = j >> 4, c8 = (j & 15) << 3;
        *(uint4*)&Ws[row * 136 + c8] = *(const uint4*)&Wb[(size_t)row * 128 + c8];
    }
    __syncthreads();

    const int w = tid >> 6, lane = tid & 63;
    const int qd = lane >> 4, lr = lane & 15;

    f32x4 acc[NT];
#pragma unroll
    for (int j = 0; j < NT; j++) acc[j] = (f32x4){0.f, 0.f, 0.f, 0.f};

#pragma unroll
    for (int k = 0; k < 4; k++) {
        bf16x8 a = *(const bf16x8*)&Xs[(w * 16 + lr) * 136 + k * 32 + qd * 8];
#pragma unroll
        for (int j = 0; j < NT; j++) {
            bf16x8 b = *(const bf16x8*)&Ws[(j * 16 + lr) * 136 + k * 32 + qd * 8];
            acc[j] = __builtin_amdgcn_mfma_f32_16x16x32_bf16(a, b, acc[j], 0, 0, 0);
        }
    }

    // D mapping: col = j*16 + lr, row = n0 + w*16 + qd*4 + r
    if (mode == 3) {
        float pr[4] = {0.f, 0.f, 0.f, 0.f};
#pragma unroll
        for (int j = 0; j < NT; j++) {
            int col = j * 16 + lr;
            float b = bias[col], wv = dw3[col];
#pragma unroll
            for (int r = 0; r < 4; r++) pr[r] += fmaxf(acc[j][r] + b, 0.f) * wv;
        }
#pragma unroll
        for (int m = 1; m < 16; m <<= 1)
#pragma unroll
            for (int r = 0; r < 4; r++) pr[r] += __shfl_xor(pr[r], m, 64);
        if (lr == 0) {
            float b3 = db3[0];
#pragma unroll
            for (int r = 0; r < 4; r++) {
                int row = n0 + w * 16 + qd * 4 + r;
                if (row < N) {
                    float prob = 1.f / (1.f + expf(-(pr[r] + b3)));
                    fout[row] = (types[row] == 0) ? prob : 0.f;
                }
            }
        }
        return;
    }

    if (DH > 0) {
        constexpr int NH = (DH == 4) ? 4 : 1;
        float sp[NH][4], dp[NH][4];
#pragma unroll
        for (int h = 0; h < NH; h++)
#pragma unroll
            for (int r = 0; r < 4; r++) { sp[h][r] = 0.f; dp[h][r] = 0.f; }
#pragma unroll
        for (int j = 0; j < NT; j++) {
            int col = j * 16 + lr;
            float as_ = att_s[col], ad_ = att_d[col];
            int h = (DH == 4) ? (j >> 1) : 0;
#pragma unroll
            for (int r = 0; r < 4; r++) {
                sp[h][r] += acc[j][r] * as_;
                dp[h][r] += acc[j][r] * ad_;
            }
        }
#pragma unroll
        for (int m = 1; m < 16; m <<= 1)
#pragma unroll
            for (int h = 0; h < NH; h++)
#pragma unroll
                for (int r = 0; r < 4; r++) {
                    sp[h][r] += __shfl_xor(sp[h][r], m, 64);
                    dp[h][r] += __shfl_xor(dp[h][r], m, 64);
                }
        if (lr == 0) {
#pragma unroll
            for (int r = 0; r < 4; r++) {
                int row = n0 + w * 16 + qd * 4 + r;
                if (row < N) {
#pragma unroll
                    for (int h = 0; h < NH; h++) {
                        a_s[row * DH + h] = sp[h][r];
                        a_d[row * DH + h] = dp[h][r];
                    }
                }
            }
        }
    }

#pragma unroll
    for (int r = 0; r < 4; r++) {
        int row = n0 + w * 16 + qd * 4 + r;
        if (row >= N) continue;
#pragma unroll
        for (int j = 0; j < NT; j++) {
            int col = j * 16 + lr;
            float v = acc[j][r];
            if (mode >= 1) v = fmaxf(v + bias[col], 0.f);
            out[(size_t)row * OUT + col] = f2bf(v);
        }
    }
}

// ============ CSR build ========================================================
__global__ void hist_kernel(const int* __restrict__ ei, int E, int E2,
                            int* __restrict__ cnt, int* __restrict__ pos) {
    int e = blockIdx.x * blockDim.x + threadIdx.x;
    if (e >= E2) return;
    int d = (e < E) ? ei[E + e] : e - E;
    pos[e] = atomicAdd(&cnt[d], 1);
}

__global__ void scan1_kernel(const int* __restrict__ cnt, int* __restrict__ rs,
                             int* __restrict__ bsum, int N) {
    __shared__ int s[256];
    int i = blockIdx.x * 256 + threadIdx.x;
    int v = (i < N) ? cnt[i] : 0;
    s[threadIdx.x] = v;
    __syncthreads();
    for (int off = 1; off < 256; off <<= 1) {
        int t = (threadIdx.x >= off) ? s[threadIdx.x - off] : 0;
        __syncthreads();
        s[threadIdx.x] += t;
        __syncthreads();
    }
    if (i < N) rs[i] = s[threadIdx.x];
    if (threadIdx.x == 255) bsum[blockIdx.x] = s[255];
}

__global__ void scan23_kernel(int* __restrict__ rs, const int* __restrict__ cnt,
                              const int* __restrict__ bsum, int N) {
    __shared__ int sdata[256];
    int b = blockIdx.x;
    int partial = 0;
    for (int i = threadIdx.x; i < b; i += 256) partial += bsum[i];
    sdata[threadIdx.x] = partial;
    __syncthreads();
    for (int off = 128; off; off >>= 1) {
        if (threadIdx.x < off) sdata[threadIdx.x] += sdata[threadIdx.x + off];
        __syncthreads();
    }
    int pre = sdata[0];
    int i = b * 256 + threadIdx.x;
    if (i < N) rs[i] = rs[i] - cnt[i] + pre;
}

__global__ void scatter_kernel(const int* __restrict__ ei, int E, int E2,
                               const int* __restrict__ rs, const int* __restrict__ pos,
                               int* __restrict__ srclist) {
    int e = blockIdx.x * blockDim.x + threadIdx.x;
    if (e >= E2) return;
    int s, d;
    if (e < E) { s = ei[e]; d = ei[E + e]; }
    else       { s = d = e - E; }
    srclist[rs[d] + pos[e]] = s;
}

// ============ GAT aggregation with INLINE softmax =============================
// out[n] = (sum_e p_e * hl[src_e]) / (sum_e p_e),  p_e = exp(leaky(a_s+a_d))
// (normalization commutes with the weighted sum, so no separate att pass).
// wave = node. lane l: edge-group g=l>>4, feature-chunk c=l&15 (8 bf16 = 16B),
// head = c>>2 (H=4). 12 edges per wave-step, 3 loads in flight per lane.
// NOTE: `out` must NEVER alias `hl`.
template <int H>
__global__ __launch_bounds__(256) void gat_agg_kernel(
        const int* __restrict__ rs, const int* __restrict__ cnt,
        const int* __restrict__ srclist, const u16* __restrict__ hl,
        const float* __restrict__ a_s, const float* __restrict__ a_d,
        const float* __restrict__ bias, const u16* __restrict__ res,
        u16* __restrict__ out, int N) {
    int n = blockIdx.x * 4 + (threadIdx.x >> 6);
    int l = threadIdx.x & 63;
    if (n >= N) return;
    const int g = l >> 4;          // edge group 0..3
    const int c = l & 15;          // feature chunk (features 8c..8c+7)
    const int head = (H == 1) ? 0 : (c >> 2);
    const int beg = rs[n];
    const int deg = cnt[n];
    const float ad = a_d[n * H + head];
    float acc0[8], acc1[8], acc2[8];
    float den0 = 0.f, den1 = 0.f, den2 = 0.f;
#pragma unroll
    for (int j = 0; j < 8; j++) { acc0[j] = 0.f; acc1[j] = 0.f; acc2[j] = 0.f; }

    for (int k = 0; k < deg; k += 12) {
        int i0 = k + g, i1 = k + 4 + g, i2 = k + 8 + g;
        int e0 = beg + min(i0, deg - 1);
        int e1 = beg + min(i1, deg - 1);
        int e2 = beg + min(i2, deg - 1);
        int s0 = srclist[e0], s1 = srclist[e1], s2 = srclist[e2];
        float al0 = a_s[s0 * H + head] + ad;
        float al1 = a_s[s1 * H + head] + ad;
        float al2 = a_s[s2 * H + head] + ad;
        al0 = (al0 > 0.f) ? al0 : NEG_SLOPE * al0;
        al1 = (al1 > 0.f) ? al1 : NEG_SLOPE * al1;
        al2 = (al2 > 0.f) ? al2 : NEG_SLOPE * al2;
        float p0 = __expf(fminf(al0, 80.f));
        float p1 = __expf(fminf(al1, 80.f));
        float p2 = __expf(fminf(al2, 80.f));
        if (i0 >= deg) p0 = 0.f;
        if (i1 >= deg) p1 = 0.f;
        if (i2 >= deg) p2 = 0.f;
        den0 += p0; den1 += p1; den2 += p2;
        uint4 v0 = *(const uint4*)&hl[(size_t)s0 * 128 + 8 * c];
        uint4 v1 = *(const uint4*)&hl[(size_t)s1 * 128 + 8 * c];
        uint4 v2 = *(const uint4*)&hl[(size_t)s2 * 128 + 8 * c];
        acc0[0] += p0 * lo16f(v0.x); acc0[1] += p0 * hi16f(v0.x);
        acc0[2] += p0 * lo16f(v0.y); acc0[3] += p0 * hi16f(v0.y);
        acc0[4] += p0 * lo16f(v0.z); acc0[5] += p0 * hi16f(v0.z);
        acc0[6] += p0 * lo16f(v0.w); acc0[7] += p0 * hi16f(v0.w);
        acc1[0] += p1 * lo16f(v1.x); acc1[1] += p1 * hi16f(v1.x);
        acc1[2] += p1 * lo16f(v1.y); acc1[3] += p1 * hi16f(v1.y);
        acc1[4] += p1 * lo16f(v1.z); acc1[5] += p1 * hi16f(v1.z);
        acc1[6] += p1 * lo16f(v1.w); acc1[7] += p1 * hi16f(v1.w);
        acc2[0] += p2 * lo16f(v2.x); acc2[1] += p2 * hi16f(v2.x);
        acc2[2] += p2 * lo16f(v2.y); acc2[3] += p2 * hi16f(v2.y);
        acc2[4] += p2 * lo16f(v2.z); acc2[5] += p2 * hi16f(v2.z);
        acc2[6] += p2 * lo16f(v2.w); acc2[7] += p2 * hi16f(v2.w);
    }
#pragma unroll
    for (int j = 0; j < 8; j++) {
        float a = acc0[j] + acc1[j] + acc2[j];
        a += __shfl_xor(a, 16, 64);
        a += __shfl_xor(a, 32, 64);
        acc0[j] = a;
    }
    float den = den0 + den1 + den2;
    den += __shfl_xor(den, 16, 64);
    den += __shfl_xor(den, 32, 64);
    if (g == 0) {   // lanes 0..15 hold the full sums for their 8 features
        float di = 1.f / den;   // deg >= 1 (self-loop)
        float4 b0 = *(const float4*)&bias[8 * c];
        float4 b1 = *(const float4*)&bias[8 * c + 4];
        float o[8];
        o[0] = fmaxf(acc0[0] * di + b0.x, 0.f);
        o[1] = fmaxf(acc0[1] * di + b0.y, 0.f);
        o[2] = fmaxf(acc0[2] * di + b0.z, 0.f);
        o[3] = fmaxf(acc0[3] * di + b0.w, 0.f);
        o[4] = fmaxf(acc0[4] * di + b1.x, 0.f);
        o[5] = fmaxf(acc0[5] * di + b1.y, 0.f);
        o[6] = fmaxf(acc0[6] * di + b1.z, 0.f);
        o[7] = fmaxf(acc0[7] * di + b1.w, 0.f);
        if (res) {
            uint4 rv = *(const uint4*)&res[(size_t)n * 128 + 8 * c];
            o[0] += lo16f(rv.x); o[1] += hi16f(rv.x);
            o[2] += lo16f(rv.y); o[3] += hi16f(rv.y);
            o[4] += lo16f(rv.z); o[5] += hi16f(rv.z);
            o[6] += lo16f(rv.w); o[7] += hi16f(rv.w);
        }
        uint4 ov = make_uint4(pack2(o[0], o[1]), pack2(o[2], o[3]),
                              pack2(o[4], o[5]), pack2(o[6], o[7]));
        *(uint4*)&out[(size_t)n * 128 + 8 * c] = ov;
    }
}

// ============ host-side layer driver ==========================================
template <int H>
static void gat_layer(const u16* X, const u16* lin, const float* as_, const float* ad_,
                      const float* bias, const u16* res, u16* hl, u16* outb,
                      float* a_s, float* a_d,
                      const int* rs, const int* cnt, const int* srclist,
                      int N, hipStream_t stream) {
    int gx = (N + 63) / 64;
    gemm_mfma_kernel<128, H><<<gx, 256, 0, stream>>>(
        X, lin, nullptr, nullptr, hl, a_s, a_d, as_, ad_, nullptr, nullptr, nullptr, N, 0);
    gat_agg_kernel<H><<<(N + 3) / 4, 256, 0, stream>>>(rs, cnt, srclist, hl, a_s, a_d,
                                                       bias, res, outb, N);
}

extern "C" void kernel_launch(void* const* d_in, const int* in_sizes, int n_in,
                              void* d_out, int out_size, void* d_ws, size_t ws_size,
                              hipStream_t stream) {
    const float* x     = (const float*)d_in[0];
    const int*   types = (const int*)d_in[1];
    const int*   ei    = (const int*)d_in[2];   // int64 in reference -> int32 on device
    const float* ew1 = (const float*)d_in[3];
    const float* eb1 = (const float*)d_in[4];
    const float* ew2 = (const float*)d_in[5];
    const float* eb2 = (const float*)d_in[6];
    const float* cw1 = (const float*)d_in[7];
    const float* cb1 = (const float*)d_in[8];
    const float* cw2 = (const float*)d_in[9];
    const float* cb2 = (const float*)d_in[10];
    const float* lin0 = (const float*)d_in[11];
    const float* as0  = (const float*)d_in[12];
    const float* ad0  = (const float*)d_in[13];
    const float* b0   = (const float*)d_in[14];
    const float* lin1 = (const float*)d_in[15];
    const float* as1  = (const float*)d_in[16];
    const float* ad1  = (const float*)d_in[17];
    const float* b1   = (const float*)d_in[18];
    const float* lin2 = (const float*)d_in[19];
    const float* as2  = (const float*)d_in[20];
    const float* ad2  = (const float*)d_in[21];
    const float* b2   = (const float*)d_in[22];
    const float* dw1 = (const float*)d_in[23];
    const float* db1 = (const float*)d_in[24];
    const float* dw2 = (const float*)d_in[25];
    const float* db2 = (const float*)d_in[26];
    const float* dw3 = (const float*)d_in[27];
    const float* db3 = (const float*)d_in[28];

    int N  = in_sizes[1];
    int E  = in_sizes[2] / 2;
    int E2 = E + N;

    size_t NF = (size_t)N * HIDDEN;
    u16* bufA = (u16*)d_ws;          // bf16 feature buffers
    u16* bufB = bufA + NF;
    u16* bufC = bufB + NF;
    float* fbase = (float*)(bufC + NF);
    float* a_s  = fbase;
    float* a_d  = a_s + (size_t)N * 4;
    int* rs      = (int*)(a_d + (size_t)N * 4);
    int* cnt     = rs + N;
    int* pos     = cnt + N;             // E2 entries
    int* bsum    = pos + E2;            // up to 1024 entries
    int* srclist = bsum + 1024;         // E2 entries
    u16* wb      = (u16*)(srclist + E2);  // 106496 bf16 pre-converted weights
    u16* wb_ew2  = wb;
    u16* wb_cw2  = wb + 16384;
    u16* wb_lin0 = wb + 32768;
    u16* wb_lin1 = wb + 49152;
    u16* wb_lin2 = wb + 65536;
    u16* wb_dw1  = wb + 81920;
    u16* wb_dw2  = wb + 98304;

    int nb = (N + 255) / 256;

    // ---- weight pre-convert + cnt zero (one dispatch)
    WPtrs wp;
    wp.p[0] = ew2; wp.p[1] = cw2; wp.p[2] = lin0; wp.p[3] = lin1;
    wp.p[4] = lin2; wp.p[5] = dw1; wp.p[6] = dw2;
    int cz = max(N, 53248);
    convw_zero_kernel<<<(cz + 255) / 256, 256, 0, stream>>>(wp, (unsigned*)wb, 53248,
                                                            cnt, N);

    // ---- CSR build
    hist_kernel<<<(E2 + 255) / 256, 256, 0, stream>>>(ei, E, E2, cnt, pos);
    scan1_kernel<<<nb, 256, 0, stream>>>(cnt, rs, bsum, N);
    scan23_kernel<<<nb, 256, 0, stream>>>(rs, cnt, bsum, N);
    scatter_kernel<<<(E2 + 255) / 256, 256, 0, stream>>>(ei, E, E2, rs, pos, srclist);

    int gx = (N + 63) / 64;

    // ---- fused encoder -> bufA
    encoder_kernel<<<gx, 256, 0, stream>>>(x, types, ew1, eb1, cw1, cb1,
                                           wb_ew2, wb_cw2, eb2, cb2, bufA, N);

    // ---- GAT layers (out never aliases hl=bufB)
    // layer 0: h0 = relu(gat(h))            bufA -> bufA
    gat_layer<4>(bufA, wb_lin0, as0, ad0, b0, nullptr, bufB, bufA,
                 a_s, a_d, rs, cnt, srclist, N, stream);
    // layer 1: h1 = h0 + relu(gat(h0))      bufA -> bufC
    gat_layer<4>(bufA, wb_lin1, as1, ad1, b1, bufA, bufB, bufC,
                 a_s, a_d, rs, cnt, srclist, N, stream);
    // layer 2: h2 = h1 + relu(gat(h1))      bufC -> bufA  (1 head, mean=identity)
    gat_layer<1>(bufC, wb_lin2, as2, ad2, b2, bufC, bufB, bufA,
                 a_s, a_d, rs, cnt, srclist, N, stream);

    // ---- decoder: d1 -> bufC ; d2 GEMM fused with final dot/sigmoid/mask
    gemm_mfma_kernel<128, 0><<<gx, 256, 0, stream>>>(
        bufA, wb_dw1, db1, nullptr, bufC, nullptr, nullptr, nullptr, nullptr,
        nullptr, nullptr, nullptr, N, 1);
    gemm_mfma_kernel<64, 0><<<gx, 256, 0, stream>>>(
        bufC, wb_dw2, db2, types, nullptr, nullptr, nullptr, nullptr, nullptr,
        dw3, db3, (float*)d_out, N, 3);
}